// Round 7
// baseline (4500.890 us; speedup 1.0000x reference)
//
#include <hip/hip_runtime.h>

#define HID     128
#define NNODES  20000
#define NEDGES  640000
#define NSTEPS  10

typedef __attribute__((ext_vector_type(8)))  short short8;
typedef __attribute__((ext_vector_type(16))) float f32x16;

union Frag { short8 s; uint4 q; uint u[4]; };
union Acc  { f32x16 v; float f[16]; };

#define MFMA(a,b,c) __builtin_amdgcn_mfma_f32_32x32x16_bf16((a),(b),(c),0,0,0)

// split 4 fp32 into bf16 hi-plane pair-u32s and lo-plane pair-u32s
static __device__ inline void pack4(const float v0, const float v1,
                                    const float v2, const float v3,
                                    uint2& hi, uint2& lo)
{
    const uint h0 = __float_as_uint(v0) & 0xFFFF0000u;
    const uint h1 = __float_as_uint(v1) & 0xFFFF0000u;
    const uint h2 = __float_as_uint(v2) & 0xFFFF0000u;
    const uint h3 = __float_as_uint(v3) & 0xFFFF0000u;
    hi.x = (h0 >> 16) | h1;
    hi.y = (h2 >> 16) | h3;
    lo.x = (__float_as_uint(v0 - __uint_as_float(h0)) >> 16)
         | (__float_as_uint(v1 - __uint_as_float(h1)) & 0xFFFF0000u);
    lo.y = (__float_as_uint(v2 - __uint_as_float(h2)) >> 16)
         | (__float_as_uint(v3 - __uint_as_float(h3)) & 0xFFFF0000u);
}

// ---------------- node encoder (KIN=16, skip first 2 feats) ----------------
template<int KIN, int KSTART>
__global__ __launch_bounds__(128) void encoder_kernel(
    const float* __restrict__ in,
    const float* __restrict__ W1, const float* __restrict__ b1,
    const float* __restrict__ W2, const float* __restrict__ b2,
    const float* __restrict__ W3, const float* __restrict__ b3,
    float* __restrict__ out, int n)
{
    __shared__ float xs[16][(KIN < 4) ? 4 : KIN];
    __shared__ float h1[16][HID];
    __shared__ float h2[16][HID];
    const int t = threadIdx.x;
    const int base = blockIdx.x * 16;

    for (int i = t; i < 16 * KIN; i += 128) {
        int e = i / KIN, k = i % KIN;
        int g = base + e;
        xs[e][k] = (g < n) ? in[(size_t)g * KIN + k] : 0.f;
    }
    __syncthreads();
    {
        const float bb = b1[t];
        for (int e = 0; e < 16; ++e) {
            float acc = bb;
            #pragma unroll
            for (int k = KSTART; k < KIN; ++k) acc += xs[e][k] * W1[k * HID + t];
            h1[e][t] = fmaxf(acc, 0.f);
        }
    }
    __syncthreads();
    {
        const float bb = b2[t];
        for (int e = 0; e < 16; ++e) {
            float acc = bb;
            for (int k = 0; k < HID; ++k) acc += h1[e][k] * W2[k * HID + t];
            h2[e][t] = fmaxf(acc, 0.f);
        }
    }
    __syncthreads();
    {
        const float bb = b3[t];
        for (int e = 0; e < 16; ++e) {
            int g = base + e;
            if (g >= n) continue;
            float acc = bb;
            for (int k = 0; k < HID; ++k) acc += h2[e][k] * W3[k * HID + t];
            out[(size_t)g * HID + t] = acc;
        }
    }
}

// ---------------- weight repack to A-frag layout (hi/lo planes) ----------------
__global__ __launch_bounds__(256) void wprep_kernel(
    const float* __restrict__ eW3,
    const float* __restrict__ pW1, const float* __restrict__ pW2,
    const float* __restrict__ pW3, const float* __restrict__ eW2,
    uint4* __restrict__ out)
{
    const int gid = blockIdx.x * 256 + threadIdx.x;
    if (gid >= NSTEPS * 16384 + 4096) return;

    int layer, rr, sid = 0;
    if (gid >= NSTEPS * 16384) { layer = 3; rr = gid - NSTEPS * 16384; }
    else {
        sid = gid / 16384;
        const int r = gid % 16384;
        if (r < 8192)       { layer = 0; rr = r; }
        else if (r < 12288) { layer = 1; rr = r - 8192; }
        else                { layer = 2; rr = r - 12288; }
    }
    const int ks  = rr >> 9;
    const int rem = rr & 511;
    const int rb  = rem >> 7;
    const int pl  = (rem >> 6) & 1;
    const int l   = rem & 63;
    const int c   = rb * 32 + (l & 31);
    const int k0  = ks * 16 + 8 * (l >> 5);

    float vals[8];
    if (layer == 0 && ks >= 8) {
        const float* W1l = pW1 + (size_t)sid * 2 * HID * HID;
        #pragma unroll
        for (int j = 0; j < 8; ++j) vals[j] = 0.f;
        const int kp = k0 - HID;
        for (int k = 0; k < HID; ++k) {
            const float wv = W1l[(size_t)(HID + k) * HID + c];
            #pragma unroll
            for (int j = 0; j < 8; ++j)
                vals[j] += eW3[(size_t)(kp + j) * HID + k] * wv;
        }
    } else {
        const float* Wsrc =
            (layer == 0) ? pW1 + (size_t)sid * 2 * HID * HID :
            (layer == 1) ? pW2 + (size_t)sid * HID * HID :
            (layer == 2) ? pW3 + (size_t)sid * HID * HID : eW2;
        #pragma unroll
        for (int j = 0; j < 8; ++j)
            vals[j] = Wsrc[(size_t)(k0 + j) * HID + c];
    }

    uint b16[8];
    #pragma unroll
    for (int j = 0; j < 8; ++j) {
        const uint hx = __float_as_uint(vals[j]) & 0xFFFF0000u;
        b16[j] = (pl == 0) ? (hx >> 16)
                           : (__float_as_uint(vals[j] - __uint_as_float(hx)) >> 16);
    }
    uint4 o;
    o.x = b16[0] | (b16[1] << 16);
    o.y = b16[2] | (b16[3] << 16);
    o.z = b16[4] | (b16[5] << 16);
    o.w = b16[6] | (b16[7] << 16);
    out[gid] = o;
}

// ---------------- fused L1 bias: g = pb1 + eb3 @ W1_lower ----------------
__global__ __launch_bounds__(128) void gfuse_kernel(
    const float* __restrict__ eb3, const float* __restrict__ pW1,
    const float* __restrict__ pb1, float* __restrict__ g)
{
    const int l = blockIdx.x, c = threadIdx.x;
    const float* W1l = pW1 + (size_t)l * 2 * HID * HID;
    float a = pb1[l * HID + c];
    for (int k = 0; k < HID; ++k)
        a += eb3[k] * W1l[(size_t)(HID + k) * HID + c];
    g[l * HID + c] = a;
}

// ---------------- CSR sort: histogram -> scan -> scatter ----------------
__global__ void hist_kernel(const int* __restrict__ dst, int* __restrict__ cnt)
{
    int i = blockIdx.x * blockDim.x + threadIdx.x;
    if (i < NEDGES) {
        int d = min(max(dst[i], 0), NNODES - 1);
        atomicAdd(&cnt[d], 1);
    }
}

__global__ __launch_bounds__(1024) void scan_kernel(
    const int* __restrict__ cnt, int* __restrict__ rowptr)
{
    __shared__ int part[1024];
    const int t = threadIdx.x;
    int vals[20];
    int s = 0;
    const int base = t * 20;
    #pragma unroll
    for (int j = 0; j < 20; ++j) {
        int idx = base + j;
        int v = (idx < NNODES) ? cnt[idx] : 0;
        vals[j] = s;
        s += v;
    }
    part[t] = s;
    __syncthreads();
    for (int off = 1; off < 1024; off <<= 1) {
        int v = (t >= off) ? part[t - off] : 0;
        __syncthreads();
        part[t] += v;
        __syncthreads();
    }
    const int pre = (t == 0) ? 0 : part[t - 1];
    #pragma unroll
    for (int j = 0; j < 20; ++j) {
        int idx = base + j;
        if (idx < NNODES) rowptr[idx] = pre + vals[j];
    }
    if (t == 0) rowptr[NNODES] = NEDGES;
}

__global__ void scatter_kernel(
    const int* __restrict__ src, const int* __restrict__ dst,
    const int* __restrict__ rowptr, int* __restrict__ fill,
    int* __restrict__ seid, unsigned short* __restrict__ ssrc,
    unsigned short* __restrict__ sdst)
{
    int i = blockIdx.x * blockDim.x + threadIdx.x;
    if (i < NEDGES) {
        int d = min(max(dst[i], 0), NNODES - 1);
        int s = min(max(src[i], 0), NNODES - 1);
        int pos = rowptr[d] + atomicAdd(&fill[d], 1);
        seid[pos] = i;
        ssrc[pos] = (unsigned short)s;
        sdst[pos] = (unsigned short)d;
    }
}

// ---------------- one MFMA layer phase (single plane-pair source) ----------------
// Wave owns ONE col-block rb and BOTH edge-groups. W: global, depth-4 ring; B: LDS depth-2.
template<int NKS>
static __device__ inline void run_phase(
    const uint4* __restrict__ wf, int rb, int l, int g, int e0, int e1,
    const uint* __restrict__ PH, const uint* __restrict__ PL,
    Acc& aA0, Acc& aB0, Acc& aA1, Acc& aB1)
{
    Frag wbuf[4][2];   // [slot][hi/lo]
    Frag bbuf[2][4];   // [slot][bh0, bl0, bh1, bl1]
    auto loadW = [&](int ks, int slot) {
        const uint4* wbase = wf + (size_t)(ks * 4 + rb) * 2 * 64;
        wbuf[slot][0].q = wbase[l];
        wbuf[slot][1].q = wbase[64 + l];
    };
    auto loadB = [&](int ks, int slot) {
        const int sl = ((ks * 16 + 8 * g) >> 3);
        const int bo0 = e0 * 64 + ((sl ^ (e0 & 15)) << 2);
        const int bo1 = e1 * 64 + ((sl ^ (e1 & 15)) << 2);
        bbuf[slot][0].q = *(const uint4*)&PH[bo0];
        bbuf[slot][1].q = *(const uint4*)&PL[bo0];
        bbuf[slot][2].q = *(const uint4*)&PH[bo1];
        bbuf[slot][3].q = *(const uint4*)&PL[bo1];
    };
    loadW(0, 0);
    loadB(0, 0);
    if (NKS > 1) loadW(1, 1);
    if (NKS > 2) loadW(2, 2);
    if (NKS > 3) loadW(3, 3);
    #pragma unroll
    for (int ks = 0; ks < NKS; ++ks) {
        if (ks + 1 < NKS) loadB(ks + 1, (ks + 1) & 1);
        Frag& ah  = wbuf[ks & 3][0];
        Frag& al  = wbuf[ks & 3][1];
        Frag& bh0 = bbuf[ks & 1][0];
        Frag& bl0 = bbuf[ks & 1][1];
        Frag& bh1 = bbuf[ks & 1][2];
        Frag& bl1 = bbuf[ks & 1][3];
        __builtin_amdgcn_s_setprio(1);
        aA0.v = MFMA(ah.s, bh0.s, aA0.v);
        aA1.v = MFMA(ah.s, bh1.s, aA1.v);
        aB0.v = MFMA(ah.s, bl0.s, aB0.v);
        aB1.v = MFMA(ah.s, bl1.s, aB1.v);
        aA0.v = MFMA(al.s, bh0.s, aA0.v);
        aA1.v = MFMA(al.s, bh1.s, aA1.v);
        __builtin_amdgcn_s_setprio(0);
        if (ks + 4 < NKS) loadW(ks + 4, ks & 3);   // refill just-freed slot
    }
}

// epilogue: bias (+relu), split hi/lo, store into planes
static __device__ inline void epi_store(
    uint* __restrict__ PH, uint* __restrict__ PL, int rb, int e, int g,
    const Acc& aA, const Acc& aB, const float* __restrict__ bias, bool relu)
{
    #pragma unroll
    for (int q = 0; q < 4; ++q) {
        const int c0 = rb * 32 + q * 8 + 4 * g;
        const float4 bv = *(const float4*)&bias[c0];
        float v0 = aA.f[q*4+0] + aB.f[q*4+0] + bv.x;
        float v1 = aA.f[q*4+1] + aB.f[q*4+1] + bv.y;
        float v2 = aA.f[q*4+2] + aB.f[q*4+2] + bv.z;
        float v3 = aA.f[q*4+3] + aB.f[q*4+3] + bv.w;
        if (relu) { v0 = fmaxf(v0, 0.f); v1 = fmaxf(v1, 0.f); v2 = fmaxf(v2, 0.f); v3 = fmaxf(v3, 0.f); }
        uint2 hi, lo;
        pack4(v0, v1, v2, v3, hi, lo);
        const int off = e * 64 + ((((c0 >> 3) ^ (e & 15))) << 2) + g * 2;
        *(uint2*)&PH[off] = hi;
        *(uint2*)&PL[off] = lo;
    }
}

// ---------------- MFMA message kernel: 32 KB time-shared LDS, 64 edges/block ----------------
// Phase order: h1e -> [edge-L2] -> h2e | [L1b: h2e half] -> x_j pack -> [L1a: x_j half]
// -> h1 | [L2] -> h2 | [L3] -> Mf (fp32 overlay) -> seg-sum.
__global__ __launch_bounds__(256, 3) void msg_mfma_s(
    const float* __restrict__ node,
    const float* __restrict__ edge_attr,
    const float* __restrict__ eW1, const float* __restrict__ eb1,
    const float* __restrict__ eb2,
    const uint4* __restrict__ ewfrag,
    const uint4* __restrict__ wfrag,
    const int* __restrict__ seidg,
    const unsigned short* __restrict__ ssrcg,
    const unsigned short* __restrict__ sdstg,
    const float* __restrict__ gb1, const float* __restrict__ b2,
    const float* __restrict__ b3,
    float* __restrict__ agg)
{
    __shared__ uint4 pool4[2048];        // 32 KB: HH|HL planes / Mf fp32 overlay
    __shared__ float eas[192];
    __shared__ int ssrc[64], sdst[64], seid[64];
    uint* HH = (uint*)pool4;
    uint* HL = (uint*)(pool4 + 1024);
    float* Mf = (float*)pool4;

    const int t   = threadIdx.x;
    const int wv  = t >> 6;
    const int l   = t & 63;
    const int l31 = l & 31;
    const int g   = l >> 5;
    const int rb  = wv;                  // wave owns one col block
    const int e0  = l31;                 // edge-group 0
    const int e1  = 32 + l31;            // edge-group 1
    const int eb0 = blockIdx.x * 64;

    if (t < 64)       ssrc[t]       = ssrcg[eb0 + t];
    else if (t < 128) sdst[t - 64]  = sdstg[eb0 + (t - 64)];
    else if (t < 192) seid[t - 128] = seidg[eb0 + (t - 128)];
    __syncthreads();

    // T14: issue x_j gathers into registers now; consumed at L1a pack
    float4 xreg[8];
    #pragma unroll
    for (int i = 0; i < 8; ++i) {
        const int idx = i * 256 + t;
        const int ee = idx >> 5, q = idx & 31;
        xreg[i] = *(const float4*)&node[(size_t)ssrc[ee] * HID + q * 4];
    }
    if (t < 192) eas[t] = edge_attr[(size_t)seid[t / 3] * 3 + (t % 3)];
    __syncthreads();

    // h1e = relu(ea @ eW1 + eb1) on VALU -> HH/HL
    {
        const int ee = t & 63, sb = t >> 6;
        const float a0 = eas[ee * 3 + 0], a1 = eas[ee * 3 + 1], a2 = eas[ee * 3 + 2];
        #pragma unroll
        for (int i = 0; i < 8; ++i) {
            const int s4 = sb + 4 * i;
            const int c0 = s4 * 4;
            const float4 w1 = *(const float4*)&eW1[0 * HID + c0];
            const float4 w2 = *(const float4*)&eW1[1 * HID + c0];
            const float4 w3 = *(const float4*)&eW1[2 * HID + c0];
            const float4 bb = *(const float4*)&eb1[c0];
            const float v0 = fmaxf(bb.x + a0 * w1.x + a1 * w2.x + a2 * w3.x, 0.f);
            const float v1 = fmaxf(bb.y + a0 * w1.y + a1 * w2.y + a2 * w3.y, 0.f);
            const float v2 = fmaxf(bb.z + a0 * w1.z + a1 * w2.z + a2 * w3.z, 0.f);
            const float v3 = fmaxf(bb.w + a0 * w1.w + a1 * w2.w + a2 * w3.w, 0.f);
            uint2 hi, lo;
            pack4(v0, v1, v2, v3, hi, lo);
            const int off = ee * 64 + ((((s4 >> 1) ^ (ee & 15))) << 2) + (s4 & 1) * 2;
            *(uint2*)&HH[off] = hi;
            *(uint2*)&HL[off] = lo;
        }
    }
    __syncthreads();

    Acc aA0, aB0, aA1, aB1;
#define ZACC() do { _Pragma("unroll") \
    for (int z = 0; z < 16; ++z) { aA0.f[z] = 0.f; aB0.f[z] = 0.f; aA1.f[z] = 0.f; aB1.f[z] = 0.f; } } while (0)

    // ---- edge L2: h2e = relu(h1e @ eW2 + eb2)  (H -> H) ----
    ZACC();
    run_phase<8>(ewfrag, rb, l, g, e0, e1, HH, HL, aA0, aB0, aA1, aB1);
    __syncthreads();
    epi_store(HH, HL, rb, e0, g, aA0, aB0, eb2, true);
    epi_store(HH, HL, rb, e1, g, aA1, aB1, eb2, true);
    __syncthreads();

    // ---- L1b: acc += h2e @ Wc_lower  (k = 128..255 half) ----
    ZACC();
    run_phase<8>(wfrag + 4096, rb, l, g, e0, e1, HH, HL, aA0, aB0, aA1, aB1);
    __syncthreads();
    // pack x_j into planes (h2e dead)
    #pragma unroll
    for (int i = 0; i < 8; ++i) {
        const int idx = i * 256 + t;
        const int ee = idx >> 5, q = idx & 31;
        uint2 hi, lo;
        pack4(xreg[i].x, xreg[i].y, xreg[i].z, xreg[i].w, hi, lo);
        const int off = ee * 64 + ((((q >> 1) ^ (ee & 15))) << 2) + (q & 1) * 2;
        *(uint2*)&HH[off] = hi;
        *(uint2*)&HL[off] = lo;
    }
    __syncthreads();

    // ---- L1a: acc += x_j @ Wc_upper  (k = 0..127 half; same accumulators) ----
    run_phase<8>(wfrag, rb, l, g, e0, e1, HH, HL, aA0, aB0, aA1, aB1);
    __syncthreads();
    epi_store(HH, HL, rb, e0, g, aA0, aB0, gb1, true);
    epi_store(HH, HL, rb, e1, g, aA1, aB1, gb1, true);
    __syncthreads();

    // ---- L2: h2 = relu(h1 @ W2 + b2)  (H -> H) ----
    ZACC();
    run_phase<8>(wfrag + 8192, rb, l, g, e0, e1, HH, HL, aA0, aB0, aA1, aB1);
    __syncthreads();
    epi_store(HH, HL, rb, e0, g, aA0, aB0, b2, true);
    epi_store(HH, HL, rb, e1, g, aA1, aB1, b2, true);
    __syncthreads();

    // ---- L3: msg = h2 @ W3 + b3 -> Mf (fp32 overlay on planes) ----
    ZACC();
    run_phase<8>(wfrag + 12288, rb, l, g, e0, e1, HH, HL, aA0, aB0, aA1, aB1);
    __syncthreads();     // all reads of h2 done before fp32 overlay
    #pragma unroll
    for (int q = 0; q < 4; ++q) {
        const int c0 = rb * 32 + q * 8 + 4 * g;
        const float4 bva = *(const float4*)&b3[c0];
        float4 v0;
        v0.x = aA0.f[q*4+0] + aB0.f[q*4+0] + bva.x;
        v0.y = aA0.f[q*4+1] + aB0.f[q*4+1] + bva.y;
        v0.z = aA0.f[q*4+2] + aB0.f[q*4+2] + bva.z;
        v0.w = aA0.f[q*4+3] + aB0.f[q*4+3] + bva.w;
        *(float4*)&Mf[e0 * 128 + (c0 ^ ((e0 & 7) << 2))] = v0;
        float4 v1;
        v1.x = aA1.f[q*4+0] + aB1.f[q*4+0] + bva.x;
        v1.y = aA1.f[q*4+1] + aB1.f[q*4+1] + bva.y;
        v1.z = aA1.f[q*4+2] + aB1.f[q*4+2] + bva.z;
        v1.w = aA1.f[q*4+3] + aB1.f[q*4+3] + bva.w;
        *(float4*)&Mf[e1 * 128 + (c0 ^ ((e1 & 7) << 2))] = v1;
    }
#undef ZACC
    __syncthreads();

    // ---- segmented sum over sorted dst (float4-vectorized: 8-edge segments) ----
    {
        const int grp = t & 31;          // channel group: c0 = grp*4
        const int seg = t >> 5;          // 0..7
        const int c0  = grp << 2;
        const int es  = seg * 8;
        float4 run = make_float4(0.f, 0.f, 0.f, 0.f);
        int cur = sdst[es];
        for (int e2 = es; e2 < es + 8; ++e2) {
            const int d2 = sdst[e2];
            const float4 v = *(const float4*)&Mf[e2 * 128 + (c0 ^ ((e2 & 7) << 2))];
            if (d2 != cur) {
                float* ap = &agg[(size_t)cur * HID + c0];
                atomicAdd(ap + 0, run.x);
                atomicAdd(ap + 1, run.y);
                atomicAdd(ap + 2, run.z);
                atomicAdd(ap + 3, run.w);
                run = make_float4(0.f, 0.f, 0.f, 0.f);
                cur = d2;
            }
            run.x += v.x; run.y += v.y; run.z += v.z; run.w += v.w;
        }
        float* ap = &agg[(size_t)cur * HID + c0];
        atomicAdd(ap + 0, run.x);
        atomicAdd(ap + 1, run.y);
        atomicAdd(ap + 2, run.z);
        atomicAdd(ap + 3, run.w);
    }
}

// ---------------- residual update (fast path: denom from rowptr); re-zero agg ----------------
__global__ void update_kernel_csr(float* __restrict__ node, float* __restrict__ agg,
                                  const int* __restrict__ rowptr)
{
    int i = blockIdx.x * blockDim.x + threadIdx.x;
    if (i < NNODES * HID) {
        int n = i >> 7;
        float cnt = (float)(rowptr[n + 1] - rowptr[n]);
        node[i] += agg[i] / fmaxf(cnt, 1.0f);
        agg[i] = 0.f;
    }
}

// ---------------- decoder: 128->128->128->2 ----------------
__global__ __launch_bounds__(128) void decoder_kernel(
    const float* __restrict__ node,
    const float* __restrict__ W1, const float* __restrict__ b1,
    const float* __restrict__ W2, const float* __restrict__ b2,
    const float* __restrict__ W3, const float* __restrict__ b3,
    float* __restrict__ out)
{
    __shared__ float xs[16][HID];
    __shared__ float h1[16][HID];
    __shared__ float h2[16][HID];
    const int t = threadIdx.x;
    const int base = blockIdx.x * 16;

    for (int i = t; i < 16 * 32; i += 128) {
        int e = i >> 5, c = (i & 31) << 2;
        *(float4*)&xs[e][c] = *(const float4*)&node[(size_t)(base + e) * HID + c];
    }
    __syncthreads();
    {
        const float bb = b1[t];
        for (int e = 0; e < 16; ++e) {
            float acc = bb;
            for (int k = 0; k < HID; ++k) acc += xs[e][k] * W1[k * HID + t];
            h1[e][t] = fmaxf(acc, 0.f);
        }
    }
    __syncthreads();
    {
        const float bb = b2[t];
        for (int e = 0; e < 16; ++e) {
            float acc = bb;
            for (int k = 0; k < HID; ++k) acc += h1[e][k] * W2[k * HID + t];
            h2[e][t] = fmaxf(acc, 0.f);
        }
    }
    __syncthreads();
    if (t < 32) {
        const int e = t >> 1, o = t & 1;
        float acc = b3[o];
        for (int k = 0; k < HID; ++k) acc += h2[e][k] * W3[k * 2 + o];
        out[(size_t)(base + e) * 2 + o] = acc;
    }
}

// ================= fallback (RECOMP fp32 path, proven rounds 2-3) =================
__global__ void degree_kernel(const int* __restrict__ dst, float* __restrict__ cnt)
{
    int i = blockIdx.x * blockDim.x + threadIdx.x;
    if (i < NEDGES) {
        int d = min(max(dst[i], 0), NNODES - 1);
        atomicAdd(&cnt[d], 1.0f);
    }
}

__global__ void update_kernel_cnt(float* __restrict__ node, float* __restrict__ agg,
                                  const float* __restrict__ cnt)
{
    int i = blockIdx.x * blockDim.x + threadIdx.x;
    if (i < NNODES * HID) {
        int n = i >> 7;
        node[i] += agg[i] / fmaxf(cnt[n], 1.0f);
        agg[i] = 0.f;
    }
}

__global__ __launch_bounds__(128) void fuse_kernel(
    const float* __restrict__ eW3, const float* __restrict__ eb3,
    const float* __restrict__ pW1, const float* __restrict__ pb1,
    float* __restrict__ Wc, float* __restrict__ g)
{
    const int l = blockIdx.x >> 3;
    const int s = blockIdx.x & 7;
    const int c = threadIdx.x;
    const float* W1l = pW1 + (size_t)l * 2 * HID * HID;
    float* Wcl = Wc + (size_t)l * 2 * HID * HID;

    for (int r = s * 16; r < s * 16 + 16; ++r)
        Wcl[r * HID + c] = W1l[r * HID + c];

    for (int m = s * 16; m < s * 16 + 16; ++m) {
        float a0 = 0.f, a1 = 0.f, a2 = 0.f, a3 = 0.f;
        for (int k = 0; k < HID; k += 4) {
            a0 += eW3[m * HID + k + 0] * W1l[(HID + k + 0) * HID + c];
            a1 += eW3[m * HID + k + 1] * W1l[(HID + k + 1) * HID + c];
            a2 += eW3[m * HID + k + 2] * W1l[(HID + k + 2) * HID + c];
            a3 += eW3[m * HID + k + 3] * W1l[(HID + k + 3) * HID + c];
        }
        Wcl[(HID + m) * HID + c] = (a0 + a1) + (a2 + a3);
    }
    if (s == 0) {
        float a = pb1[l * HID + c];
        for (int k = 0; k < HID; ++k)
            a += eb3[k] * W1l[(HID + k) * HID + c];
        g[l * HID + c] = a;
    }
}

__global__ __launch_bounds__(256) void msg_recomp(
    const float* __restrict__ node,
    const float* __restrict__ edge_attr,
    const float* __restrict__ eW1, const float* __restrict__ eb1,
    const float* __restrict__ eW2, const float* __restrict__ eb2,
    const int* __restrict__ src_idx, const int* __restrict__ dst_idx,
    const float* __restrict__ W1, const float* __restrict__ b1,
    const float* __restrict__ W2, const float* __restrict__ b2,
    const float* __restrict__ W3, const float* __restrict__ b3,
    float* __restrict__ agg)
{
    __shared__ float X[32][256];
    __shared__ float H[32][HID];
    __shared__ int ssrc[32];
    __shared__ int sdst[32];
    __shared__ float ea_s[32][4];

    const int t = threadIdx.x;
    const int eb = blockIdx.x * 32;

    if (t < 32) { int s = src_idx[eb + t]; ssrc[t] = min(max(s, 0), NNODES - 1); }
    else if (t < 64) { int d = dst_idx[eb + (t - 32)]; sdst[t - 32] = min(max(d, 0), NNODES - 1); }
    __syncthreads();

    for (int i = t; i < 32 * 32; i += 256) {
        int e = i >> 5; int c = (i & 31) << 2;
        *(float4*)&X[e][c] = *(const float4*)&node[(size_t)ssrc[e] * HID + c];
    }
    for (int i = t; i < 32 * 3; i += 256)
        ea_s[i / 3][i % 3] = edge_attr[(size_t)(eb + i / 3) * 3 + (i % 3)];
    __syncthreads();

    const int ct = t & 31;
    const int et = (t >> 5) << 2;
    const int cb = ct << 2;
    float acc[4][4];

    {
        const float4 bv = *(const float4*)&eb1[cb];
        #pragma unroll
        for (int j = 0; j < 4; ++j) { acc[j][0] = bv.x; acc[j][1] = bv.y; acc[j][2] = bv.z; acc[j][3] = bv.w; }
        #pragma unroll
        for (int k = 0; k < 3; ++k) {
            const float4 wv = *(const float4*)&eW1[k * HID + cb];
            #pragma unroll
            for (int j = 0; j < 4; ++j) {
                const float xx = ea_s[et + j][k];
                acc[j][0] += xx * wv.x; acc[j][1] += xx * wv.y; acc[j][2] += xx * wv.z; acc[j][3] += xx * wv.w;
            }
        }
        #pragma unroll
        for (int j = 0; j < 4; ++j)
            *(float4*)&H[et + j][cb] = make_float4(fmaxf(acc[j][0],0.f), fmaxf(acc[j][1],0.f), fmaxf(acc[j][2],0.f), fmaxf(acc[j][3],0.f));
    }
    __syncthreads();
    {
        const float4 bv = *(const float4*)&eb2[cb];
        #pragma unroll
        for (int j = 0; j < 4; ++j) { acc[j][0] = bv.x; acc[j][1] = bv.y; acc[j][2] = bv.z; acc[j][3] = bv.w; }
        for (int k = 0; k < HID; ++k) {
            const float4 wv = *(const float4*)&eW2[k * HID + cb];
            const float x0 = H[et+0][k], x1 = H[et+1][k], x2 = H[et+2][k], x3 = H[et+3][k];
            acc[0][0]+=x0*wv.x; acc[0][1]+=x0*wv.y; acc[0][2]+=x0*wv.z; acc[0][3]+=x0*wv.w;
            acc[1][0]+=x1*wv.x; acc[1][1]+=x1*wv.y; acc[1][2]+=x1*wv.z; acc[1][3]+=x1*wv.w;
            acc[2][0]+=x2*wv.x; acc[2][1]+=x2*wv.y; acc[2][2]+=x2*wv.z; acc[2][3]+=x2*wv.w;
            acc[3][0]+=x3*wv.x; acc[3][1]+=x3*wv.y; acc[3][2]+=x3*wv.z; acc[3][3]+=x3*wv.w;
        }
        #pragma unroll
        for (int j = 0; j < 4; ++j)
            *(float4*)&X[et + j][HID + cb] = make_float4(fmaxf(acc[j][0],0.f), fmaxf(acc[j][1],0.f), fmaxf(acc[j][2],0.f), fmaxf(acc[j][3],0.f));
    }
    __syncthreads();
    {
        const float4 bv = *(const float4*)&b1[cb];
        #pragma unroll
        for (int j = 0; j < 4; ++j) { acc[j][0] = bv.x; acc[j][1] = bv.y; acc[j][2] = bv.z; acc[j][3] = bv.w; }
        for (int k = 0; k < 256; ++k) {
            const float4 wv = *(const float4*)&W1[k * HID + cb];
            const float x0 = X[et+0][k], x1 = X[et+1][k], x2 = X[et+2][k], x3 = X[et+3][k];
            acc[0][0]+=x0*wv.x; acc[0][1]+=x0*wv.y; acc[0][2]+=x0*wv.z; acc[0][3]+=x0*wv.w;
            acc[1][0]+=x1*wv.x; acc[1][1]+=x1*wv.y; acc[1][2]+=x1*wv.z; acc[1][3]+=x1*wv.w;
            acc[2][0]+=x2*wv.x; acc[2][1]+=x2*wv.y; acc[2][2]+=x2*wv.z; acc[2][3]+=x2*wv.w;
            acc[3][0]+=x3*wv.x; acc[3][1]+=x3*wv.y; acc[3][2]+=x3*wv.z; acc[3][3]+=x3*wv.w;
        }
        __syncthreads();
        #pragma unroll
        for (int j = 0; j < 4; ++j)
            *(float4*)&H[et + j][cb] = make_float4(fmaxf(acc[j][0],0.f), fmaxf(acc[j][1],0.f), fmaxf(acc[j][2],0.f), fmaxf(acc[j][3],0.f));
    }
    __syncthreads();
    float* Xf = &X[0][0];
    {
        const float4 bv = *(const float4*)&b2[cb];
        #pragma unroll
        for (int j = 0; j < 4; ++j) { acc[j][0] = bv.x; acc[j][1] = bv.y; acc[j][2] = bv.z; acc[j][3] = bv.w; }
        for (int k = 0; k < HID; ++k) {
            const float4 wv = *(const float4*)&W2[k * HID + cb];
            const float x0 = H[et+0][k], x1 = H[et+1][k], x2 = H[et+2][k], x3 = H[et+3][k];
            acc[0][0]+=x0*wv.x; acc[0][1]+=x0*wv.y; acc[0][2]+=x0*wv.z; acc[0][3]+=x0*wv.w;
            acc[1][0]+=x1*wv.x; acc[1][1]+=x1*wv.y; acc[1][2]+=x1*wv.z; acc[1][3]+=x1*wv.w;
            acc[2][0]+=x2*wv.x; acc[2][1]+=x2*wv.y; acc[2][2]+=x2*wv.z; acc[2][3]+=x2*wv.w;
            acc[3][0]+=x3*wv.x; acc[3][1]+=x3*wv.y; acc[3][2]+=x3*wv.z; acc[3][3]+=x3*wv.w;
        }
        #pragma unroll
        for (int j = 0; j < 4; ++j)
            *(float4*)&Xf[(et + j) * HID + cb] = make_float4(fmaxf(acc[j][0],0.f), fmaxf(acc[j][1],0.f), fmaxf(acc[j][2],0.f), fmaxf(acc[j][3],0.f));
    }
    __syncthreads();
    {
        const float4 bv = *(const float4*)&b3[cb];
        #pragma unroll
        for (int j = 0; j < 4; ++j) { acc[j][0] = bv.x; acc[j][1] = bv.y; acc[j][2] = bv.z; acc[j][3] = bv.w; }
        for (int k = 0; k < HID; ++k) {
            const float4 wv = *(const float4*)&W3[k * HID + cb];
            const float x0 = Xf[(et+0)*HID+k], x1 = Xf[(et+1)*HID+k];
            const float x2 = Xf[(et+2)*HID+k], x3 = Xf[(et+3)*HID+k];
            acc[0][0]+=x0*wv.x; acc[0][1]+=x0*wv.y; acc[0][2]+=x0*wv.z; acc[0][3]+=x0*wv.w;
            acc[1][0]+=x1*wv.x; acc[1][1]+=x1*wv.y; acc[1][2]+=x1*wv.z; acc[1][3]+=x1*wv.w;
            acc[2][0]+=x2*wv.x; acc[2][1]+=x2*wv.y; acc[2][2]+=x2*wv.z; acc[2][3]+=x2*wv.w;
            acc[3][0]+=x3*wv.x; acc[3][1]+=x3*wv.y; acc[3][2]+=x3*wv.z; acc[3][3]+=x3*wv.w;
        }
        #pragma unroll
        for (int j = 0; j < 4; ++j) {
            const int d = sdst[et + j];
            float* ap = &agg[(size_t)d * HID + cb];
            atomicAdd(ap + 0, acc[j][0]);
            atomicAdd(ap + 1, acc[j][1]);
            atomicAdd(ap + 2, acc[j][2]);
            atomicAdd(ap + 3, acc[j][3]);
        }
    }
}

extern "C" void kernel_launch(void* const* d_in, const int* in_sizes, int n_in,
                              void* d_out, int out_size, void* d_ws, size_t ws_size,
                              hipStream_t stream)
{
    const float* x         = (const float*)d_in[0];
    const float* edge_attr = (const float*)d_in[1];
    const float* nW1 = (const float*)d_in[2];  const float* nb1 = (const float*)d_in[3];
    const float* nW2 = (const float*)d_in[4];  const float* nb2 = (const float*)d_in[5];
    const float* nW3 = (const float*)d_in[6];  const float* nb3 = (const float*)d_in[7];
    const float* eW1 = (const float*)d_in[8];  const float* eb1 = (const float*)d_in[9];
    const float* eW2 = (const float*)d_in[10]; const float* eb2 = (const float*)d_in[11];
    const float* eW3 = (const float*)d_in[12]; const float* eb3 = (const float*)d_in[13];
    const float* pW1 = (const float*)d_in[14]; const float* pb1 = (const float*)d_in[15];
    const float* pW2 = (const float*)d_in[16]; const float* pb2 = (const float*)d_in[17];
    const float* pW3 = (const float*)d_in[18]; const float* pb3 = (const float*)d_in[19];
    const float* dW1 = (const float*)d_in[20]; const float* db1 = (const float*)d_in[21];
    const float* dW2 = (const float*)d_in[22]; const float* db2 = (const float*)d_in[23];
    const float* dW3 = (const float*)d_in[24]; const float* db3 = (const float*)d_in[25];
    const int* ei  = (const int*)d_in[26];
    const int* src = ei;
    const int* dst = ei + NEDGES;

    // fast-path workspace layout (bytes)
    char* ws = (char*)d_ws;
    float* node    = (float*)(ws);                     // 10,240,000
    float* agg     = (float*)(ws + 10240000);          // 10,240,000
    int*   cnt_i   = (int*)  (ws + 20480000);          //     80,000
    int*   fill    = (int*)  (ws + 20560000);          //     80,000
    int*   rowptr  = (int*)  (ws + 20640000);          //     80,064 (20001 ints, padded)
    float* gb      = (float*)(ws + 20720064);          //      5,120
    uint4* wfrag   = (uint4*)(ws + 20725184);          //  2,621,440
    uint4* ewf     = (uint4*)(ws + 23346624);          //     65,536
    int*   seid    = (int*)  (ws + 23412160);          //  2,560,000
    unsigned short* ssrc16 = (unsigned short*)(ws + 25972160);  // 1,280,000
    unsigned short* sdst16 = (unsigned short*)(ws + 27252160);  // 1,280,000
    const size_t NEED_FAST = 28532160ull;

    // fallback layout (proven fits)
    float* cntf = (float*)(ws + 20480000);
    float* Wc   = (float*)(ws + 20560000);
    float* gb2  = (float*)(ws + 21870720);

    const bool fast = (ws_size >= NEED_FAST);

    encoder_kernel<16, 2><<<NNODES / 16, 128, 0, stream>>>(
        x, nW1, nb1, nW2, nb2, nW3, nb3, node, NNODES);

    if (fast) {
        // zero agg + cnt_i + fill (contiguous)
        hipMemsetAsync(ws + 10240000, 0, 10240000 + 160000, stream);

        hist_kernel<<<(NEDGES + 255) / 256, 256, 0, stream>>>(dst, cnt_i);
        scan_kernel<<<1, 1024, 0, stream>>>(cnt_i, rowptr);
        scatter_kernel<<<(NEDGES + 255) / 256, 256, 0, stream>>>(
            src, dst, rowptr, fill, seid, ssrc16, sdst16);

        wprep_kernel<<<(NSTEPS * 16384 + 4096) / 256, 256, 0, stream>>>(
            eW3, pW1, pW2, pW3, eW2, wfrag);
        gfuse_kernel<<<NSTEPS, 128, 0, stream>>>(eb3, pW1, pb1, gb);

        for (int l = 0; l < NSTEPS; ++l) {
            msg_mfma_s<<<NEDGES / 64, 256, 0, stream>>>(
                node, edge_attr, eW1, eb1, eb2,
                ewf, wfrag + (size_t)l * 16384,
                seid, ssrc16, sdst16,
                gb + l * HID, pb2 + l * HID, pb3 + l * HID, agg);
            update_kernel_csr<<<(NNODES * HID) / 256, 256, 0, stream>>>(node, agg, rowptr);
        }
    } else {
        hipMemsetAsync(ws + 10240000, 0, 10240000 + 80000, stream);
        degree_kernel<<<(NEDGES + 255) / 256, 256, 0, stream>>>(dst, cntf);
        fuse_kernel<<<NSTEPS * 8, 128, 0, stream>>>(eW3, eb3, pW1, pb1, Wc, gb2);
        for (int l = 0; l < NSTEPS; ++l) {
            msg_recomp<<<NEDGES / 32, 256, 0, stream>>>(
                node, edge_attr, eW1, eb1, eW2, eb2, src, dst,
                Wc + (size_t)l * 2 * HID * HID,  gb2 + l * HID,
                pW2 + (size_t)l * HID * HID,     pb2 + l * HID,
                pW3 + (size_t)l * HID * HID,     pb3 + l * HID,
                agg);
            update_kernel_cnt<<<(NNODES * HID) / 256, 256, 0, stream>>>(node, agg, cntf);
        }
    }

    decoder_kernel<<<NNODES / 16, 128, 0, stream>>>(
        node, dW1, db1, dW2, db2, dW3, db3, (float*)d_out);
}

// Round 8
// 3736.291 us; speedup vs baseline: 1.2046x; 1.2046x over previous
//
#include <hip/hip_runtime.h>

#define HID     128
#define NNODES  20000
#define NEDGES  640000
#define NSTEPS  10

typedef __attribute__((ext_vector_type(8)))  short short8;
typedef __attribute__((ext_vector_type(16))) float f32x16;

union Frag { short8 s; uint4 q; uint u[4]; };
union Acc  { f32x16 v; float f[16]; };

#define MFMA(a,b,c) __builtin_amdgcn_mfma_f32_32x32x16_bf16((a),(b),(c),0,0,0)

// split 4 fp32 into bf16 hi-plane pair-u32s and lo-plane pair-u32s
static __device__ inline void pack4(const float v0, const float v1,
                                    const float v2, const float v3,
                                    uint2& hi, uint2& lo)
{
    const uint h0 = __float_as_uint(v0) & 0xFFFF0000u;
    const uint h1 = __float_as_uint(v1) & 0xFFFF0000u;
    const uint h2 = __float_as_uint(v2) & 0xFFFF0000u;
    const uint h3 = __float_as_uint(v3) & 0xFFFF0000u;
    hi.x = (h0 >> 16) | h1;
    hi.y = (h2 >> 16) | h3;
    lo.x = (__float_as_uint(v0 - __uint_as_float(h0)) >> 16)
         | (__float_as_uint(v1 - __uint_as_float(h1)) & 0xFFFF0000u);
    lo.y = (__float_as_uint(v2 - __uint_as_float(h2)) >> 16)
         | (__float_as_uint(v3 - __uint_as_float(h3)) & 0xFFFF0000u);
}

// ---------------- node encoder (KIN=16, skip first 2 feats) ----------------
template<int KIN, int KSTART>
__global__ __launch_bounds__(128) void encoder_kernel(
    const float* __restrict__ in,
    const float* __restrict__ W1, const float* __restrict__ b1,
    const float* __restrict__ W2, const float* __restrict__ b2,
    const float* __restrict__ W3, const float* __restrict__ b3,
    float* __restrict__ out, int n)
{
    __shared__ float xs[16][(KIN < 4) ? 4 : KIN];
    __shared__ float h1[16][HID];
    __shared__ float h2[16][HID];
    const int t = threadIdx.x;
    const int base = blockIdx.x * 16;

    for (int i = t; i < 16 * KIN; i += 128) {
        int e = i / KIN, k = i % KIN;
        int g = base + e;
        xs[e][k] = (g < n) ? in[(size_t)g * KIN + k] : 0.f;
    }
    __syncthreads();
    {
        const float bb = b1[t];
        for (int e = 0; e < 16; ++e) {
            float acc = bb;
            #pragma unroll
            for (int k = KSTART; k < KIN; ++k) acc += xs[e][k] * W1[k * HID + t];
            h1[e][t] = fmaxf(acc, 0.f);
        }
    }
    __syncthreads();
    {
        const float bb = b2[t];
        for (int e = 0; e < 16; ++e) {
            float acc = bb;
            for (int k = 0; k < HID; ++k) acc += h1[e][k] * W2[k * HID + t];
            h2[e][t] = fmaxf(acc, 0.f);
        }
    }
    __syncthreads();
    {
        const float bb = b3[t];
        for (int e = 0; e < 16; ++e) {
            int g = base + e;
            if (g >= n) continue;
            float acc = bb;
            for (int k = 0; k < HID; ++k) acc += h2[e][k] * W3[k * HID + t];
            out[(size_t)g * HID + t] = acc;
        }
    }
}

// ---------------- weight repack to A-frag layout (hi/lo planes) ----------------
__global__ __launch_bounds__(256) void wprep_kernel(
    const float* __restrict__ eW3,
    const float* __restrict__ pW1, const float* __restrict__ pW2,
    const float* __restrict__ pW3, const float* __restrict__ eW2,
    uint4* __restrict__ out)
{
    const int gid = blockIdx.x * 256 + threadIdx.x;
    if (gid >= NSTEPS * 16384 + 4096) return;

    int layer, rr, sid = 0;
    if (gid >= NSTEPS * 16384) { layer = 3; rr = gid - NSTEPS * 16384; }
    else {
        sid = gid / 16384;
        const int r = gid % 16384;
        if (r < 8192)       { layer = 0; rr = r; }
        else if (r < 12288) { layer = 1; rr = r - 8192; }
        else                { layer = 2; rr = r - 12288; }
    }
    const int ks  = rr >> 9;
    const int rem = rr & 511;
    const int rb  = rem >> 7;
    const int pl  = (rem >> 6) & 1;
    const int l   = rem & 63;
    const int c   = rb * 32 + (l & 31);
    const int k0  = ks * 16 + 8 * (l >> 5);

    float vals[8];
    if (layer == 0 && ks >= 8) {
        const float* W1l = pW1 + (size_t)sid * 2 * HID * HID;
        #pragma unroll
        for (int j = 0; j < 8; ++j) vals[j] = 0.f;
        const int kp = k0 - HID;
        for (int k = 0; k < HID; ++k) {
            const float wv = W1l[(size_t)(HID + k) * HID + c];
            #pragma unroll
            for (int j = 0; j < 8; ++j)
                vals[j] += eW3[(size_t)(kp + j) * HID + k] * wv;
        }
    } else {
        const float* Wsrc =
            (layer == 0) ? pW1 + (size_t)sid * 2 * HID * HID :
            (layer == 1) ? pW2 + (size_t)sid * HID * HID :
            (layer == 2) ? pW3 + (size_t)sid * HID * HID : eW2;
        #pragma unroll
        for (int j = 0; j < 8; ++j)
            vals[j] = Wsrc[(size_t)(k0 + j) * HID + c];
    }

    uint b16[8];
    #pragma unroll
    for (int j = 0; j < 8; ++j) {
        const uint hx = __float_as_uint(vals[j]) & 0xFFFF0000u;
        b16[j] = (pl == 0) ? (hx >> 16)
                           : (__float_as_uint(vals[j] - __uint_as_float(hx)) >> 16);
    }
    uint4 o;
    o.x = b16[0] | (b16[1] << 16);
    o.y = b16[2] | (b16[3] << 16);
    o.z = b16[4] | (b16[5] << 16);
    o.w = b16[6] | (b16[7] << 16);
    out[gid] = o;
}

// ---------------- fused L1 bias: g = pb1 + eb3 @ W1_lower ----------------
__global__ __launch_bounds__(128) void gfuse_kernel(
    const float* __restrict__ eb3, const float* __restrict__ pW1,
    const float* __restrict__ pb1, float* __restrict__ g)
{
    const int l = blockIdx.x, c = threadIdx.x;
    const float* W1l = pW1 + (size_t)l * 2 * HID * HID;
    float a = pb1[l * HID + c];
    for (int k = 0; k < HID; ++k)
        a += eb3[k] * W1l[(size_t)(HID + k) * HID + c];
    g[l * HID + c] = a;
}

// ---------------- CSR sort: histogram -> scan -> scatter ----------------
__global__ void hist_kernel(const int* __restrict__ dst, int* __restrict__ cnt)
{
    int i = blockIdx.x * blockDim.x + threadIdx.x;
    if (i < NEDGES) {
        int d = min(max(dst[i], 0), NNODES - 1);
        atomicAdd(&cnt[d], 1);
    }
}

__global__ __launch_bounds__(1024) void scan_kernel(
    const int* __restrict__ cnt, int* __restrict__ rowptr)
{
    __shared__ int part[1024];
    const int t = threadIdx.x;
    int vals[20];
    int s = 0;
    const int base = t * 20;
    #pragma unroll
    for (int j = 0; j < 20; ++j) {
        int idx = base + j;
        int v = (idx < NNODES) ? cnt[idx] : 0;
        vals[j] = s;
        s += v;
    }
    part[t] = s;
    __syncthreads();
    for (int off = 1; off < 1024; off <<= 1) {
        int v = (t >= off) ? part[t - off] : 0;
        __syncthreads();
        part[t] += v;
        __syncthreads();
    }
    const int pre = (t == 0) ? 0 : part[t - 1];
    #pragma unroll
    for (int j = 0; j < 20; ++j) {
        int idx = base + j;
        if (idx < NNODES) rowptr[idx] = pre + vals[j];
    }
    if (t == 0) rowptr[NNODES] = NEDGES;
}

__global__ void scatter_kernel(
    const int* __restrict__ src, const int* __restrict__ dst,
    const int* __restrict__ rowptr, int* __restrict__ fill,
    int* __restrict__ seid, unsigned short* __restrict__ ssrc,
    unsigned short* __restrict__ sdst)
{
    int i = blockIdx.x * blockDim.x + threadIdx.x;
    if (i < NEDGES) {
        int d = min(max(dst[i], 0), NNODES - 1);
        int s = min(max(src[i], 0), NNODES - 1);
        int pos = rowptr[d] + atomicAdd(&fill[d], 1);
        seid[pos] = i;
        ssrc[pos] = (unsigned short)s;
        sdst[pos] = (unsigned short)d;
    }
}

// ---------------- one MFMA layer phase (single plane-pair source) ----------------
// Wave owns ONE col-block rb and BOTH edge-groups. W: global, depth-4 ring; B: LDS depth-2.
template<int NKS>
static __device__ inline void run_phase(
    const uint4* __restrict__ wf, int rb, int l, int g, int e0, int e1,
    const uint* __restrict__ PH, const uint* __restrict__ PL,
    Acc& aA0, Acc& aB0, Acc& aA1, Acc& aB1)
{
    Frag wbuf[4][2];   // [slot][hi/lo]
    Frag bbuf[2][4];   // [slot][bh0, bl0, bh1, bl1]
    auto loadW = [&](int ks, int slot) {
        const uint4* wbase = wf + (size_t)(ks * 4 + rb) * 2 * 64;
        wbuf[slot][0].q = wbase[l];
        wbuf[slot][1].q = wbase[64 + l];
    };
    auto loadB = [&](int ks, int slot) {
        const int sl = ((ks * 16 + 8 * g) >> 3);
        const int bo0 = e0 * 64 + ((sl ^ (e0 & 15)) << 2);
        const int bo1 = e1 * 64 + ((sl ^ (e1 & 15)) << 2);
        bbuf[slot][0].q = *(const uint4*)&PH[bo0];
        bbuf[slot][1].q = *(const uint4*)&PL[bo0];
        bbuf[slot][2].q = *(const uint4*)&PH[bo1];
        bbuf[slot][3].q = *(const uint4*)&PL[bo1];
    };
    loadW(0, 0);
    loadB(0, 0);
    if (NKS > 1) loadW(1, 1);
    if (NKS > 2) loadW(2, 2);
    if (NKS > 3) loadW(3, 3);
    #pragma unroll
    for (int ks = 0; ks < NKS; ++ks) {
        if (ks + 1 < NKS) loadB(ks + 1, (ks + 1) & 1);
        Frag& ah  = wbuf[ks & 3][0];
        Frag& al  = wbuf[ks & 3][1];
        Frag& bh0 = bbuf[ks & 1][0];
        Frag& bl0 = bbuf[ks & 1][1];
        Frag& bh1 = bbuf[ks & 1][2];
        Frag& bl1 = bbuf[ks & 1][3];
        __builtin_amdgcn_s_setprio(1);
        aA0.v = MFMA(ah.s, bh0.s, aA0.v);
        aA1.v = MFMA(ah.s, bh1.s, aA1.v);
        aB0.v = MFMA(ah.s, bl0.s, aB0.v);
        aB1.v = MFMA(ah.s, bl1.s, aB1.v);
        aA0.v = MFMA(al.s, bh0.s, aA0.v);
        aA1.v = MFMA(al.s, bh1.s, aA1.v);
        __builtin_amdgcn_s_setprio(0);
        if (ks + 4 < NKS) loadW(ks + 4, ks & 3);   // refill just-freed slot
    }
}

// epilogue: bias (+relu), split hi/lo, store into planes
static __device__ inline void epi_store(
    uint* __restrict__ PH, uint* __restrict__ PL, int rb, int e, int g,
    const Acc& aA, const Acc& aB, const float* __restrict__ bias, bool relu)
{
    #pragma unroll
    for (int q = 0; q < 4; ++q) {
        const int c0 = rb * 32 + q * 8 + 4 * g;
        const float4 bv = *(const float4*)&bias[c0];
        float v0 = aA.f[q*4+0] + aB.f[q*4+0] + bv.x;
        float v1 = aA.f[q*4+1] + aB.f[q*4+1] + bv.y;
        float v2 = aA.f[q*4+2] + aB.f[q*4+2] + bv.z;
        float v3 = aA.f[q*4+3] + aB.f[q*4+3] + bv.w;
        if (relu) { v0 = fmaxf(v0, 0.f); v1 = fmaxf(v1, 0.f); v2 = fmaxf(v2, 0.f); v3 = fmaxf(v3, 0.f); }
        uint2 hi, lo;
        pack4(v0, v1, v2, v3, hi, lo);
        const int off = e * 64 + ((((c0 >> 3) ^ (e & 15))) << 2) + g * 2;
        *(uint2*)&PH[off] = hi;
        *(uint2*)&PL[off] = lo;
    }
}

// ---------------- MFMA message kernel: 32 KB time-shared LDS, 64 edges/block ----------------
// launch_bounds(256, 2): VGPR budget 256 -> NO occupancy-driven spill (round-7 lesson).
// Occupancy comes from the 34 KB LDS footprint (3-4 blocks/CU if VGPR <= 170/128).
__global__ __launch_bounds__(256, 2) void msg_mfma_s(
    const float* __restrict__ node,
    const float* __restrict__ edge_attr,
    const float* __restrict__ eW1, const float* __restrict__ eb1,
    const float* __restrict__ eb2,
    const uint4* __restrict__ ewfrag,
    const uint4* __restrict__ wfrag,
    const int* __restrict__ seidg,
    const unsigned short* __restrict__ ssrcg,
    const unsigned short* __restrict__ sdstg,
    const float* __restrict__ gb1, const float* __restrict__ b2,
    const float* __restrict__ b3,
    float* __restrict__ agg)
{
    __shared__ uint4 pool4[2048];        // 32 KB: HH|HL planes / Mf fp32 overlay
    __shared__ float eas[192];
    __shared__ int ssrc[64], sdst[64], seid[64];
    uint* HH = (uint*)pool4;
    uint* HL = (uint*)(pool4 + 1024);
    float* Mf = (float*)pool4;

    const int t   = threadIdx.x;
    const int wv  = t >> 6;
    const int l   = t & 63;
    const int l31 = l & 31;
    const int g   = l >> 5;
    const int rb  = wv;                  // wave owns one col block
    const int e0  = l31;                 // edge-group 0
    const int e1  = 32 + l31;            // edge-group 1
    const int eb0 = blockIdx.x * 64;

    if (t < 64)       ssrc[t]       = ssrcg[eb0 + t];
    else if (t < 128) sdst[t - 64]  = sdstg[eb0 + (t - 64)];
    else if (t < 192) seid[t - 128] = seidg[eb0 + (t - 128)];
    __syncthreads();

    // T14: issue x_j gathers into registers now; consumed at L1a pack
    float4 xreg[8];
    #pragma unroll
    for (int i = 0; i < 8; ++i) {
        const int idx = i * 256 + t;
        const int ee = idx >> 5, q = idx & 31;
        xreg[i] = *(const float4*)&node[(size_t)ssrc[ee] * HID + q * 4];
    }
    if (t < 192) eas[t] = edge_attr[(size_t)seid[t / 3] * 3 + (t % 3)];
    __syncthreads();

    // h1e = relu(ea @ eW1 + eb1) on VALU -> HH/HL
    {
        const int ee = t & 63, sb = t >> 6;
        const float a0 = eas[ee * 3 + 0], a1 = eas[ee * 3 + 1], a2 = eas[ee * 3 + 2];
        #pragma unroll
        for (int i = 0; i < 8; ++i) {
            const int s4 = sb + 4 * i;
            const int c0 = s4 * 4;
            const float4 w1 = *(const float4*)&eW1[0 * HID + c0];
            const float4 w2 = *(const float4*)&eW1[1 * HID + c0];
            const float4 w3 = *(const float4*)&eW1[2 * HID + c0];
            const float4 bb = *(const float4*)&eb1[c0];
            const float v0 = fmaxf(bb.x + a0 * w1.x + a1 * w2.x + a2 * w3.x, 0.f);
            const float v1 = fmaxf(bb.y + a0 * w1.y + a1 * w2.y + a2 * w3.y, 0.f);
            const float v2 = fmaxf(bb.z + a0 * w1.z + a1 * w2.z + a2 * w3.z, 0.f);
            const float v3 = fmaxf(bb.w + a0 * w1.w + a1 * w2.w + a2 * w3.w, 0.f);
            uint2 hi, lo;
            pack4(v0, v1, v2, v3, hi, lo);
            const int off = ee * 64 + ((((s4 >> 1) ^ (ee & 15))) << 2) + (s4 & 1) * 2;
            *(uint2*)&HH[off] = hi;
            *(uint2*)&HL[off] = lo;
        }
    }
    __syncthreads();

    Acc aA0, aB0, aA1, aB1;
#define ZACC() do { _Pragma("unroll") \
    for (int z = 0; z < 16; ++z) { aA0.f[z] = 0.f; aB0.f[z] = 0.f; aA1.f[z] = 0.f; aB1.f[z] = 0.f; } } while (0)

    // ---- edge L2: h2e = relu(h1e @ eW2 + eb2)  (H -> H) ----
    ZACC();
    run_phase<8>(ewfrag, rb, l, g, e0, e1, HH, HL, aA0, aB0, aA1, aB1);
    __syncthreads();
    epi_store(HH, HL, rb, e0, g, aA0, aB0, eb2, true);
    epi_store(HH, HL, rb, e1, g, aA1, aB1, eb2, true);
    __syncthreads();

    // ---- L1b: acc += h2e @ Wc_lower  (k = 128..255 half) ----
    ZACC();
    run_phase<8>(wfrag + 4096, rb, l, g, e0, e1, HH, HL, aA0, aB0, aA1, aB1);
    __syncthreads();
    // pack x_j into planes (h2e dead)
    #pragma unroll
    for (int i = 0; i < 8; ++i) {
        const int idx = i * 256 + t;
        const int ee = idx >> 5, q = idx & 31;
        uint2 hi, lo;
        pack4(xreg[i].x, xreg[i].y, xreg[i].z, xreg[i].w, hi, lo);
        const int off = ee * 64 + ((((q >> 1) ^ (ee & 15))) << 2) + (q & 1) * 2;
        *(uint2*)&HH[off] = hi;
        *(uint2*)&HL[off] = lo;
    }
    __syncthreads();

    // ---- L1a: acc += x_j @ Wc_upper  (k = 0..127 half; same accumulators) ----
    run_phase<8>(wfrag, rb, l, g, e0, e1, HH, HL, aA0, aB0, aA1, aB1);
    __syncthreads();
    epi_store(HH, HL, rb, e0, g, aA0, aB0, gb1, true);
    epi_store(HH, HL, rb, e1, g, aA1, aB1, gb1, true);
    __syncthreads();

    // ---- L2: h2 = relu(h1 @ W2 + b2)  (H -> H) ----
    ZACC();
    run_phase<8>(wfrag + 8192, rb, l, g, e0, e1, HH, HL, aA0, aB0, aA1, aB1);
    __syncthreads();
    epi_store(HH, HL, rb, e0, g, aA0, aB0, b2, true);
    epi_store(HH, HL, rb, e1, g, aA1, aB1, b2, true);
    __syncthreads();

    // ---- L3: msg = h2 @ W3 + b3 -> Mf (fp32 overlay on planes) ----
    ZACC();
    run_phase<8>(wfrag + 12288, rb, l, g, e0, e1, HH, HL, aA0, aB0, aA1, aB1);
    __syncthreads();     // all reads of h2 done before fp32 overlay
    #pragma unroll
    for (int q = 0; q < 4; ++q) {
        const int c0 = rb * 32 + q * 8 + 4 * g;
        const float4 bva = *(const float4*)&b3[c0];
        float4 v0;
        v0.x = aA0.f[q*4+0] + aB0.f[q*4+0] + bva.x;
        v0.y = aA0.f[q*4+1] + aB0.f[q*4+1] + bva.y;
        v0.z = aA0.f[q*4+2] + aB0.f[q*4+2] + bva.z;
        v0.w = aA0.f[q*4+3] + aB0.f[q*4+3] + bva.w;
        *(float4*)&Mf[e0 * 128 + (c0 ^ ((e0 & 7) << 2))] = v0;
        float4 v1;
        v1.x = aA1.f[q*4+0] + aB1.f[q*4+0] + bva.x;
        v1.y = aA1.f[q*4+1] + aB1.f[q*4+1] + bva.y;
        v1.z = aA1.f[q*4+2] + aB1.f[q*4+2] + bva.z;
        v1.w = aA1.f[q*4+3] + aB1.f[q*4+3] + bva.w;
        *(float4*)&Mf[e1 * 128 + (c0 ^ ((e1 & 7) << 2))] = v1;
    }
#undef ZACC
    __syncthreads();

    // ---- segmented sum over sorted dst (float4, 16-edge segments, 128 threads) ----
    if (t < 128) {
        const int grp = t & 31;          // channel group: c0 = grp*4
        const int seg = t >> 5;          // 0..3
        const int c0  = grp << 2;
        const int es  = seg * 16;
        float4 run = make_float4(0.f, 0.f, 0.f, 0.f);
        int cur = sdst[es];
        for (int e2 = es; e2 < es + 16; ++e2) {
            const int d2 = sdst[e2];
            const float4 v = *(const float4*)&Mf[e2 * 128 + (c0 ^ ((e2 & 7) << 2))];
            if (d2 != cur) {
                float* ap = &agg[(size_t)cur * HID + c0];
                atomicAdd(ap + 0, run.x);
                atomicAdd(ap + 1, run.y);
                atomicAdd(ap + 2, run.z);
                atomicAdd(ap + 3, run.w);
                run = make_float4(0.f, 0.f, 0.f, 0.f);
                cur = d2;
            }
            run.x += v.x; run.y += v.y; run.z += v.z; run.w += v.w;
        }
        float* ap = &agg[(size_t)cur * HID + c0];
        atomicAdd(ap + 0, run.x);
        atomicAdd(ap + 1, run.y);
        atomicAdd(ap + 2, run.z);
        atomicAdd(ap + 3, run.w);
    }
}

// ---------------- residual update (fast path: denom from rowptr); re-zero agg ----------------
__global__ void update_kernel_csr(float* __restrict__ node, float* __restrict__ agg,
                                  const int* __restrict__ rowptr)
{
    int i = blockIdx.x * blockDim.x + threadIdx.x;
    if (i < NNODES * HID) {
        int n = i >> 7;
        float cnt = (float)(rowptr[n + 1] - rowptr[n]);
        node[i] += agg[i] / fmaxf(cnt, 1.0f);
        agg[i] = 0.f;
    }
}

// ---------------- decoder: 128->128->128->2 ----------------
__global__ __launch_bounds__(128) void decoder_kernel(
    const float* __restrict__ node,
    const float* __restrict__ W1, const float* __restrict__ b1,
    const float* __restrict__ W2, const float* __restrict__ b2,
    const float* __restrict__ W3, const float* __restrict__ b3,
    float* __restrict__ out)
{
    __shared__ float xs[16][HID];
    __shared__ float h1[16][HID];
    __shared__ float h2[16][HID];
    const int t = threadIdx.x;
    const int base = blockIdx.x * 16;

    for (int i = t; i < 16 * 32; i += 128) {
        int e = i >> 5, c = (i & 31) << 2;
        *(float4*)&xs[e][c] = *(const float4*)&node[(size_t)(base + e) * HID + c];
    }
    __syncthreads();
    {
        const float bb = b1[t];
        for (int e = 0; e < 16; ++e) {
            float acc = bb;
            for (int k = 0; k < HID; ++k) acc += xs[e][k] * W1[k * HID + t];
            h1[e][t] = fmaxf(acc, 0.f);
        }
    }
    __syncthreads();
    {
        const float bb = b2[t];
        for (int e = 0; e < 16; ++e) {
            float acc = bb;
            for (int k = 0; k < HID; ++k) acc += h1[e][k] * W2[k * HID + t];
            h2[e][t] = fmaxf(acc, 0.f);
        }
    }
    __syncthreads();
    if (t < 32) {
        const int e = t >> 1, o = t & 1;
        float acc = b3[o];
        for (int k = 0; k < HID; ++k) acc += h2[e][k] * W3[k * 2 + o];
        out[(size_t)(base + e) * 2 + o] = acc;
    }
}

// ================= fallback (RECOMP fp32 path, proven rounds 2-3) =================
__global__ void degree_kernel(const int* __restrict__ dst, float* __restrict__ cnt)
{
    int i = blockIdx.x * blockDim.x + threadIdx.x;
    if (i < NEDGES) {
        int d = min(max(dst[i], 0), NNODES - 1);
        atomicAdd(&cnt[d], 1.0f);
    }
}

__global__ void update_kernel_cnt(float* __restrict__ node, float* __restrict__ agg,
                                  const float* __restrict__ cnt)
{
    int i = blockIdx.x * blockDim.x + threadIdx.x;
    if (i < NNODES * HID) {
        int n = i >> 7;
        node[i] += agg[i] / fmaxf(cnt[n], 1.0f);
        agg[i] = 0.f;
    }
}

__global__ __launch_bounds__(128) void fuse_kernel(
    const float* __restrict__ eW3, const float* __restrict__ eb3,
    const float* __restrict__ pW1, const float* __restrict__ pb1,
    float* __restrict__ Wc, float* __restrict__ g)
{
    const int l = blockIdx.x >> 3;
    const int s = blockIdx.x & 7;
    const int c = threadIdx.x;
    const float* W1l = pW1 + (size_t)l * 2 * HID * HID;
    float* Wcl = Wc + (size_t)l * 2 * HID * HID;

    for (int r = s * 16; r < s * 16 + 16; ++r)
        Wcl[r * HID + c] = W1l[r * HID + c];

    for (int m = s * 16; m < s * 16 + 16; ++m) {
        float a0 = 0.f, a1 = 0.f, a2 = 0.f, a3 = 0.f;
        for (int k = 0; k < HID; k += 4) {
            a0 += eW3[m * HID + k + 0] * W1l[(HID + k + 0) * HID + c];
            a1 += eW3[m * HID + k + 1] * W1l[(HID + k + 1) * HID + c];
            a2 += eW3[m * HID + k + 2] * W1l[(HID + k + 2) * HID + c];
            a3 += eW3[m * HID + k + 3] * W1l[(HID + k + 3) * HID + c];
        }
        Wcl[(HID + m) * HID + c] = (a0 + a1) + (a2 + a3);
    }
    if (s == 0) {
        float a = pb1[l * HID + c];
        for (int k = 0; k < HID; ++k)
            a += eb3[k] * W1l[(HID + k) * HID + c];
        g[l * HID + c] = a;
    }
}

__global__ __launch_bounds__(256) void msg_recomp(
    const float* __restrict__ node,
    const float* __restrict__ edge_attr,
    const float* __restrict__ eW1, const float* __restrict__ eb1,
    const float* __restrict__ eW2, const float* __restrict__ eb2,
    const int* __restrict__ src_idx, const int* __restrict__ dst_idx,
    const float* __restrict__ W1, const float* __restrict__ b1,
    const float* __restrict__ W2, const float* __restrict__ b2,
    const float* __restrict__ W3, const float* __restrict__ b3,
    float* __restrict__ agg)
{
    __shared__ float X[32][256];
    __shared__ float H[32][HID];
    __shared__ int ssrc[32];
    __shared__ int sdst[32];
    __shared__ float ea_s[32][4];

    const int t = threadIdx.x;
    const int eb = blockIdx.x * 32;

    if (t < 32) { int s = src_idx[eb + t]; ssrc[t] = min(max(s, 0), NNODES - 1); }
    else if (t < 64) { int d = dst_idx[eb + (t - 32)]; sdst[t - 32] = min(max(d, 0), NNODES - 1); }
    __syncthreads();

    for (int i = t; i < 32 * 32; i += 256) {
        int e = i >> 5; int c = (i & 31) << 2;
        *(float4*)&X[e][c] = *(const float4*)&node[(size_t)ssrc[e] * HID + c];
    }
    for (int i = t; i < 32 * 3; i += 256)
        ea_s[i / 3][i % 3] = edge_attr[(size_t)(eb + i / 3) * 3 + (i % 3)];
    __syncthreads();

    const int ct = t & 31;
    const int et = (t >> 5) << 2;
    const int cb = ct << 2;
    float acc[4][4];

    {
        const float4 bv = *(const float4*)&eb1[cb];
        #pragma unroll
        for (int j = 0; j < 4; ++j) { acc[j][0] = bv.x; acc[j][1] = bv.y; acc[j][2] = bv.z; acc[j][3] = bv.w; }
        #pragma unroll
        for (int k = 0; k < 3; ++k) {
            const float4 wv = *(const float4*)&eW1[k * HID + cb];
            #pragma unroll
            for (int j = 0; j < 4; ++j) {
                const float xx = ea_s[et + j][k];
                acc[j][0] += xx * wv.x; acc[j][1] += xx * wv.y; acc[j][2] += xx * wv.z; acc[j][3] += xx * wv.w;
            }
        }
        #pragma unroll
        for (int j = 0; j < 4; ++j)
            *(float4*)&H[et + j][cb] = make_float4(fmaxf(acc[j][0],0.f), fmaxf(acc[j][1],0.f), fmaxf(acc[j][2],0.f), fmaxf(acc[j][3],0.f));
    }
    __syncthreads();
    {
        const float4 bv = *(const float4*)&eb2[cb];
        #pragma unroll
        for (int j = 0; j < 4; ++j) { acc[j][0] = bv.x; acc[j][1] = bv.y; acc[j][2] = bv.z; acc[j][3] = bv.w; }
        for (int k = 0; k < HID; ++k) {
            const float4 wv = *(const float4*)&eW2[k * HID + cb];
            const float x0 = H[et+0][k], x1 = H[et+1][k], x2 = H[et+2][k], x3 = H[et+3][k];
            acc[0][0]+=x0*wv.x; acc[0][1]+=x0*wv.y; acc[0][2]+=x0*wv.z; acc[0][3]+=x0*wv.w;
            acc[1][0]+=x1*wv.x; acc[1][1]+=x1*wv.y; acc[1][2]+=x1*wv.z; acc[1][3]+=x1*wv.w;
            acc[2][0]+=x2*wv.x; acc[2][1]+=x2*wv.y; acc[2][2]+=x2*wv.z; acc[2][3]+=x2*wv.w;
            acc[3][0]+=x3*wv.x; acc[3][1]+=x3*wv.y; acc[3][2]+=x3*wv.z; acc[3][3]+=x3*wv.w;
        }
        #pragma unroll
        for (int j = 0; j < 4; ++j)
            *(float4*)&X[et + j][HID + cb] = make_float4(fmaxf(acc[j][0],0.f), fmaxf(acc[j][1],0.f), fmaxf(acc[j][2],0.f), fmaxf(acc[j][3],0.f));
    }
    __syncthreads();
    {
        const float4 bv = *(const float4*)&b1[cb];
        #pragma unroll
        for (int j = 0; j < 4; ++j) { acc[j][0] = bv.x; acc[j][1] = bv.y; acc[j][2] = bv.z; acc[j][3] = bv.w; }
        for (int k = 0; k < 256; ++k) {
            const float4 wv = *(const float4*)&W1[k * HID + cb];
            const float x0 = X[et+0][k], x1 = X[et+1][k], x2 = X[et+2][k], x3 = X[et+3][k];
            acc[0][0]+=x0*wv.x; acc[0][1]+=x0*wv.y; acc[0][2]+=x0*wv.z; acc[0][3]+=x0*wv.w;
            acc[1][0]+=x1*wv.x; acc[1][1]+=x1*wv.y; acc[1][2]+=x1*wv.z; acc[1][3]+=x1*wv.w;
            acc[2][0]+=x2*wv.x; acc[2][1]+=x2*wv.y; acc[2][2]+=x2*wv.z; acc[2][3]+=x2*wv.w;
            acc[3][0]+=x3*wv.x; acc[3][1]+=x3*wv.y; acc[3][2]+=x3*wv.z; acc[3][3]+=x3*wv.w;
        }
        __syncthreads();
        #pragma unroll
        for (int j = 0; j < 4; ++j)
            *(float4*)&H[et + j][cb] = make_float4(fmaxf(acc[j][0],0.f), fmaxf(acc[j][1],0.f), fmaxf(acc[j][2],0.f), fmaxf(acc[j][3],0.f));
    }
    __syncthreads();
    float* Xf = &X[0][0];
    {
        const float4 bv = *(const float4*)&b2[cb];
        #pragma unroll
        for (int j = 0; j < 4; ++j) { acc[j][0] = bv.x; acc[j][1] = bv.y; acc[j][2] = bv.z; acc[j][3] = bv.w; }
        for (int k = 0; k < HID; ++k) {
            const float4 wv = *(const float4*)&W2[k * HID + cb];
            const float x0 = H[et+0][k], x1 = H[et+1][k], x2 = H[et+2][k], x3 = H[et+3][k];
            acc[0][0]+=x0*wv.x; acc[0][1]+=x0*wv.y; acc[0][2]+=x0*wv.z; acc[0][3]+=x0*wv.w;
            acc[1][0]+=x1*wv.x; acc[1][1]+=x1*wv.y; acc[1][2]+=x1*wv.z; acc[1][3]+=x1*wv.w;
            acc[2][0]+=x2*wv.x; acc[2][1]+=x2*wv.y; acc[2][2]+=x2*wv.z; acc[2][3]+=x2*wv.w;
            acc[3][0]+=x3*wv.x; acc[3][1]+=x3*wv.y; acc[3][2]+=x3*wv.z; acc[3][3]+=x3*wv.w;
        }
        #pragma unroll
        for (int j = 0; j < 4; ++j)
            *(float4*)&Xf[(et + j) * HID + cb] = make_float4(fmaxf(acc[j][0],0.f), fmaxf(acc[j][1],0.f), fmaxf(acc[j][2],0.f), fmaxf(acc[j][3],0.f));
    }
    __syncthreads();
    {
        const float4 bv = *(const float4*)&b3[cb];
        #pragma unroll
        for (int j = 0; j < 4; ++j) { acc[j][0] = bv.x; acc[j][1] = bv.y; acc[j][2] = bv.z; acc[j][3] = bv.w; }
        for (int k = 0; k < HID; ++k) {
            const float4 wv = *(const float4*)&W3[k * HID + cb];
            const float x0 = Xf[(et+0)*HID+k], x1 = Xf[(et+1)*HID+k];
            const float x2 = Xf[(et+2)*HID+k], x3 = Xf[(et+3)*HID+k];
            acc[0][0]+=x0*wv.x; acc[0][1]+=x0*wv.y; acc[0][2]+=x0*wv.z; acc[0][3]+=x0*wv.w;
            acc[1][0]+=x1*wv.x; acc[1][1]+=x1*wv.y; acc[1][2]+=x1*wv.z; acc[1][3]+=x1*wv.w;
            acc[2][0]+=x2*wv.x; acc[2][1]+=x2*wv.y; acc[2][2]+=x2*wv.z; acc[2][3]+=x2*wv.w;
            acc[3][0]+=x3*wv.x; acc[3][1]+=x3*wv.y; acc[3][2]+=x3*wv.z; acc[3][3]+=x3*wv.w;
        }
        #pragma unroll
        for (int j = 0; j < 4; ++j) {
            const int d = sdst[et + j];
            float* ap = &agg[(size_t)d * HID + cb];
            atomicAdd(ap + 0, acc[j][0]);
            atomicAdd(ap + 1, acc[j][1]);
            atomicAdd(ap + 2, acc[j][2]);
            atomicAdd(ap + 3, acc[j][3]);
        }
    }
}

extern "C" void kernel_launch(void* const* d_in, const int* in_sizes, int n_in,
                              void* d_out, int out_size, void* d_ws, size_t ws_size,
                              hipStream_t stream)
{
    const float* x         = (const float*)d_in[0];
    const float* edge_attr = (const float*)d_in[1];
    const float* nW1 = (const float*)d_in[2];  const float* nb1 = (const float*)d_in[3];
    const float* nW2 = (const float*)d_in[4];  const float* nb2 = (const float*)d_in[5];
    const float* nW3 = (const float*)d_in[6];  const float* nb3 = (const float*)d_in[7];
    const float* eW1 = (const float*)d_in[8];  const float* eb1 = (const float*)d_in[9];
    const float* eW2 = (const float*)d_in[10]; const float* eb2 = (const float*)d_in[11];
    const float* eW3 = (const float*)d_in[12]; const float* eb3 = (const float*)d_in[13];
    const float* pW1 = (const float*)d_in[14]; const float* pb1 = (const float*)d_in[15];
    const float* pW2 = (const float*)d_in[16]; const float* pb2 = (const float*)d_in[17];
    const float* pW3 = (const float*)d_in[18]; const float* pb3 = (const float*)d_in[19];
    const float* dW1 = (const float*)d_in[20]; const float* db1 = (const float*)d_in[21];
    const float* dW2 = (const float*)d_in[22]; const float* db2 = (const float*)d_in[23];
    const float* dW3 = (const float*)d_in[24]; const float* db3 = (const float*)d_in[25];
    const int* ei  = (const int*)d_in[26];
    const int* src = ei;
    const int* dst = ei + NEDGES;

    // fast-path workspace layout (bytes)
    char* ws = (char*)d_ws;
    float* node    = (float*)(ws);                     // 10,240,000
    float* agg     = (float*)(ws + 10240000);          // 10,240,000
    int*   cnt_i   = (int*)  (ws + 20480000);          //     80,000
    int*   fill    = (int*)  (ws + 20560000);          //     80,000
    int*   rowptr  = (int*)  (ws + 20640000);          //     80,064 (20001 ints, padded)
    float* gb      = (float*)(ws + 20720064);          //      5,120
    uint4* wfrag   = (uint4*)(ws + 20725184);          //  2,621,440
    uint4* ewf     = (uint4*)(ws + 23346624);          //     65,536
    int*   seid    = (int*)  (ws + 23412160);          //  2,560,000
    unsigned short* ssrc16 = (unsigned short*)(ws + 25972160);  // 1,280,000
    unsigned short* sdst16 = (unsigned short*)(ws + 27252160);  // 1,280,000
    const size_t NEED_FAST = 28532160ull;

    // fallback layout (proven fits)
    float* cntf = (float*)(ws + 20480000);
    float* Wc   = (float*)(ws + 20560000);
    float* gb2  = (float*)(ws + 21870720);

    const bool fast = (ws_size >= NEED_FAST);

    encoder_kernel<16, 2><<<NNODES / 16, 128, 0, stream>>>(
        x, nW1, nb1, nW2, nb2, nW3, nb3, node, NNODES);

    if (fast) {
        // zero agg + cnt_i + fill (contiguous)
        hipMemsetAsync(ws + 10240000, 0, 10240000 + 160000, stream);

        hist_kernel<<<(NEDGES + 255) / 256, 256, 0, stream>>>(dst, cnt_i);
        scan_kernel<<<1, 1024, 0, stream>>>(cnt_i, rowptr);
        scatter_kernel<<<(NEDGES + 255) / 256, 256, 0, stream>>>(
            src, dst, rowptr, fill, seid, ssrc16, sdst16);

        wprep_kernel<<<(NSTEPS * 16384 + 4096) / 256, 256, 0, stream>>>(
            eW3, pW1, pW2, pW3, eW2, wfrag);
        gfuse_kernel<<<NSTEPS, 128, 0, stream>>>(eb3, pW1, pb1, gb);

        for (int l = 0; l < NSTEPS; ++l) {
            msg_mfma_s<<<NEDGES / 64, 256, 0, stream>>>(
                node, edge_attr, eW1, eb1, eb2,
                ewf, wfrag + (size_t)l * 16384,
                seid, ssrc16, sdst16,
                gb + l * HID, pb2 + l * HID, pb3 + l * HID, agg);
            update_kernel_csr<<<(NNODES * HID) / 256, 256, 0, stream>>>(node, agg, rowptr);
        }
    } else {
        hipMemsetAsync(ws + 10240000, 0, 10240000 + 80000, stream);
        degree_kernel<<<(NEDGES + 255) / 256, 256, 0, stream>>>(dst, cntf);
        fuse_kernel<<<NSTEPS * 8, 128, 0, stream>>>(eW3, eb3, pW1, pb1, Wc, gb2);
        for (int l = 0; l < NSTEPS; ++l) {
            msg_recomp<<<NEDGES / 32, 256, 0, stream>>>(
                node, edge_attr, eW1, eb1, eW2, eb2, src, dst,
                Wc + (size_t)l * 2 * HID * HID,  gb2 + l * HID,
                pW2 + (size_t)l * HID * HID,     pb2 + l * HID,
                pW3 + (size_t)l * HID * HID,     pb3 + l * HID,
                agg);
            update_kernel_cnt<<<(NNODES * HID) / 256, 256, 0, stream>>>(node, agg, cntf);
        }
    }

    decoder_kernel<<<NNODES / 16, 128, 0, stream>>>(
        node, dW1, db1, dW2, db2, dW3, db3, (float*)d_out);
}

// Round 9
// 3565.072 us; speedup vs baseline: 1.2625x; 1.0480x over previous
//
#include <hip/hip_runtime.h>

#define HID     128
#define NNODES  20000
#define NEDGES  640000
#define NSTEPS  10

typedef __attribute__((ext_vector_type(8)))  short short8;
typedef __attribute__((ext_vector_type(16))) float f32x16;

union Frag { short8 s; uint4 q; uint u[4]; };
union Acc  { f32x16 v; float f[16]; };

#define MFMA(a,b,c) __builtin_amdgcn_mfma_f32_32x32x16_bf16((a),(b),(c),0,0,0)

// split 4 fp32 into bf16 hi-plane pair-u32s and lo-plane pair-u32s
static __device__ inline void pack4(const float v0, const float v1,
                                    const float v2, const float v3,
                                    uint2& hi, uint2& lo)
{
    const uint h0 = __float_as_uint(v0) & 0xFFFF0000u;
    const uint h1 = __float_as_uint(v1) & 0xFFFF0000u;
    const uint h2 = __float_as_uint(v2) & 0xFFFF0000u;
    const uint h3 = __float_as_uint(v3) & 0xFFFF0000u;
    hi.x = (h0 >> 16) | h1;
    hi.y = (h2 >> 16) | h3;
    lo.x = (__float_as_uint(v0 - __uint_as_float(h0)) >> 16)
         | (__float_as_uint(v1 - __uint_as_float(h1)) & 0xFFFF0000u);
    lo.y = (__float_as_uint(v2 - __uint_as_float(h2)) >> 16)
         | (__float_as_uint(v3 - __uint_as_float(h3)) & 0xFFFF0000u);
}

// ---------------- node encoder (KIN=16, skip first 2 feats) ----------------
template<int KIN, int KSTART>
__global__ __launch_bounds__(128) void encoder_kernel(
    const float* __restrict__ in,
    const float* __restrict__ W1, const float* __restrict__ b1,
    const float* __restrict__ W2, const float* __restrict__ b2,
    const float* __restrict__ W3, const float* __restrict__ b3,
    float* __restrict__ out, int n)
{
    __shared__ float xs[16][(KIN < 4) ? 4 : KIN];
    __shared__ float h1[16][HID];
    __shared__ float h2[16][HID];
    const int t = threadIdx.x;
    const int base = blockIdx.x * 16;

    for (int i = t; i < 16 * KIN; i += 128) {
        int e = i / KIN, k = i % KIN;
        int g = base + e;
        xs[e][k] = (g < n) ? in[(size_t)g * KIN + k] : 0.f;
    }
    __syncthreads();
    {
        const float bb = b1[t];
        for (int e = 0; e < 16; ++e) {
            float acc = bb;
            #pragma unroll
            for (int k = KSTART; k < KIN; ++k) acc += xs[e][k] * W1[k * HID + t];
            h1[e][t] = fmaxf(acc, 0.f);
        }
    }
    __syncthreads();
    {
        const float bb = b2[t];
        for (int e = 0; e < 16; ++e) {
            float acc = bb;
            for (int k = 0; k < HID; ++k) acc += h1[e][k] * W2[k * HID + t];
            h2[e][t] = fmaxf(acc, 0.f);
        }
    }
    __syncthreads();
    {
        const float bb = b3[t];
        for (int e = 0; e < 16; ++e) {
            int g = base + e;
            if (g >= n) continue;
            float acc = bb;
            for (int k = 0; k < HID; ++k) acc += h2[e][k] * W3[k * HID + t];
            out[(size_t)g * HID + t] = acc;
        }
    }
}

// ---------------- weight repack to A-frag layout (hi/lo planes) ----------------
__global__ __launch_bounds__(256) void wprep_kernel(
    const float* __restrict__ eW3,
    const float* __restrict__ pW1, const float* __restrict__ pW2,
    const float* __restrict__ pW3, const float* __restrict__ eW2,
    uint4* __restrict__ out)
{
    const int gid = blockIdx.x * 256 + threadIdx.x;
    if (gid >= NSTEPS * 16384 + 4096) return;

    int layer, rr, sid = 0;
    if (gid >= NSTEPS * 16384) { layer = 3; rr = gid - NSTEPS * 16384; }
    else {
        sid = gid / 16384;
        const int r = gid % 16384;
        if (r < 8192)       { layer = 0; rr = r; }
        else if (r < 12288) { layer = 1; rr = r - 8192; }
        else                { layer = 2; rr = r - 12288; }
    }
    const int ks  = rr >> 9;
    const int rem = rr & 511;
    const int rb  = rem >> 7;
    const int pl  = (rem >> 6) & 1;
    const int l   = rem & 63;
    const int c   = rb * 32 + (l & 31);
    const int k0  = ks * 16 + 8 * (l >> 5);

    float vals[8];
    if (layer == 0 && ks >= 8) {
        const float* W1l = pW1 + (size_t)sid * 2 * HID * HID;
        #pragma unroll
        for (int j = 0; j < 8; ++j) vals[j] = 0.f;
        const int kp = k0 - HID;
        for (int k = 0; k < HID; ++k) {
            const float wv = W1l[(size_t)(HID + k) * HID + c];
            #pragma unroll
            for (int j = 0; j < 8; ++j)
                vals[j] += eW3[(size_t)(kp + j) * HID + k] * wv;
        }
    } else {
        const float* Wsrc =
            (layer == 0) ? pW1 + (size_t)sid * 2 * HID * HID :
            (layer == 1) ? pW2 + (size_t)sid * HID * HID :
            (layer == 2) ? pW3 + (size_t)sid * HID * HID : eW2;
        #pragma unroll
        for (int j = 0; j < 8; ++j)
            vals[j] = Wsrc[(size_t)(k0 + j) * HID + c];
    }

    uint b16[8];
    #pragma unroll
    for (int j = 0; j < 8; ++j) {
        const uint hx = __float_as_uint(vals[j]) & 0xFFFF0000u;
        b16[j] = (pl == 0) ? (hx >> 16)
                           : (__float_as_uint(vals[j] - __uint_as_float(hx)) >> 16);
    }
    uint4 o;
    o.x = b16[0] | (b16[1] << 16);
    o.y = b16[2] | (b16[3] << 16);
    o.z = b16[4] | (b16[5] << 16);
    o.w = b16[6] | (b16[7] << 16);
    out[gid] = o;
}

// ---------------- fused L1 bias: g = pb1 + eb3 @ W1_lower ----------------
__global__ __launch_bounds__(128) void gfuse_kernel(
    const float* __restrict__ eb3, const float* __restrict__ pW1,
    const float* __restrict__ pb1, float* __restrict__ g)
{
    const int l = blockIdx.x, c = threadIdx.x;
    const float* W1l = pW1 + (size_t)l * 2 * HID * HID;
    float a = pb1[l * HID + c];
    for (int k = 0; k < HID; ++k)
        a += eb3[k] * W1l[(size_t)(HID + k) * HID + c];
    g[l * HID + c] = a;
}

// ---------------- CSR sort: histogram -> scan -> scatter ----------------
__global__ void hist_kernel(const int* __restrict__ dst, int* __restrict__ cnt)
{
    int i = blockIdx.x * blockDim.x + threadIdx.x;
    if (i < NEDGES) {
        int d = min(max(dst[i], 0), NNODES - 1);
        atomicAdd(&cnt[d], 1);
    }
}

__global__ __launch_bounds__(1024) void scan_kernel(
    const int* __restrict__ cnt, int* __restrict__ rowptr)
{
    __shared__ int part[1024];
    const int t = threadIdx.x;
    int vals[20];
    int s = 0;
    const int base = t * 20;
    #pragma unroll
    for (int j = 0; j < 20; ++j) {
        int idx = base + j;
        int v = (idx < NNODES) ? cnt[idx] : 0;
        vals[j] = s;
        s += v;
    }
    part[t] = s;
    __syncthreads();
    for (int off = 1; off < 1024; off <<= 1) {
        int v = (t >= off) ? part[t - off] : 0;
        __syncthreads();
        part[t] += v;
        __syncthreads();
    }
    const int pre = (t == 0) ? 0 : part[t - 1];
    #pragma unroll
    for (int j = 0; j < 20; ++j) {
        int idx = base + j;
        if (idx < NNODES) rowptr[idx] = pre + vals[j];
    }
    if (t == 0) rowptr[NNODES] = NEDGES;
}

__global__ void scatter_kernel(
    const int* __restrict__ src, const int* __restrict__ dst,
    const int* __restrict__ rowptr, int* __restrict__ fill,
    int* __restrict__ seid, unsigned short* __restrict__ ssrc,
    unsigned short* __restrict__ sdst)
{
    int i = blockIdx.x * blockDim.x + threadIdx.x;
    if (i < NEDGES) {
        int d = min(max(dst[i], 0), NNODES - 1);
        int s = min(max(src[i], 0), NNODES - 1);
        int pos = rowptr[d] + atomicAdd(&fill[d], 1);
        seid[pos] = i;
        ssrc[pos] = (unsigned short)s;
        sdst[pos] = (unsigned short)d;
    }
}

// ---------------- one MFMA layer phase ----------------
// Wave owns ONE col-block rb and FOUR 32-edge groups (e = gi*32 + l31).
// Single accumulator per group (3 same-acc MFMAs spaced 4 apart >= latency).
// W: global, depth-4 ring (2 uint4/ks). B: LDS, depth-2 (8 uint4/ks).
template<int NKS>
static __device__ inline void run_phase(
    const uint4* __restrict__ wf, int rb, int l, int g, int l31,
    const uint* __restrict__ PH, const uint* __restrict__ PL,
    Acc& ac0, Acc& ac1, Acc& ac2, Acc& ac3)
{
    Frag wbuf[4][2];
    Frag bh[2][4], bl[2][4];
    auto loadW = [&](int ks, int slot) {
        const uint4* wbase = wf + (size_t)(ks * 4 + rb) * 2 * 64;
        wbuf[slot][0].q = wbase[l];
        wbuf[slot][1].q = wbase[64 + l];
    };
    auto loadB = [&](int ks, int slot) {
        const int sl = ((ks * 16 + 8 * g) >> 3);
        const int bo = l31 * 64 + ((sl ^ (l31 & 15)) << 2);
        #pragma unroll
        for (int gi = 0; gi < 4; ++gi) {
            bh[slot][gi].q = *(const uint4*)&PH[bo + gi * 2048];
            bl[slot][gi].q = *(const uint4*)&PL[bo + gi * 2048];
        }
    };
    loadW(0, 0);
    loadB(0, 0);
    if (NKS > 1) loadW(1, 1);
    if (NKS > 2) loadW(2, 2);
    if (NKS > 3) loadW(3, 3);
    #pragma unroll
    for (int ks = 0; ks < NKS; ++ks) {
        if (ks + 1 < NKS) loadB(ks + 1, (ks + 1) & 1);
        Frag& ah = wbuf[ks & 3][0];
        Frag& al = wbuf[ks & 3][1];
        const int s = ks & 1;
        __builtin_amdgcn_s_setprio(1);
        ac0.v = MFMA(ah.s, bh[s][0].s, ac0.v);
        ac1.v = MFMA(ah.s, bh[s][1].s, ac1.v);
        ac2.v = MFMA(ah.s, bh[s][2].s, ac2.v);
        ac3.v = MFMA(ah.s, bh[s][3].s, ac3.v);
        ac0.v = MFMA(al.s, bh[s][0].s, ac0.v);
        ac1.v = MFMA(al.s, bh[s][1].s, ac1.v);
        ac2.v = MFMA(al.s, bh[s][2].s, ac2.v);
        ac3.v = MFMA(al.s, bh[s][3].s, ac3.v);
        ac0.v = MFMA(ah.s, bl[s][0].s, ac0.v);
        ac1.v = MFMA(ah.s, bl[s][1].s, ac1.v);
        ac2.v = MFMA(ah.s, bl[s][2].s, ac2.v);
        ac3.v = MFMA(ah.s, bl[s][3].s, ac3.v);
        __builtin_amdgcn_s_setprio(0);
        if (ks + 4 < NKS) loadW(ks + 4, ks & 3);   // refill just-freed slot
    }
}

// epilogue: bias (+relu), split hi/lo, store into planes
static __device__ inline void epi_store(
    uint* __restrict__ PH, uint* __restrict__ PL, int rb, int e, int g,
    const Acc& a, const float* __restrict__ bias, bool relu)
{
    #pragma unroll
    for (int q = 0; q < 4; ++q) {
        const int c0 = rb * 32 + q * 8 + 4 * g;
        const float4 bv = *(const float4*)&bias[c0];
        float v0 = a.f[q*4+0] + bv.x;
        float v1 = a.f[q*4+1] + bv.y;
        float v2 = a.f[q*4+2] + bv.z;
        float v3 = a.f[q*4+3] + bv.w;
        if (relu) { v0 = fmaxf(v0, 0.f); v1 = fmaxf(v1, 0.f); v2 = fmaxf(v2, 0.f); v3 = fmaxf(v3, 0.f); }
        uint2 hi, lo;
        pack4(v0, v1, v2, v3, hi, lo);
        const int off = e * 64 + ((((c0 >> 3) ^ (e & 15))) << 2) + g * 2;
        *(uint2*)&PH[off] = hi;
        *(uint2*)&PL[off] = lo;
    }
}

// ---------------- MFMA message kernel: 128 edges/block, 64 KB time-shared LDS ----------------
__global__ __launch_bounds__(256, 2) void msg_mfma_s(
    const float* __restrict__ node,
    const float* __restrict__ edge_attr,
    const float* __restrict__ eW1, const float* __restrict__ eb1,
    const float* __restrict__ eb2,
    const uint4* __restrict__ ewfrag,
    const uint4* __restrict__ wfrag,
    const int* __restrict__ seidg,
    const unsigned short* __restrict__ ssrcg,
    const unsigned short* __restrict__ sdstg,
    const float* __restrict__ gb1, const float* __restrict__ b2,
    const float* __restrict__ b3,
    float* __restrict__ agg)
{
    __shared__ uint4 pool4[4096];        // 64 KB: HH|HL planes / Mf fp32 overlay
    __shared__ float eas[384];
    __shared__ int ssrc[128], sdst[128], seid[128];
    uint* HH = (uint*)pool4;             // 8192 u32
    uint* HL = (uint*)(pool4 + 2048);    // 8192 u32
    float* Mf = (float*)pool4;           // 16384 f32 overlay

    const int t   = threadIdx.x;
    const int wv  = t >> 6;
    const int l   = t & 63;
    const int l31 = l & 31;
    const int g   = l >> 5;
    const int rb  = wv;                  // wave owns one col block
    const int eb0 = blockIdx.x * 128;

    if (t < 128) { ssrc[t] = ssrcg[eb0 + t]; seid[t] = seidg[eb0 + t]; }
    else         { sdst[t - 128] = sdstg[eb0 + (t - 128)]; }
    __syncthreads();

    for (int i = t; i < 384; i += 256)
        eas[i] = edge_attr[(size_t)seid[i / 3] * 3 + (i % 3)];
    __syncthreads();

    // h1e = relu(ea @ eW1 + eb1) on VALU -> planes
    {
        const int e = t & 127, sb = t >> 7;
        const float a0 = eas[e * 3 + 0], a1 = eas[e * 3 + 1], a2 = eas[e * 3 + 2];
        #pragma unroll
        for (int i = 0; i < 16; ++i) {
            const int s4 = sb * 16 + i;
            const int c0 = s4 * 4;
            const float4 w1 = *(const float4*)&eW1[0 * HID + c0];
            const float4 w2 = *(const float4*)&eW1[1 * HID + c0];
            const float4 w3 = *(const float4*)&eW1[2 * HID + c0];
            const float4 bb = *(const float4*)&eb1[c0];
            const float v0 = fmaxf(bb.x + a0 * w1.x + a1 * w2.x + a2 * w3.x, 0.f);
            const float v1 = fmaxf(bb.y + a0 * w1.y + a1 * w2.y + a2 * w3.y, 0.f);
            const float v2 = fmaxf(bb.z + a0 * w1.z + a1 * w2.z + a2 * w3.z, 0.f);
            const float v3 = fmaxf(bb.w + a0 * w1.w + a1 * w2.w + a2 * w3.w, 0.f);
            uint2 hi, lo;
            pack4(v0, v1, v2, v3, hi, lo);
            const int off = e * 64 + ((((s4 >> 1) ^ (e & 15))) << 2) + (s4 & 1) * 2;
            *(uint2*)&HH[off] = hi;
            *(uint2*)&HL[off] = lo;
        }
    }
    __syncthreads();

    Acc ac0, ac1, ac2, ac3;
#define ZACC() do { _Pragma("unroll") \
    for (int z = 0; z < 16; ++z) { ac0.f[z] = 0.f; ac1.f[z] = 0.f; ac2.f[z] = 0.f; ac3.f[z] = 0.f; } } while (0)
#define EPI4(BIAS, RELU) do { \
    epi_store(HH, HL, rb,  0 + l31, g, ac0, (BIAS), (RELU)); \
    epi_store(HH, HL, rb, 32 + l31, g, ac1, (BIAS), (RELU)); \
    epi_store(HH, HL, rb, 64 + l31, g, ac2, (BIAS), (RELU)); \
    epi_store(HH, HL, rb, 96 + l31, g, ac3, (BIAS), (RELU)); } while (0)

    // ---- edge L2: h2e = relu(h1e @ eW2 + eb2)  (planes -> planes) ----
    ZACC();
    run_phase<8>(ewfrag, rb, l, g, l31, HH, HL, ac0, ac1, ac2, ac3);
    __syncthreads();
    EPI4(eb2, true);
    __syncthreads();

    // ---- L1b: acc += h2e @ Wc_lower  (k = 128..255 half) ----
    ZACC();
    run_phase<8>(wfrag + 4096, rb, l, g, l31, HH, HL, ac0, ac1, ac2, ac3);
    __syncthreads();
    // pack x_j into planes (h2e dead); node rows re-gathered from L2/L3
    #pragma unroll
    for (int i = 0; i < 16; ++i) {
        const int idx = i * 256 + t;     // 4096 float4 slots: e = idx/32, q = idx%32
        const int ee = idx >> 5, q = idx & 31;
        const float4 v = *(const float4*)&node[(size_t)ssrc[ee] * HID + q * 4];
        uint2 hi, lo;
        pack4(v.x, v.y, v.z, v.w, hi, lo);
        const int off = ee * 64 + ((((q >> 1) ^ (ee & 15))) << 2) + (q & 1) * 2;
        *(uint2*)&HH[off] = hi;
        *(uint2*)&HL[off] = lo;
    }
    __syncthreads();

    // ---- L1a: acc += x_j @ Wc_upper  (same accumulators) ----
    run_phase<8>(wfrag, rb, l, g, l31, HH, HL, ac0, ac1, ac2, ac3);
    __syncthreads();
    EPI4(gb1, true);
    __syncthreads();

    // ---- L2: h2 = relu(h1 @ W2 + b2) ----
    ZACC();
    run_phase<8>(wfrag + 8192, rb, l, g, l31, HH, HL, ac0, ac1, ac2, ac3);
    __syncthreads();
    EPI4(b2, true);
    __syncthreads();

    // ---- L3: msg = h2 @ W3 + b3 -> Mf (fp32 overlay) ----
    ZACC();
    run_phase<8>(wfrag + 12288, rb, l, g, l31, HH, HL, ac0, ac1, ac2, ac3);
    __syncthreads();     // all reads of h2 done before fp32 overlay
    #pragma unroll
    for (int q = 0; q < 4; ++q) {
        const int c0 = rb * 32 + q * 8 + 4 * g;
        const float4 bva = *(const float4*)&b3[c0];
        const int sw = c0 ^ ((l31 & 7) << 2);
        float4 v0;
        v0.x = ac0.f[q*4+0] + bva.x; v0.y = ac0.f[q*4+1] + bva.y;
        v0.z = ac0.f[q*4+2] + bva.z; v0.w = ac0.f[q*4+3] + bva.w;
        *(float4*)&Mf[( 0 + l31) * 128 + sw] = v0;
        float4 v1;
        v1.x = ac1.f[q*4+0] + bva.x; v1.y = ac1.f[q*4+1] + bva.y;
        v1.z = ac1.f[q*4+2] + bva.z; v1.w = ac1.f[q*4+3] + bva.w;
        *(float4*)&Mf[(32 + l31) * 128 + sw] = v1;
        float4 v2;
        v2.x = ac2.f[q*4+0] + bva.x; v2.y = ac2.f[q*4+1] + bva.y;
        v2.z = ac2.f[q*4+2] + bva.z; v2.w = ac2.f[q*4+3] + bva.w;
        *(float4*)&Mf[(64 + l31) * 128 + sw] = v2;
        float4 v3;
        v3.x = ac3.f[q*4+0] + bva.x; v3.y = ac3.f[q*4+1] + bva.y;
        v3.z = ac3.f[q*4+2] + bva.z; v3.w = ac3.f[q*4+3] + bva.w;
        *(float4*)&Mf[(96 + l31) * 128 + sw] = v3;
    }
#undef ZACC
#undef EPI4
    __syncthreads();

    // ---- segmented sum over sorted dst (float4, 8 segs x 16 edges, 256 threads) ----
    {
        const int grp = t & 31;          // channel group: c0 = grp*4
        const int seg = t >> 5;          // 0..7
        const int c0  = grp << 2;
        const int es  = seg * 16;
        float4 run = make_float4(0.f, 0.f, 0.f, 0.f);
        int cur = sdst[es];
        for (int e2 = es; e2 < es + 16; ++e2) {
            const int d2 = sdst[e2];
            const float4 v = *(const float4*)&Mf[e2 * 128 + (c0 ^ ((e2 & 7) << 2))];
            if (d2 != cur) {
                float* ap = &agg[(size_t)cur * HID + c0];
                atomicAdd(ap + 0, run.x);
                atomicAdd(ap + 1, run.y);
                atomicAdd(ap + 2, run.z);
                atomicAdd(ap + 3, run.w);
                run = make_float4(0.f, 0.f, 0.f, 0.f);
                cur = d2;
            }
            run.x += v.x; run.y += v.y; run.z += v.z; run.w += v.w;
        }
        float* ap = &agg[(size_t)cur * HID + c0];
        atomicAdd(ap + 0, run.x);
        atomicAdd(ap + 1, run.y);
        atomicAdd(ap + 2, run.z);
        atomicAdd(ap + 3, run.w);
    }
}

// ---------------- residual update (fast path: denom from rowptr); re-zero agg ----------------
__global__ void update_kernel_csr(float* __restrict__ node, float* __restrict__ agg,
                                  const int* __restrict__ rowptr)
{
    int i = blockIdx.x * blockDim.x + threadIdx.x;
    if (i < NNODES * HID) {
        int n = i >> 7;
        float cnt = (float)(rowptr[n + 1] - rowptr[n]);
        node[i] += agg[i] / fmaxf(cnt, 1.0f);
        agg[i] = 0.f;
    }
}

// ---------------- decoder: 128->128->128->2 ----------------
__global__ __launch_bounds__(128) void decoder_kernel(
    const float* __restrict__ node,
    const float* __restrict__ W1, const float* __restrict__ b1,
    const float* __restrict__ W2, const float* __restrict__ b2,
    const float* __restrict__ W3, const float* __restrict__ b3,
    float* __restrict__ out)
{
    __shared__ float xs[16][HID];
    __shared__ float h1[16][HID];
    __shared__ float h2[16][HID];
    const int t = threadIdx.x;
    const int base = blockIdx.x * 16;

    for (int i = t; i < 16 * 32; i += 128) {
        int e = i >> 5, c = (i & 31) << 2;
        *(float4*)&xs[e][c] = *(const float4*)&node[(size_t)(base + e) * HID + c];
    }
    __syncthreads();
    {
        const float bb = b1[t];
        for (int e = 0; e < 16; ++e) {
            float acc = bb;
            for (int k = 0; k < HID; ++k) acc += xs[e][k] * W1[k * HID + t];
            h1[e][t] = fmaxf(acc, 0.f);
        }
    }
    __syncthreads();
    {
        const float bb = b2[t];
        for (int e = 0; e < 16; ++e) {
            float acc = bb;
            for (int k = 0; k < HID; ++k) acc += h1[e][k] * W2[k * HID + t];
            h2[e][t] = fmaxf(acc, 0.f);
        }
    }
    __syncthreads();
    if (t < 32) {
        const int e = t >> 1, o = t & 1;
        float acc = b3[o];
        for (int k = 0; k < HID; ++k) acc += h2[e][k] * W3[k * 2 + o];
        out[(size_t)(base + e) * 2 + o] = acc;
    }
}

// ================= fallback (RECOMP fp32 path, proven rounds 2-3) =================
__global__ void degree_kernel(const int* __restrict__ dst, float* __restrict__ cnt)
{
    int i = blockIdx.x * blockDim.x + threadIdx.x;
    if (i < NEDGES) {
        int d = min(max(dst[i], 0), NNODES - 1);
        atomicAdd(&cnt[d], 1.0f);
    }
}

__global__ void update_kernel_cnt(float* __restrict__ node, float* __restrict__ agg,
                                  const float* __restrict__ cnt)
{
    int i = blockIdx.x * blockDim.x + threadIdx.x;
    if (i < NNODES * HID) {
        int n = i >> 7;
        node[i] += agg[i] / fmaxf(cnt[n], 1.0f);
        agg[i] = 0.f;
    }
}

__global__ __launch_bounds__(128) void fuse_kernel(
    const float* __restrict__ eW3, const float* __restrict__ eb3,
    const float* __restrict__ pW1, const float* __restrict__ pb1,
    float* __restrict__ Wc, float* __restrict__ g)
{
    const int l = blockIdx.x >> 3;
    const int s = blockIdx.x & 7;
    const int c = threadIdx.x;
    const float* W1l = pW1 + (size_t)l * 2 * HID * HID;
    float* Wcl = Wc + (size_t)l * 2 * HID * HID;

    for (int r = s * 16; r < s * 16 + 16; ++r)
        Wcl[r * HID + c] = W1l[r * HID + c];

    for (int m = s * 16; m < s * 16 + 16; ++m) {
        float a0 = 0.f, a1 = 0.f, a2 = 0.f, a3 = 0.f;
        for (int k = 0; k < HID; k += 4) {
            a0 += eW3[m * HID + k + 0] * W1l[(HID + k + 0) * HID + c];
            a1 += eW3[m * HID + k + 1] * W1l[(HID + k + 1) * HID + c];
            a2 += eW3[m * HID + k + 2] * W1l[(HID + k + 2) * HID + c];
            a3 += eW3[m * HID + k + 3] * W1l[(HID + k + 3) * HID + c];
        }
        Wcl[(HID + m) * HID + c] = (a0 + a1) + (a2 + a3);
    }
    if (s == 0) {
        float a = pb1[l * HID + c];
        for (int k = 0; k < HID; ++k)
            a += eb3[k] * W1l[(HID + k) * HID + c];
        g[l * HID + c] = a;
    }
}

__global__ __launch_bounds__(256) void msg_recomp(
    const float* __restrict__ node,
    const float* __restrict__ edge_attr,
    const float* __restrict__ eW1, const float* __restrict__ eb1,
    const float* __restrict__ eW2, const float* __restrict__ eb2,
    const int* __restrict__ src_idx, const int* __restrict__ dst_idx,
    const float* __restrict__ W1, const float* __restrict__ b1,
    const float* __restrict__ W2, const float* __restrict__ b2,
    const float* __restrict__ W3, const float* __restrict__ b3,
    float* __restrict__ agg)
{
    __shared__ float X[32][256];
    __shared__ float H[32][HID];
    __shared__ int ssrc[32];
    __shared__ int sdst[32];
    __shared__ float ea_s[32][4];

    const int t = threadIdx.x;
    const int eb = blockIdx.x * 32;

    if (t < 32) { int s = src_idx[eb + t]; ssrc[t] = min(max(s, 0), NNODES - 1); }
    else if (t < 64) { int d = dst_idx[eb + (t - 32)]; sdst[t - 32] = min(max(d, 0), NNODES - 1); }
    __syncthreads();

    for (int i = t; i < 32 * 32; i += 256) {
        int e = i >> 5; int c = (i & 31) << 2;
        *(float4*)&X[e][c] = *(const float4*)&node[(size_t)ssrc[e] * HID + c];
    }
    for (int i = t; i < 32 * 3; i += 256)
        ea_s[i / 3][i % 3] = edge_attr[(size_t)(eb + i / 3) * 3 + (i % 3)];
    __syncthreads();

    const int ct = t & 31;
    const int et = (t >> 5) << 2;
    const int cb = ct << 2;
    float acc[4][4];

    {
        const float4 bv = *(const float4*)&eb1[cb];
        #pragma unroll
        for (int j = 0; j < 4; ++j) { acc[j][0] = bv.x; acc[j][1] = bv.y; acc[j][2] = bv.z; acc[j][3] = bv.w; }
        #pragma unroll
        for (int k = 0; k < 3; ++k) {
            const float4 wv = *(const float4*)&eW1[k * HID + cb];
            #pragma unroll
            for (int j = 0; j < 4; ++j) {
                const float xx = ea_s[et + j][k];
                acc[j][0] += xx * wv.x; acc[j][1] += xx * wv.y; acc[j][2] += xx * wv.z; acc[j][3] += xx * wv.w;
            }
        }
        #pragma unroll
        for (int j = 0; j < 4; ++j)
            *(float4*)&H[et + j][cb] = make_float4(fmaxf(acc[j][0],0.f), fmaxf(acc[j][1],0.f), fmaxf(acc[j][2],0.f), fmaxf(acc[j][3],0.f));
    }
    __syncthreads();
    {
        const float4 bv = *(const float4*)&eb2[cb];
        #pragma unroll
        for (int j = 0; j < 4; ++j) { acc[j][0] = bv.x; acc[j][1] = bv.y; acc[j][2] = bv.z; acc[j][3] = bv.w; }
        for (int k = 0; k < HID; ++k) {
            const float4 wv = *(const float4*)&eW2[k * HID + cb];
            const float x0 = H[et+0][k], x1 = H[et+1][k], x2 = H[et+2][k], x3 = H[et+3][k];
            acc[0][0]+=x0*wv.x; acc[0][1]+=x0*wv.y; acc[0][2]+=x0*wv.z; acc[0][3]+=x0*wv.w;
            acc[1][0]+=x1*wv.x; acc[1][1]+=x1*wv.y; acc[1][2]+=x1*wv.z; acc[1][3]+=x1*wv.w;
            acc[2][0]+=x2*wv.x; acc[2][1]+=x2*wv.y; acc[2][2]+=x2*wv.z; acc[2][3]+=x2*wv.w;
            acc[3][0]+=x3*wv.x; acc[3][1]+=x3*wv.y; acc[3][2]+=x3*wv.z; acc[3][3]+=x3*wv.w;
        }
        #pragma unroll
        for (int j = 0; j < 4; ++j)
            *(float4*)&X[et + j][HID + cb] = make_float4(fmaxf(acc[j][0],0.f), fmaxf(acc[j][1],0.f), fmaxf(acc[j][2],0.f), fmaxf(acc[j][3],0.f));
    }
    __syncthreads();
    {
        const float4 bv = *(const float4*)&b1[cb];
        #pragma unroll
        for (int j = 0; j < 4; ++j) { acc[j][0] = bv.x; acc[j][1] = bv.y; acc[j][2] = bv.z; acc[j][3] = bv.w; }
        for (int k = 0; k < 256; ++k) {
            const float4 wv = *(const float4*)&W1[k * HID + cb];
            const float x0 = X[et+0][k], x1 = X[et+1][k], x2 = X[et+2][k], x3 = X[et+3][k];
            acc[0][0]+=x0*wv.x; acc[0][1]+=x0*wv.y; acc[0][2]+=x0*wv.z; acc[0][3]+=x0*wv.w;
            acc[1][0]+=x1*wv.x; acc[1][1]+=x1*wv.y; acc[1][2]+=x1*wv.z; acc[1][3]+=x1*wv.w;
            acc[2][0]+=x2*wv.x; acc[2][1]+=x2*wv.y; acc[2][2]+=x2*wv.z; acc[2][3]+=x2*wv.w;
            acc[3][0]+=x3*wv.x; acc[3][1]+=x3*wv.y; acc[3][2]+=x3*wv.z; acc[3][3]+=x3*wv.w;
        }
        __syncthreads();
        #pragma unroll
        for (int j = 0; j < 4; ++j)
            *(float4*)&H[et + j][cb] = make_float4(fmaxf(acc[j][0],0.f), fmaxf(acc[j][1],0.f), fmaxf(acc[j][2],0.f), fmaxf(acc[j][3],0.f));
    }
    __syncthreads();
    float* Xf = &X[0][0];
    {
        const float4 bv = *(const float4*)&b2[cb];
        #pragma unroll
        for (int j = 0; j < 4; ++j) { acc[j][0] = bv.x; acc[j][1] = bv.y; acc[j][2] = bv.z; acc[j][3] = bv.w; }
        for (int k = 0; k < HID; ++k) {
            const float4 wv = *(const float4*)&W2[k * HID + cb];
            const float x0 = H[et+0][k], x1 = H[et+1][k], x2 = H[et+2][k], x3 = H[et+3][k];
            acc[0][0]+=x0*wv.x; acc[0][1]+=x0*wv.y; acc[0][2]+=x0*wv.z; acc[0][3]+=x0*wv.w;
            acc[1][0]+=x1*wv.x; acc[1][1]+=x1*wv.y; acc[1][2]+=x1*wv.z; acc[1][3]+=x1*wv.w;
            acc[2][0]+=x2*wv.x; acc[2][1]+=x2*wv.y; acc[2][2]+=x2*wv.z; acc[2][3]+=x2*wv.w;
            acc[3][0]+=x3*wv.x; acc[3][1]+=x3*wv.y; acc[3][2]+=x3*wv.z; acc[3][3]+=x3*wv.w;
        }
        #pragma unroll
        for (int j = 0; j < 4; ++j)
            *(float4*)&Xf[(et + j) * HID + cb] = make_float4(fmaxf(acc[j][0],0.f), fmaxf(acc[j][1],0.f), fmaxf(acc[j][2],0.f), fmaxf(acc[j][3],0.f));
    }
    __syncthreads();
    {
        const float4 bv = *(const float4*)&b3[cb];
        #pragma unroll
        for (int j = 0; j < 4; ++j) { acc[j][0] = bv.x; acc[j][1] = bv.y; acc[j][2] = bv.z; acc[j][3] = bv.w; }
        for (int k = 0; k < HID; ++k) {
            const float4 wv = *(const float4*)&W3[k * HID + cb];
            const float x0 = Xf[(et+0)*HID+k], x1 = Xf[(et+1)*HID+k];
            const float x2 = Xf[(et+2)*HID+k], x3 = Xf[(et+3)*HID+k];
            acc[0][0]+=x0*wv.x; acc[0][1]+=x0*wv.y; acc[0][2]+=x0*wv.z; acc[0][3]+=x0*wv.w;
            acc[1][0]+=x1*wv.x; acc[1][1]+=x1*wv.y; acc[1][2]+=x1*wv.z; acc[1][3]+=x1*wv.w;
            acc[2][0]+=x2*wv.x; acc[2][1]+=x2*wv.y; acc[2][2]+=x2*wv.z; acc[2][3]+=x2*wv.w;
            acc[3][0]+=x3*wv.x; acc[3][1]+=x3*wv.y; acc[3][2]+=x3*wv.z; acc[3][3]+=x3*wv.w;
        }
        #pragma unroll
        for (int j = 0; j < 4; ++j) {
            const int d = sdst[et + j];
            float* ap = &agg[(size_t)d * HID + cb];
            atomicAdd(ap + 0, acc[j][0]);
            atomicAdd(ap + 1, acc[j][1]);
            atomicAdd(ap + 2, acc[j][2]);
            atomicAdd(ap + 3, acc[j][3]);
        }
    }
}

extern "C" void kernel_launch(void* const* d_in, const int* in_sizes, int n_in,
                              void* d_out, int out_size, void* d_ws, size_t ws_size,
                              hipStream_t stream)
{
    const float* x         = (const float*)d_in[0];
    const float* edge_attr = (const float*)d_in[1];
    const float* nW1 = (const float*)d_in[2];  const float* nb1 = (const float*)d_in[3];
    const float* nW2 = (const float*)d_in[4];  const float* nb2 = (const float*)d_in[5];
    const float* nW3 = (const float*)d_in[6];  const float* nb3 = (const float*)d_in[7];
    const float* eW1 = (const float*)d_in[8];  const float* eb1 = (const float*)d_in[9];
    const float* eW2 = (const float*)d_in[10]; const float* eb2 = (const float*)d_in[11];
    const float* eW3 = (const float*)d_in[12]; const float* eb3 = (const float*)d_in[13];
    const float* pW1 = (const float*)d_in[14]; const float* pb1 = (const float*)d_in[15];
    const float* pW2 = (const float*)d_in[16]; const float* pb2 = (const float*)d_in[17];
    const float* pW3 = (const float*)d_in[18]; const float* pb3 = (const float*)d_in[19];
    const float* dW1 = (const float*)d_in[20]; const float* db1 = (const float*)d_in[21];
    const float* dW2 = (const float*)d_in[22]; const float* db2 = (const float*)d_in[23];
    const float* dW3 = (const float*)d_in[24]; const float* db3 = (const float*)d_in[25];
    const int* ei  = (const int*)d_in[26];
    const int* src = ei;
    const int* dst = ei + NEDGES;

    // fast-path workspace layout (bytes)
    char* ws = (char*)d_ws;
    float* node    = (float*)(ws);                     // 10,240,000
    float* agg     = (float*)(ws + 10240000);          // 10,240,000
    int*   cnt_i   = (int*)  (ws + 20480000);          //     80,000
    int*   fill    = (int*)  (ws + 20560000);          //     80,000
    int*   rowptr  = (int*)  (ws + 20640000);          //     80,064 (20001 ints, padded)
    float* gb      = (float*)(ws + 20720064);          //      5,120
    uint4* wfrag   = (uint4*)(ws + 20725184);          //  2,621,440
    uint4* ewf     = (uint4*)(ws + 23346624);          //     65,536
    int*   seid    = (int*)  (ws + 23412160);          //  2,560,000
    unsigned short* ssrc16 = (unsigned short*)(ws + 25972160);  // 1,280,000
    unsigned short* sdst16 = (unsigned short*)(ws + 27252160);  // 1,280,000
    const size_t NEED_FAST = 28532160ull;

    // fallback layout (proven fits)
    float* cntf = (float*)(ws + 20480000);
    float* Wc   = (float*)(ws + 20560000);
    float* gb2  = (float*)(ws + 21870720);

    const bool fast = (ws_size >= NEED_FAST);

    encoder_kernel<16, 2><<<NNODES / 16, 128, 0, stream>>>(
        x, nW1, nb1, nW2, nb2, nW3, nb3, node, NNODES);

    if (fast) {
        // zero agg + cnt_i + fill (contiguous)
        hipMemsetAsync(ws + 10240000, 0, 10240000 + 160000, stream);

        hist_kernel<<<(NEDGES + 255) / 256, 256, 0, stream>>>(dst, cnt_i);
        scan_kernel<<<1, 1024, 0, stream>>>(cnt_i, rowptr);
        scatter_kernel<<<(NEDGES + 255) / 256, 256, 0, stream>>>(
            src, dst, rowptr, fill, seid, ssrc16, sdst16);

        wprep_kernel<<<(NSTEPS * 16384 + 4096) / 256, 256, 0, stream>>>(
            eW3, pW1, pW2, pW3, eW2, wfrag);
        gfuse_kernel<<<NSTEPS, 128, 0, stream>>>(eb3, pW1, pb1, gb);

        for (int l = 0; l < NSTEPS; ++l) {
            msg_mfma_s<<<NEDGES / 128, 256, 0, stream>>>(
                node, edge_attr, eW1, eb1, eb2,
                ewf, wfrag + (size_t)l * 16384,
                seid, ssrc16, sdst16,
                gb + l * HID, pb2 + l * HID, pb3 + l * HID, agg);
            update_kernel_csr<<<(NNODES * HID) / 256, 256, 0, stream>>>(node, agg, rowptr);
        }
    } else {
        hipMemsetAsync(ws + 10240000, 0, 10240000 + 80000, stream);
        degree_kernel<<<(NEDGES + 255) / 256, 256, 0, stream>>>(dst, cntf);
        fuse_kernel<<<NSTEPS * 8, 128, 0, stream>>>(eW3, eb3, pW1, pb1, Wc, gb2);
        for (int l = 0; l < NSTEPS; ++l) {
            msg_recomp<<<NEDGES / 32, 256, 0, stream>>>(
                node, edge_attr, eW1, eb1, eW2, eb2, src, dst,
                Wc + (size_t)l * 2 * HID * HID,  gb2 + l * HID,
                pW2 + (size_t)l * HID * HID,     pb2 + l * HID,
                pW3 + (size_t)l * HID * HID,     pb3 + l * HID,
                agg);
            update_kernel_cnt<<<(NNODES * HID) / 256, 256, 0, stream>>>(node, agg, cntf);
        }
    }

    decoder_kernel<<<NNODES / 16, 128, 0, stream>>>(
        node, dW1, db1, dW2, db2, dW3, db3, (float*)d_out);
}

// Round 10
// 2919.890 us; speedup vs baseline: 1.5415x; 1.2210x over previous
//
#include <hip/hip_runtime.h>

#define HID     128
#define NNODES  20000
#define NEDGES  640000
#define NSTEPS  10

typedef __attribute__((ext_vector_type(8)))  short short8;
typedef __attribute__((ext_vector_type(16))) float f32x16;

union Frag { short8 s; uint4 q; uint u[4]; };
union Acc  { f32x16 v; float f[16]; };

#define MFMA(a,b,c) __builtin_amdgcn_mfma_f32_32x32x16_bf16((a),(b),(c),0,0,0)

// split 4 fp32 into bf16 hi-plane pair-u32s and lo-plane pair-u32s (truncation)
static __device__ inline void pack4(const float v0, const float v1,
                                    const float v2, const float v3,
                                    uint2& hi, uint2& lo)
{
    const uint h0 = __float_as_uint(v0) & 0xFFFF0000u;
    const uint h1 = __float_as_uint(v1) & 0xFFFF0000u;
    const uint h2 = __float_as_uint(v2) & 0xFFFF0000u;
    const uint h3 = __float_as_uint(v3) & 0xFFFF0000u;
    hi.x = (h0 >> 16) | h1;
    hi.y = (h2 >> 16) | h3;
    lo.x = (__float_as_uint(v0 - __uint_as_float(h0)) >> 16)
         | (__float_as_uint(v1 - __uint_as_float(h1)) & 0xFFFF0000u);
    lo.y = (__float_as_uint(v2 - __uint_as_float(h2)) >> 16)
         | (__float_as_uint(v3 - __uint_as_float(h3)) & 0xFFFF0000u);
}

// RNE bf16 (unbiased) — used for the materialized h2e-hi image
static __device__ inline uint rne16(float x)
{
    const uint u = __float_as_uint(x);
    return (u + 0x7FFFu + ((u >> 16) & 1u)) >> 16;
}

// ---------------- node encoder (KIN=16, skip first 2 feats) ----------------
template<int KIN, int KSTART>
__global__ __launch_bounds__(128) void encoder_kernel(
    const float* __restrict__ in,
    const float* __restrict__ W1, const float* __restrict__ b1,
    const float* __restrict__ W2, const float* __restrict__ b2,
    const float* __restrict__ W3, const float* __restrict__ b3,
    float* __restrict__ out, int n)
{
    __shared__ float xs[16][(KIN < 4) ? 4 : KIN];
    __shared__ float h1[16][HID];
    __shared__ float h2[16][HID];
    const int t = threadIdx.x;
    const int base = blockIdx.x * 16;

    for (int i = t; i < 16 * KIN; i += 128) {
        int e = i / KIN, k = i % KIN;
        int g = base + e;
        xs[e][k] = (g < n) ? in[(size_t)g * KIN + k] : 0.f;
    }
    __syncthreads();
    {
        const float bb = b1[t];
        for (int e = 0; e < 16; ++e) {
            float acc = bb;
            #pragma unroll
            for (int k = KSTART; k < KIN; ++k) acc += xs[e][k] * W1[k * HID + t];
            h1[e][t] = fmaxf(acc, 0.f);
        }
    }
    __syncthreads();
    {
        const float bb = b2[t];
        for (int e = 0; e < 16; ++e) {
            float acc = bb;
            for (int k = 0; k < HID; ++k) acc += h1[e][k] * W2[k * HID + t];
            h2[e][t] = fmaxf(acc, 0.f);
        }
    }
    __syncthreads();
    {
        const float bb = b3[t];
        for (int e = 0; e < 16; ++e) {
            int g = base + e;
            if (g >= n) continue;
            float acc = bb;
            for (int k = 0; k < HID; ++k) acc += h2[e][k] * W3[k * HID + t];
            out[(size_t)g * HID + t] = acc;
        }
    }
}

// ---------------- weight repack to A-frag layout (hi/lo planes) ----------------
__global__ __launch_bounds__(256) void wprep_kernel(
    const float* __restrict__ eW3,
    const float* __restrict__ pW1, const float* __restrict__ pW2,
    const float* __restrict__ pW3, const float* __restrict__ eW2,
    uint4* __restrict__ out)
{
    const int gid = blockIdx.x * 256 + threadIdx.x;
    if (gid >= NSTEPS * 16384 + 4096) return;

    int layer, rr, sid = 0;
    if (gid >= NSTEPS * 16384) { layer = 3; rr = gid - NSTEPS * 16384; }
    else {
        sid = gid / 16384;
        const int r = gid % 16384;
        if (r < 8192)       { layer = 0; rr = r; }
        else if (r < 12288) { layer = 1; rr = r - 8192; }
        else                { layer = 2; rr = r - 12288; }
    }
    const int ks  = rr >> 9;
    const int rem = rr & 511;
    const int rb  = rem >> 7;
    const int pl  = (rem >> 6) & 1;
    const int l   = rem & 63;
    const int c   = rb * 32 + (l & 31);
    const int k0  = ks * 16 + 8 * (l >> 5);

    float vals[8];
    if (layer == 0 && ks >= 8) {
        const float* W1l = pW1 + (size_t)sid * 2 * HID * HID;
        #pragma unroll
        for (int j = 0; j < 8; ++j) vals[j] = 0.f;
        const int kp = k0 - HID;
        for (int k = 0; k < HID; ++k) {
            const float wv = W1l[(size_t)(HID + k) * HID + c];
            #pragma unroll
            for (int j = 0; j < 8; ++j)
                vals[j] += eW3[(size_t)(kp + j) * HID + k] * wv;
        }
    } else {
        const float* Wsrc =
            (layer == 0) ? pW1 + (size_t)sid * 2 * HID * HID :
            (layer == 1) ? pW2 + (size_t)sid * HID * HID :
            (layer == 2) ? pW3 + (size_t)sid * HID * HID : eW2;
        #pragma unroll
        for (int j = 0; j < 8; ++j)
            vals[j] = Wsrc[(size_t)(k0 + j) * HID + c];
    }

    uint b16[8];
    #pragma unroll
    for (int j = 0; j < 8; ++j) {
        const uint hx = __float_as_uint(vals[j]) & 0xFFFF0000u;
        b16[j] = (pl == 0) ? (hx >> 16)
                           : (__float_as_uint(vals[j] - __uint_as_float(hx)) >> 16);
    }
    uint4 o;
    o.x = b16[0] | (b16[1] << 16);
    o.y = b16[2] | (b16[3] << 16);
    o.z = b16[4] | (b16[5] << 16);
    o.w = b16[6] | (b16[7] << 16);
    out[gid] = o;
}

// ---------------- fused L1 bias: g = pb1 + eb3 @ W1_lower ----------------
__global__ __launch_bounds__(128) void gfuse_kernel(
    const float* __restrict__ eb3, const float* __restrict__ pW1,
    const float* __restrict__ pb1, float* __restrict__ g)
{
    const int l = blockIdx.x, c = threadIdx.x;
    const float* W1l = pW1 + (size_t)l * 2 * HID * HID;
    float a = pb1[l * HID + c];
    for (int k = 0; k < HID; ++k)
        a += eb3[k] * W1l[(size_t)(HID + k) * HID + c];
    g[l * HID + c] = a;
}

// ---------------- CSR sort: histogram -> scan -> scatter ----------------
__global__ void hist_kernel(const int* __restrict__ dst, int* __restrict__ cnt)
{
    int i = blockIdx.x * blockDim.x + threadIdx.x;
    if (i < NEDGES) {
        int d = min(max(dst[i], 0), NNODES - 1);
        atomicAdd(&cnt[d], 1);
    }
}

__global__ __launch_bounds__(1024) void scan_kernel(
    const int* __restrict__ cnt, int* __restrict__ rowptr)
{
    __shared__ int part[1024];
    const int t = threadIdx.x;
    int vals[20];
    int s = 0;
    const int base = t * 20;
    #pragma unroll
    for (int j = 0; j < 20; ++j) {
        int idx = base + j;
        int v = (idx < NNODES) ? cnt[idx] : 0;
        vals[j] = s;
        s += v;
    }
    part[t] = s;
    __syncthreads();
    for (int off = 1; off < 1024; off <<= 1) {
        int v = (t >= off) ? part[t - off] : 0;
        __syncthreads();
        part[t] += v;
        __syncthreads();
    }
    const int pre = (t == 0) ? 0 : part[t - 1];
    #pragma unroll
    for (int j = 0; j < 20; ++j) {
        int idx = base + j;
        if (idx < NNODES) rowptr[idx] = pre + vals[j];
    }
    if (t == 0) rowptr[NNODES] = NEDGES;
}

__global__ void scatter_kernel(
    const int* __restrict__ src, const int* __restrict__ dst,
    const int* __restrict__ rowptr, int* __restrict__ fill,
    int* __restrict__ seid, unsigned short* __restrict__ ssrc,
    unsigned short* __restrict__ sdst)
{
    int i = blockIdx.x * blockDim.x + threadIdx.x;
    if (i < NEDGES) {
        int d = min(max(dst[i], 0), NNODES - 1);
        int s = min(max(src[i], 0), NNODES - 1);
        int pos = rowptr[d] + atomicAdd(&fill[d], 1);
        seid[pos] = i;
        ssrc[pos] = (unsigned short)s;
        sdst[pos] = (unsigned short)d;
    }
}

// ---------------- one MFMA layer phase ----------------
// Wave owns ONE col-block rb and FOUR 32-edge groups. HASLO: include AhBl term.
template<int NKS, bool HASLO>
static __device__ inline void run_phaseT(
    const uint4* __restrict__ wf, int rb, int l, int g, int l31,
    const uint* __restrict__ PH, const uint* __restrict__ PL,
    Acc& ac0, Acc& ac1, Acc& ac2, Acc& ac3)
{
    Frag wbuf[4][2];
    Frag bh[2][4], bl[2][4];
    auto loadW = [&](int ks, int slot) {
        const uint4* wbase = wf + (size_t)(ks * 4 + rb) * 2 * 64;
        wbuf[slot][0].q = wbase[l];
        wbuf[slot][1].q = wbase[64 + l];
    };
    auto loadB = [&](int ks, int slot) {
        const int sl = ((ks * 16 + 8 * g) >> 3);
        const int bo = l31 * 64 + ((sl ^ (l31 & 15)) << 2);
        #pragma unroll
        for (int gi = 0; gi < 4; ++gi) {
            bh[slot][gi].q = *(const uint4*)&PH[bo + gi * 2048];
            if (HASLO) bl[slot][gi].q = *(const uint4*)&PL[bo + gi * 2048];
        }
    };
    loadW(0, 0);
    loadB(0, 0);
    if (NKS > 1) loadW(1, 1);
    if (NKS > 2) loadW(2, 2);
    if (NKS > 3) loadW(3, 3);
    #pragma unroll
    for (int ks = 0; ks < NKS; ++ks) {
        if (ks + 1 < NKS) loadB(ks + 1, (ks + 1) & 1);
        Frag& ah = wbuf[ks & 3][0];
        Frag& al = wbuf[ks & 3][1];
        const int s = ks & 1;
        __builtin_amdgcn_s_setprio(1);
        ac0.v = MFMA(ah.s, bh[s][0].s, ac0.v);
        ac1.v = MFMA(ah.s, bh[s][1].s, ac1.v);
        ac2.v = MFMA(ah.s, bh[s][2].s, ac2.v);
        ac3.v = MFMA(ah.s, bh[s][3].s, ac3.v);
        ac0.v = MFMA(al.s, bh[s][0].s, ac0.v);
        ac1.v = MFMA(al.s, bh[s][1].s, ac1.v);
        ac2.v = MFMA(al.s, bh[s][2].s, ac2.v);
        ac3.v = MFMA(al.s, bh[s][3].s, ac3.v);
        if (HASLO) {
            ac0.v = MFMA(ah.s, bl[s][0].s, ac0.v);
            ac1.v = MFMA(ah.s, bl[s][1].s, ac1.v);
            ac2.v = MFMA(ah.s, bl[s][2].s, ac2.v);
            ac3.v = MFMA(ah.s, bl[s][3].s, ac3.v);
        }
        __builtin_amdgcn_s_setprio(0);
        if (ks + 4 < NKS) loadW(ks + 4, ks & 3);
    }
}

// epilogue: bias (+relu), split hi/lo, store into planes
static __device__ inline void epi_store(
    uint* __restrict__ PH, uint* __restrict__ PL, int rb, int e, int g,
    const Acc& a, const float* __restrict__ bias, bool relu)
{
    #pragma unroll
    for (int q = 0; q < 4; ++q) {
        const int c0 = rb * 32 + q * 8 + 4 * g;
        const float4 bv = *(const float4*)&bias[c0];
        float v0 = a.f[q*4+0] + bv.x;
        float v1 = a.f[q*4+1] + bv.y;
        float v2 = a.f[q*4+2] + bv.z;
        float v3 = a.f[q*4+3] + bv.w;
        if (relu) { v0 = fmaxf(v0, 0.f); v1 = fmaxf(v1, 0.f); v2 = fmaxf(v2, 0.f); v3 = fmaxf(v3, 0.f); }
        uint2 hi, lo;
        pack4(v0, v1, v2, v3, hi, lo);
        const int off = e * 64 + ((((c0 >> 3) ^ (e & 15))) << 2) + g * 2;
        *(uint2*)&PH[off] = hi;
        *(uint2*)&PL[off] = lo;
    }
}

// epilogue: bias + relu, RNE hi-only store (for the materialized h2e image)
static __device__ inline void epi_store_rne(
    uint* __restrict__ PH, int rb, int e, int g,
    const Acc& a, const float* __restrict__ bias)
{
    #pragma unroll
    for (int q = 0; q < 4; ++q) {
        const int c0 = rb * 32 + q * 8 + 4 * g;
        const float4 bv = *(const float4*)&bias[c0];
        const float v0 = fmaxf(a.f[q*4+0] + bv.x, 0.f);
        const float v1 = fmaxf(a.f[q*4+1] + bv.y, 0.f);
        const float v2 = fmaxf(a.f[q*4+2] + bv.z, 0.f);
        const float v3 = fmaxf(a.f[q*4+3] + bv.w, 0.f);
        uint2 hi;
        hi.x = rne16(v0) | (rne16(v1) << 16);
        hi.y = rne16(v2) | (rne16(v3) << 16);
        const int off = e * 64 + ((((c0 >> 3) ^ (e & 15))) << 2) + g * 2;
        *(uint2*)&PH[off] = hi;
    }
}

// ---------------- h2e prep: edge MLP once per launch -> pre-swizzled hi image ----------------
__global__ __launch_bounds__(256, 2) void h2prep_kernel(
    const float* __restrict__ edge_attr,
    const float* __restrict__ eW1, const float* __restrict__ eb1,
    const float* __restrict__ eb2,
    const uint4* __restrict__ ewfrag,
    const int* __restrict__ seidg,
    uint4* __restrict__ h2img)
{
    __shared__ uint4 pool4[4096];
    __shared__ float eas[384];
    __shared__ int seid[128];
    uint* HH = (uint*)pool4;
    uint* HL = (uint*)(pool4 + 2048);

    const int t   = threadIdx.x;
    const int wv  = t >> 6;
    const int l   = t & 63;
    const int l31 = l & 31;
    const int g   = l >> 5;
    const int rb  = wv;
    const int eb0 = blockIdx.x * 128;

    if (t < 128) seid[t] = seidg[eb0 + t];
    __syncthreads();
    for (int i = t; i < 384; i += 256)
        eas[i] = edge_attr[(size_t)seid[i / 3] * 3 + (i % 3)];
    __syncthreads();

    // h1e = relu(ea @ eW1 + eb1) on VALU -> planes (hi/lo, trunc)
    {
        const int e = t & 127, sb = t >> 7;
        const float a0 = eas[e * 3 + 0], a1 = eas[e * 3 + 1], a2 = eas[e * 3 + 2];
        #pragma unroll
        for (int i = 0; i < 16; ++i) {
            const int s4 = sb * 16 + i;
            const int c0 = s4 * 4;
            const float4 w1 = *(const float4*)&eW1[0 * HID + c0];
            const float4 w2 = *(const float4*)&eW1[1 * HID + c0];
            const float4 w3 = *(const float4*)&eW1[2 * HID + c0];
            const float4 bb = *(const float4*)&eb1[c0];
            const float v0 = fmaxf(bb.x + a0 * w1.x + a1 * w2.x + a2 * w3.x, 0.f);
            const float v1 = fmaxf(bb.y + a0 * w1.y + a1 * w2.y + a2 * w3.y, 0.f);
            const float v2 = fmaxf(bb.z + a0 * w1.z + a1 * w2.z + a2 * w3.z, 0.f);
            const float v3 = fmaxf(bb.w + a0 * w1.w + a1 * w2.w + a2 * w3.w, 0.f);
            uint2 hi, lo;
            pack4(v0, v1, v2, v3, hi, lo);
            const int off = e * 64 + ((((s4 >> 1) ^ (e & 15))) << 2) + (s4 & 1) * 2;
            *(uint2*)&HH[off] = hi;
            *(uint2*)&HL[off] = lo;
        }
    }
    __syncthreads();

    Acc ac0, ac1, ac2, ac3;
    #pragma unroll
    for (int z = 0; z < 16; ++z) { ac0.f[z] = 0.f; ac1.f[z] = 0.f; ac2.f[z] = 0.f; ac3.f[z] = 0.f; }

    run_phaseT<8, true>(ewfrag, rb, l, g, l31, HH, HL, ac0, ac1, ac2, ac3);
    __syncthreads();

    epi_store_rne(HH, rb,  0 + l31, g, ac0, eb2);
    epi_store_rne(HH, rb, 32 + l31, g, ac1, eb2);
    epi_store_rne(HH, rb, 64 + l31, g, ac2, eb2);
    epi_store_rne(HH, rb, 96 + l31, g, ac3, eb2);
    __syncthreads();

    // linear coalesced copy of the 32 KB HH image to global
    uint4* dstp = h2img + (size_t)blockIdx.x * 2048;
    const uint4* srcp = (const uint4*)HH;
    #pragma unroll
    for (int i = 0; i < 8; ++i)
        dstp[i * 256 + t] = srcp[i * 256 + t];
}

// ---------------- MFMA message kernel (materialized h2e): 128 edges/block ----------------
__global__ __launch_bounds__(256, 2) void msg_mfma_m(
    const float* __restrict__ node,
    const uint4* __restrict__ h2img,
    const uint4* __restrict__ wfrag,
    const unsigned short* __restrict__ ssrcg,
    const unsigned short* __restrict__ sdstg,
    const float* __restrict__ gb1, const float* __restrict__ b2,
    const float* __restrict__ b3,
    float* __restrict__ agg)
{
    __shared__ uint4 pool4[4096];        // 64 KB: HH|HL planes / Mf fp32 overlay
    __shared__ int ssrc[128], sdst[128];
    uint* HH = (uint*)pool4;
    uint* HL = (uint*)(pool4 + 2048);
    float* Mf = (float*)pool4;

    const int t   = threadIdx.x;
    const int wv  = t >> 6;
    const int l   = t & 63;
    const int l31 = l & 31;
    const int g   = l >> 5;
    const int rb  = wv;
    const int eb0 = blockIdx.x * 128;

    if (t < 128) ssrc[t] = ssrcg[eb0 + t];
    else         sdst[t - 128] = sdstg[eb0 + (t - 128)];
    __syncthreads();

    // pack x_j into planes (hi/lo)
    #pragma unroll
    for (int i = 0; i < 16; ++i) {
        const int idx = i * 256 + t;
        const int ee = idx >> 5, q = idx & 31;
        const float4 v = *(const float4*)&node[(size_t)ssrc[ee] * HID + q * 4];
        uint2 hi, lo;
        pack4(v.x, v.y, v.z, v.w, hi, lo);
        const int off = ee * 64 + ((((q >> 1) ^ (ee & 15))) << 2) + (q & 1) * 2;
        *(uint2*)&HH[off] = hi;
        *(uint2*)&HL[off] = lo;
    }
    __syncthreads();

    Acc ac0, ac1, ac2, ac3;
#define ZACC() do { _Pragma("unroll") \
    for (int z = 0; z < 16; ++z) { ac0.f[z] = 0.f; ac1.f[z] = 0.f; ac2.f[z] = 0.f; ac3.f[z] = 0.f; } } while (0)
#define EPI4(BIAS, RELU) do { \
    epi_store(HH, HL, rb,  0 + l31, g, ac0, (BIAS), (RELU)); \
    epi_store(HH, HL, rb, 32 + l31, g, ac1, (BIAS), (RELU)); \
    epi_store(HH, HL, rb, 64 + l31, g, ac2, (BIAS), (RELU)); \
    epi_store(HH, HL, rb, 96 + l31, g, ac3, (BIAS), (RELU)); } while (0)

    // ---- L1a: acc = x_j @ Wc_upper (full hi/lo precision) ----
    ZACC();
    run_phaseT<8, true>(wfrag, rb, l, g, l31, HH, HL, ac0, ac1, ac2, ac3);
    __syncthreads();

    // ---- load materialized h2e-hi image into HH (linear, coalesced) ----
    {
        const uint4* srcp = h2img + (size_t)blockIdx.x * 2048;
        uint4* dstp = (uint4*)HH;
        #pragma unroll
        for (int i = 0; i < 8; ++i)
            dstp[i * 256 + t] = srcp[i * 256 + t];
    }
    __syncthreads();

    // ---- L1b: acc += h2e @ Wc_lower (B hi-only: 8 MFMAs/ks) ----
    run_phaseT<8, false>(wfrag + 4096, rb, l, g, l31, HH, HH, ac0, ac1, ac2, ac3);
    __syncthreads();
    EPI4(gb1, true);
    __syncthreads();

    // ---- L2: h2 = relu(h1 @ W2 + b2) ----
    ZACC();
    run_phaseT<8, true>(wfrag + 8192, rb, l, g, l31, HH, HL, ac0, ac1, ac2, ac3);
    __syncthreads();
    EPI4(b2, true);
    __syncthreads();

    // ---- L3: msg = h2 @ W3 + b3 -> Mf (fp32 overlay) ----
    ZACC();
    run_phaseT<8, true>(wfrag + 12288, rb, l, g, l31, HH, HL, ac0, ac1, ac2, ac3);
    __syncthreads();
    #pragma unroll
    for (int q = 0; q < 4; ++q) {
        const int c0 = rb * 32 + q * 8 + 4 * g;
        const float4 bva = *(const float4*)&b3[c0];
        const int sw = c0 ^ ((l31 & 7) << 2);
        float4 v0;
        v0.x = ac0.f[q*4+0] + bva.x; v0.y = ac0.f[q*4+1] + bva.y;
        v0.z = ac0.f[q*4+2] + bva.z; v0.w = ac0.f[q*4+3] + bva.w;
        *(float4*)&Mf[( 0 + l31) * 128 + sw] = v0;
        float4 v1;
        v1.x = ac1.f[q*4+0] + bva.x; v1.y = ac1.f[q*4+1] + bva.y;
        v1.z = ac1.f[q*4+2] + bva.z; v1.w = ac1.f[q*4+3] + bva.w;
        *(float4*)&Mf[(32 + l31) * 128 + sw] = v1;
        float4 v2;
        v2.x = ac2.f[q*4+0] + bva.x; v2.y = ac2.f[q*4+1] + bva.y;
        v2.z = ac2.f[q*4+2] + bva.z; v2.w = ac2.f[q*4+3] + bva.w;
        *(float4*)&Mf[(64 + l31) * 128 + sw] = v2;
        float4 v3;
        v3.x = ac3.f[q*4+0] + bva.x; v3.y = ac3.f[q*4+1] + bva.y;
        v3.z = ac3.f[q*4+2] + bva.z; v3.w = ac3.f[q*4+3] + bva.w;
        *(float4*)&Mf[(96 + l31) * 128 + sw] = v3;
    }
#undef ZACC
#undef EPI4
    __syncthreads();

    // ---- segmented sum over sorted dst (float4, 8 segs x 16 edges) ----
    {
        const int grp = t & 31;
        const int seg = t >> 5;
        const int c0  = grp << 2;
        const int es  = seg * 16;
        float4 run = make_float4(0.f, 0.f, 0.f, 0.f);
        int cur = sdst[es];
        for (int e2 = es; e2 < es + 16; ++e2) {
            const int d2 = sdst[e2];
            const float4 v = *(const float4*)&Mf[e2 * 128 + (c0 ^ ((e2 & 7) << 2))];
            if (d2 != cur) {
                float* ap = &agg[(size_t)cur * HID + c0];
                atomicAdd(ap + 0, run.x);
                atomicAdd(ap + 1, run.y);
                atomicAdd(ap + 2, run.z);
                atomicAdd(ap + 3, run.w);
                run = make_float4(0.f, 0.f, 0.f, 0.f);
                cur = d2;
            }
            run.x += v.x; run.y += v.y; run.z += v.z; run.w += v.w;
        }
        float* ap = &agg[(size_t)cur * HID + c0];
        atomicAdd(ap + 0, run.x);
        atomicAdd(ap + 1, run.y);
        atomicAdd(ap + 2, run.z);
        atomicAdd(ap + 3, run.w);
    }
}

// ---------------- mid-fallback: round-9 msg kernel (recompute h2e each step) ----------------
__global__ __launch_bounds__(256, 2) void msg_mfma_s(
    const float* __restrict__ node,
    const float* __restrict__ edge_attr,
    const float* __restrict__ eW1, const float* __restrict__ eb1,
    const float* __restrict__ eb2,
    const uint4* __restrict__ ewfrag,
    const uint4* __restrict__ wfrag,
    const int* __restrict__ seidg,
    const unsigned short* __restrict__ ssrcg,
    const unsigned short* __restrict__ sdstg,
    const float* __restrict__ gb1, const float* __restrict__ b2,
    const float* __restrict__ b3,
    float* __restrict__ agg)
{
    __shared__ uint4 pool4[4096];
    __shared__ float eas[384];
    __shared__ int ssrc[128], sdst[128], seid[128];
    uint* HH = (uint*)pool4;
    uint* HL = (uint*)(pool4 + 2048);
    float* Mf = (float*)pool4;

    const int t   = threadIdx.x;
    const int wv  = t >> 6;
    const int l   = t & 63;
    const int l31 = l & 31;
    const int g   = l >> 5;
    const int rb  = wv;
    const int eb0 = blockIdx.x * 128;

    if (t < 128) { ssrc[t] = ssrcg[eb0 + t]; seid[t] = seidg[eb0 + t]; }
    else         { sdst[t - 128] = sdstg[eb0 + (t - 128)]; }
    __syncthreads();

    for (int i = t; i < 384; i += 256)
        eas[i] = edge_attr[(size_t)seid[i / 3] * 3 + (i % 3)];
    __syncthreads();

    {
        const int e = t & 127, sb = t >> 7;
        const float a0 = eas[e * 3 + 0], a1 = eas[e * 3 + 1], a2 = eas[e * 3 + 2];
        #pragma unroll
        for (int i = 0; i < 16; ++i) {
            const int s4 = sb * 16 + i;
            const int c0 = s4 * 4;
            const float4 w1 = *(const float4*)&eW1[0 * HID + c0];
            const float4 w2 = *(const float4*)&eW1[1 * HID + c0];
            const float4 w3 = *(const float4*)&eW1[2 * HID + c0];
            const float4 bb = *(const float4*)&eb1[c0];
            const float v0 = fmaxf(bb.x + a0 * w1.x + a1 * w2.x + a2 * w3.x, 0.f);
            const float v1 = fmaxf(bb.y + a0 * w1.y + a1 * w2.y + a2 * w3.y, 0.f);
            const float v2 = fmaxf(bb.z + a0 * w1.z + a1 * w2.z + a2 * w3.z, 0.f);
            const float v3 = fmaxf(bb.w + a0 * w1.w + a1 * w2.w + a2 * w3.w, 0.f);
            uint2 hi, lo;
            pack4(v0, v1, v2, v3, hi, lo);
            const int off = e * 64 + ((((s4 >> 1) ^ (e & 15))) << 2) + (s4 & 1) * 2;
            *(uint2*)&HH[off] = hi;
            *(uint2*)&HL[off] = lo;
        }
    }
    __syncthreads();

    Acc ac0, ac1, ac2, ac3;
#define ZACC() do { _Pragma("unroll") \
    for (int z = 0; z < 16; ++z) { ac0.f[z] = 0.f; ac1.f[z] = 0.f; ac2.f[z] = 0.f; ac3.f[z] = 0.f; } } while (0)
#define EPI4(BIAS, RELU) do { \
    epi_store(HH, HL, rb,  0 + l31, g, ac0, (BIAS), (RELU)); \
    epi_store(HH, HL, rb, 32 + l31, g, ac1, (BIAS), (RELU)); \
    epi_store(HH, HL, rb, 64 + l31, g, ac2, (BIAS), (RELU)); \
    epi_store(HH, HL, rb, 96 + l31, g, ac3, (BIAS), (RELU)); } while (0)

    ZACC();
    run_phaseT<8, true>(ewfrag, rb, l, g, l31, HH, HL, ac0, ac1, ac2, ac3);
    __syncthreads();
    EPI4(eb2, true);
    __syncthreads();

    ZACC();
    run_phaseT<8, true>(wfrag + 4096, rb, l, g, l31, HH, HL, ac0, ac1, ac2, ac3);
    __syncthreads();
    #pragma unroll
    for (int i = 0; i < 16; ++i) {
        const int idx = i * 256 + t;
        const int ee = idx >> 5, q = idx & 31;
        const float4 v = *(const float4*)&node[(size_t)ssrc[ee] * HID + q * 4];
        uint2 hi, lo;
        pack4(v.x, v.y, v.z, v.w, hi, lo);
        const int off = ee * 64 + ((((q >> 1) ^ (ee & 15))) << 2) + (q & 1) * 2;
        *(uint2*)&HH[off] = hi;
        *(uint2*)&HL[off] = lo;
    }
    __syncthreads();

    run_phaseT<8, true>(wfrag, rb, l, g, l31, HH, HL, ac0, ac1, ac2, ac3);
    __syncthreads();
    EPI4(gb1, true);
    __syncthreads();

    ZACC();
    run_phaseT<8, true>(wfrag + 8192, rb, l, g, l31, HH, HL, ac0, ac1, ac2, ac3);
    __syncthreads();
    EPI4(b2, true);
    __syncthreads();

    ZACC();
    run_phaseT<8, true>(wfrag + 12288, rb, l, g, l31, HH, HL, ac0, ac1, ac2, ac3);
    __syncthreads();
    #pragma unroll
    for (int q = 0; q < 4; ++q) {
        const int c0 = rb * 32 + q * 8 + 4 * g;
        const float4 bva = *(const float4*)&b3[c0];
        const int sw = c0 ^ ((l31 & 7) << 2);
        float4 v0;
        v0.x = ac0.f[q*4+0] + bva.x; v0.y = ac0.f[q*4+1] + bva.y;
        v0.z = ac0.f[q*4+2] + bva.z; v0.w = ac0.f[q*4+3] + bva.w;
        *(float4*)&Mf[( 0 + l31) * 128 + sw] = v0;
        float4 v1;
        v1.x = ac1.f[q*4+0] + bva.x; v1.y = ac1.f[q*4+1] + bva.y;
        v1.z = ac1.f[q*4+2] + bva.z; v1.w = ac1.f[q*4+3] + bva.w;
        *(float4*)&Mf[(32 + l31) * 128 + sw] = v1;
        float4 v2;
        v2.x = ac2.f[q*4+0] + bva.x; v2.y = ac2.f[q*4+1] + bva.y;
        v2.z = ac2.f[q*4+2] + bva.z; v2.w = ac2.f[q*4+3] + bva.w;
        *(float4*)&Mf[(64 + l31) * 128 + sw] = v2;
        float4 v3;
        v3.x = ac3.f[q*4+0] + bva.x; v3.y = ac3.f[q*4+1] + bva.y;
        v3.z = ac3.f[q*4+2] + bva.z; v3.w = ac3.f[q*4+3] + bva.w;
        *(float4*)&Mf[(96 + l31) * 128 + sw] = v3;
    }
#undef ZACC
#undef EPI4
    __syncthreads();

    {
        const int grp = t & 31;
        const int seg = t >> 5;
        const int c0  = grp << 2;
        const int es  = seg * 16;
        float4 run = make_float4(0.f, 0.f, 0.f, 0.f);
        int cur = sdst[es];
        for (int e2 = es; e2 < es + 16; ++e2) {
            const int d2 = sdst[e2];
            const float4 v = *(const float4*)&Mf[e2 * 128 + (c0 ^ ((e2 & 7) << 2))];
            if (d2 != cur) {
                float* ap = &agg[(size_t)cur * HID + c0];
                atomicAdd(ap + 0, run.x);
                atomicAdd(ap + 1, run.y);
                atomicAdd(ap + 2, run.z);
                atomicAdd(ap + 3, run.w);
                run = make_float4(0.f, 0.f, 0.f, 0.f);
                cur = d2;
            }
            run.x += v.x; run.y += v.y; run.z += v.z; run.w += v.w;
        }
        float* ap = &agg[(size_t)cur * HID + c0];
        atomicAdd(ap + 0, run.x);
        atomicAdd(ap + 1, run.y);
        atomicAdd(ap + 2, run.z);
        atomicAdd(ap + 3, run.w);
    }
}

// ---------------- residual update (fast path: denom from rowptr); re-zero agg ----------------
__global__ void update_kernel_csr(float* __restrict__ node, float* __restrict__ agg,
                                  const int* __restrict__ rowptr)
{
    int i = blockIdx.x * blockDim.x + threadIdx.x;
    if (i < NNODES * HID) {
        int n = i >> 7;
        float cnt = (float)(rowptr[n + 1] - rowptr[n]);
        node[i] += agg[i] / fmaxf(cnt, 1.0f);
        agg[i] = 0.f;
    }
}

// ---------------- decoder: 128->128->128->2 ----------------
__global__ __launch_bounds__(128) void decoder_kernel(
    const float* __restrict__ node,
    const float* __restrict__ W1, const float* __restrict__ b1,
    const float* __restrict__ W2, const float* __restrict__ b2,
    const float* __restrict__ W3, const float* __restrict__ b3,
    float* __restrict__ out)
{
    __shared__ float xs[16][HID];
    __shared__ float h1[16][HID];
    __shared__ float h2[16][HID];
    const int t = threadIdx.x;
    const int base = blockIdx.x * 16;

    for (int i = t; i < 16 * 32; i += 128) {
        int e = i >> 5, c = (i & 31) << 2;
        *(float4*)&xs[e][c] = *(const float4*)&node[(size_t)(base + e) * HID + c];
    }
    __syncthreads();
    {
        const float bb = b1[t];
        for (int e = 0; e < 16; ++e) {
            float acc = bb;
            for (int k = 0; k < HID; ++k) acc += xs[e][k] * W1[k * HID + t];
            h1[e][t] = fmaxf(acc, 0.f);
        }
    }
    __syncthreads();
    {
        const float bb = b2[t];
        for (int e = 0; e < 16; ++e) {
            float acc = bb;
            for (int k = 0; k < HID; ++k) acc += h1[e][k] * W2[k * HID + t];
            h2[e][t] = fmaxf(acc, 0.f);
        }
    }
    __syncthreads();
    if (t < 32) {
        const int e = t >> 1, o = t & 1;
        float acc = b3[o];
        for (int k = 0; k < HID; ++k) acc += h2[e][k] * W3[k * 2 + o];
        out[(size_t)(base + e) * 2 + o] = acc;
    }
}

// ================= fallback (RECOMP fp32 path, proven rounds 2-3) =================
__global__ void degree_kernel(const int* __restrict__ dst, float* __restrict__ cnt)
{
    int i = blockIdx.x * blockDim.x + threadIdx.x;
    if (i < NEDGES) {
        int d = min(max(dst[i], 0), NNODES - 1);
        atomicAdd(&cnt[d], 1.0f);
    }
}

__global__ void update_kernel_cnt(float* __restrict__ node, float* __restrict__ agg,
                                  const float* __restrict__ cnt)
{
    int i = blockIdx.x * blockDim.x + threadIdx.x;
    if (i < NNODES * HID) {
        int n = i >> 7;
        node[i] += agg[i] / fmaxf(cnt[n], 1.0f);
        agg[i] = 0.f;
    }
}

__global__ __launch_bounds__(128) void fuse_kernel(
    const float* __restrict__ eW3, const float* __restrict__ eb3,
    const float* __restrict__ pW1, const float* __restrict__ pb1,
    float* __restrict__ Wc, float* __restrict__ g)
{
    const int l = blockIdx.x >> 3;
    const int s = blockIdx.x & 7;
    const int c = threadIdx.x;
    const float* W1l = pW1 + (size_t)l * 2 * HID * HID;
    float* Wcl = Wc + (size_t)l * 2 * HID * HID;

    for (int r = s * 16; r < s * 16 + 16; ++r)
        Wcl[r * HID + c] = W1l[r * HID + c];

    for (int m = s * 16; m < s * 16 + 16; ++m) {
        float a0 = 0.f, a1 = 0.f, a2 = 0.f, a3 = 0.f;
        for (int k = 0; k < HID; k += 4) {
            a0 += eW3[m * HID + k + 0] * W1l[(HID + k + 0) * HID + c];
            a1 += eW3[m * HID + k + 1] * W1l[(HID + k + 1) * HID + c];
            a2 += eW3[m * HID + k + 2] * W1l[(HID + k + 2) * HID + c];
            a3 += eW3[m * HID + k + 3] * W1l[(HID + k + 3) * HID + c];
        }
        Wcl[(HID + m) * HID + c] = (a0 + a1) + (a2 + a3);
    }
    if (s == 0) {
        float a = pb1[l * HID + c];
        for (int k = 0; k < HID; ++k)
            a += eb3[k] * W1l[(HID + k) * HID + c];
        g[l * HID + c] = a;
    }
}

__global__ __launch_bounds__(256) void msg_recomp(
    const float* __restrict__ node,
    const float* __restrict__ edge_attr,
    const float* __restrict__ eW1, const float* __restrict__ eb1,
    const float* __restrict__ eW2, const float* __restrict__ eb2,
    const int* __restrict__ src_idx, const int* __restrict__ dst_idx,
    const float* __restrict__ W1, const float* __restrict__ b1,
    const float* __restrict__ W2, const float* __restrict__ b2,
    const float* __restrict__ W3, const float* __restrict__ b3,
    float* __restrict__ agg)
{
    __shared__ float X[32][256];
    __shared__ float H[32][HID];
    __shared__ int ssrc[32];
    __shared__ int sdst[32];
    __shared__ float ea_s[32][4];

    const int t = threadIdx.x;
    const int eb = blockIdx.x * 32;

    if (t < 32) { int s = src_idx[eb + t]; ssrc[t] = min(max(s, 0), NNODES - 1); }
    else if (t < 64) { int d = dst_idx[eb + (t - 32)]; sdst[t - 32] = min(max(d, 0), NNODES - 1); }
    __syncthreads();

    for (int i = t; i < 32 * 32; i += 256) {
        int e = i >> 5; int c = (i & 31) << 2;
        *(float4*)&X[e][c] = *(const float4*)&node[(size_t)ssrc[e] * HID + c];
    }
    for (int i = t; i < 32 * 3; i += 256)
        ea_s[i / 3][i % 3] = edge_attr[(size_t)(eb + i / 3) * 3 + (i % 3)];
    __syncthreads();

    const int ct = t & 31;
    const int et = (t >> 5) << 2;
    const int cb = ct << 2;
    float acc[4][4];

    {
        const float4 bv = *(const float4*)&eb1[cb];
        #pragma unroll
        for (int j = 0; j < 4; ++j) { acc[j][0] = bv.x; acc[j][1] = bv.y; acc[j][2] = bv.z; acc[j][3] = bv.w; }
        #pragma unroll
        for (int k = 0; k < 3; ++k) {
            const float4 wv = *(const float4*)&eW1[k * HID + cb];
            #pragma unroll
            for (int j = 0; j < 4; ++j) {
                const float xx = ea_s[et + j][k];
                acc[j][0] += xx * wv.x; acc[j][1] += xx * wv.y; acc[j][2] += xx * wv.z; acc[j][3] += xx * wv.w;
            }
        }
        #pragma unroll
        for (int j = 0; j < 4; ++j)
            *(float4*)&H[et + j][cb] = make_float4(fmaxf(acc[j][0],0.f), fmaxf(acc[j][1],0.f), fmaxf(acc[j][2],0.f), fmaxf(acc[j][3],0.f));
    }
    __syncthreads();
    {
        const float4 bv = *(const float4*)&eb2[cb];
        #pragma unroll
        for (int j = 0; j < 4; ++j) { acc[j][0] = bv.x; acc[j][1] = bv.y; acc[j][2] = bv.z; acc[j][3] = bv.w; }
        for (int k = 0; k < HID; ++k) {
            const float4 wv = *(const float4*)&eW2[k * HID + cb];
            const float x0 = H[et+0][k], x1 = H[et+1][k], x2 = H[et+2][k], x3 = H[et+3][k];
            acc[0][0]+=x0*wv.x; acc[0][1]+=x0*wv.y; acc[0][2]+=x0*wv.z; acc[0][3]+=x0*wv.w;
            acc[1][0]+=x1*wv.x; acc[1][1]+=x1*wv.y; acc[1][2]+=x1*wv.z; acc[1][3]+=x1*wv.w;
            acc[2][0]+=x2*wv.x; acc[2][1]+=x2*wv.y; acc[2][2]+=x2*wv.z; acc[2][3]+=x2*wv.w;
            acc[3][0]+=x3*wv.x; acc[3][1]+=x3*wv.y; acc[3][2]+=x3*wv.z; acc[3][3]+=x3*wv.w;
        }
        #pragma unroll
        for (int j = 0; j < 4; ++j)
            *(float4*)&X[et + j][HID + cb] = make_float4(fmaxf(acc[j][0],0.f), fmaxf(acc[j][1],0.f), fmaxf(acc[j][2],0.f), fmaxf(acc[j][3],0.f));
    }
    __syncthreads();
    {
        const float4 bv = *(const float4*)&b1[cb];
        #pragma unroll
        for (int j = 0; j < 4; ++j) { acc[j][0] = bv.x; acc[j][1] = bv.y; acc[j][2] = bv.z; acc[j][3] = bv.w; }
        for (int k = 0; k < 256; ++k) {
            const float4 wv = *(const float4*)&W1[k * HID + cb];
            const float x0 = X[et+0][k], x1 = X[et+1][k], x2 = X[et+2][k], x3 = X[et+3][k];
            acc[0][0]+=x0*wv.x; acc[0][1]+=x0*wv.y; acc[0][2]+=x0*wv.z; acc[0][3]+=x0*wv.w;
            acc[1][0]+=x1*wv.x; acc[1][1]+=x1*wv.y; acc[1][2]+=x1*wv.z; acc[1][3]+=x1*wv.w;
            acc[2][0]+=x2*wv.x; acc[2][1]+=x2*wv.y; acc[2][2]+=x2*wv.z; acc[2][3]+=x2*wv.w;
            acc[3][0]+=x3*wv.x; acc[3][1]+=x3*wv.y; acc[3][2]+=x3*wv.z; acc[3][3]+=x3*wv.w;
        }
        __syncthreads();
        #pragma unroll
        for (int j = 0; j < 4; ++j)
            *(float4*)&H[et + j][cb] = make_float4(fmaxf(acc[j][0],0.f), fmaxf(acc[j][1],0.f), fmaxf(acc[j][2],0.f), fmaxf(acc[j][3],0.f));
    }
    __syncthreads();
    float* Xf = &X[0][0];
    {
        const float4 bv = *(const float4*)&b2[cb];
        #pragma unroll
        for (int j = 0; j < 4; ++j) { acc[j][0] = bv.x; acc[j][1] = bv.y; acc[j][2] = bv.z; acc[j][3] = bv.w; }
        for (int k = 0; k < HID; ++k) {
            const float4 wv = *(const float4*)&W2[k * HID + cb];
            const float x0 = H[et+0][k], x1 = H[et+1][k], x2 = H[et+2][k], x3 = H[et+3][k];
            acc[0][0]+=x0*wv.x; acc[0][1]+=x0*wv.y; acc[0][2]+=x0*wv.z; acc[0][3]+=x0*wv.w;
            acc[1][0]+=x1*wv.x; acc[1][1]+=x1*wv.y; acc[1][2]+=x1*wv.z; acc[1][3]+=x1*wv.w;
            acc[2][0]+=x2*wv.x; acc[2][1]+=x2*wv.y; acc[2][2]+=x2*wv.z; acc[2][3]+=x2*wv.w;
            acc[3][0]+=x3*wv.x; acc[3][1]+=x3*wv.y; acc[3][2]+=x3*wv.z; acc[3][3]+=x3*wv.w;
        }
        #pragma unroll
        for (int j = 0; j < 4; ++j)
            *(float4*)&Xf[(et + j) * HID + cb] = make_float4(fmaxf(acc[j][0],0.f), fmaxf(acc[j][1],0.f), fmaxf(acc[j][2],0.f), fmaxf(acc[j][3],0.f));
    }
    __syncthreads();
    {
        const float4 bv = *(const float4*)&b3[cb];
        #pragma unroll
        for (int j = 0; j < 4; ++j) { acc[j][0] = bv.x; acc[j][1] = bv.y; acc[j][2] = bv.z; acc[j][3] = bv.w; }
        for (int k = 0; k < HID; ++k) {
            const float4 wv = *(const float4*)&W3[k * HID + cb];
            const float x0 = Xf[(et+0)*HID+k], x1 = Xf[(et+1)*HID+k];
            const float x2 = Xf[(et+2)*HID+k], x3 = Xf[(et+3)*HID+k];
            acc[0][0]+=x0*wv.x; acc[0][1]+=x0*wv.y; acc[0][2]+=x0*wv.z; acc[0][3]+=x0*wv.w;
            acc[1][0]+=x1*wv.x; acc[1][1]+=x1*wv.y; acc[1][2]+=x1*wv.z; acc[1][3]+=x1*wv.w;
            acc[2][0]+=x2*wv.x; acc[2][1]+=x2*wv.y; acc[2][2]+=x2*wv.z; acc[2][3]+=x2*wv.w;
            acc[3][0]+=x3*wv.x; acc[3][1]+=x3*wv.y; acc[3][2]+=x3*wv.z; acc[3][3]+=x3*wv.w;
        }
        #pragma unroll
        for (int j = 0; j < 4; ++j) {
            const int d = sdst[et + j];
            float* ap = &agg[(size_t)d * HID + cb];
            atomicAdd(ap + 0, acc[j][0]);
            atomicAdd(ap + 1, acc[j][1]);
            atomicAdd(ap + 2, acc[j][2]);
            atomicAdd(ap + 3, acc[j][3]);
        }
    }
}

extern "C" void kernel_launch(void* const* d_in, const int* in_sizes, int n_in,
                              void* d_out, int out_size, void* d_ws, size_t ws_size,
                              hipStream_t stream)
{
    const float* x         = (const float*)d_in[0];
    const float* edge_attr = (const float*)d_in[1];
    const float* nW1 = (const float*)d_in[2];  const float* nb1 = (const float*)d_in[3];
    const float* nW2 = (const float*)d_in[4];  const float* nb2 = (const float*)d_in[5];
    const float* nW3 = (const float*)d_in[6];  const float* nb3 = (const float*)d_in[7];
    const float* eW1 = (const float*)d_in[8];  const float* eb1 = (const float*)d_in[9];
    const float* eW2 = (const float*)d_in[10]; const float* eb2 = (const float*)d_in[11];
    const float* eW3 = (const float*)d_in[12]; const float* eb3 = (const float*)d_in[13];
    const float* pW1 = (const float*)d_in[14]; const float* pb1 = (const float*)d_in[15];
    const float* pW2 = (const float*)d_in[16]; const float* pb2 = (const float*)d_in[17];
    const float* pW3 = (const float*)d_in[18]; const float* pb3 = (const float*)d_in[19];
    const float* dW1 = (const float*)d_in[20]; const float* db1 = (const float*)d_in[21];
    const float* dW2 = (const float*)d_in[22]; const float* db2 = (const float*)d_in[23];
    const float* dW3 = (const float*)d_in[24]; const float* db3 = (const float*)d_in[25];
    const int* ei  = (const int*)d_in[26];
    const int* src = ei;
    const int* dst = ei + NEDGES;

    // fast-path workspace layout (bytes)
    char* ws = (char*)d_ws;
    float* node    = (float*)(ws);                     // 10,240,000
    float* agg     = (float*)(ws + 10240000);          // 10,240,000
    int*   cnt_i   = (int*)  (ws + 20480000);          //     80,000
    int*   fill    = (int*)  (ws + 20560000);          //     80,000
    int*   rowptr  = (int*)  (ws + 20640000);          //     80,064
    float* gb      = (float*)(ws + 20720064);          //      5,120
    uint4* wfrag   = (uint4*)(ws + 20725184);          //  2,621,440
    uint4* ewf     = (uint4*)(ws + 23346624);          //     65,536
    int*   seid    = (int*)  (ws + 23412160);          //  2,560,000
    unsigned short* ssrc16 = (unsigned short*)(ws + 25972160);  // 1,280,000
    unsigned short* sdst16 = (unsigned short*)(ws + 27252160);  // 1,280,000
    uint4* h2img   = (uint4*)(ws + 28532160);          // 163,840,000 (MAT only)
    const size_t NEED_FAST = 28532160ull;
    const size_t NEED_MAT  = 28532160ull + 163840000ull;   // 192,372,160

    // fp32 fallback layout (proven fits)
    float* cntf = (float*)(ws + 20480000);
    float* Wc   = (float*)(ws + 20560000);
    float* gb2  = (float*)(ws + 21870720);

    const bool fast = (ws_size >= NEED_FAST);
    const bool mat  = (ws_size >= NEED_MAT);

    encoder_kernel<16, 2><<<NNODES / 16, 128, 0, stream>>>(
        x, nW1, nb1, nW2, nb2, nW3, nb3, node, NNODES);

    if (fast) {
        hipMemsetAsync(ws + 10240000, 0, 10240000 + 160000, stream);

        hist_kernel<<<(NEDGES + 255) / 256, 256, 0, stream>>>(dst, cnt_i);
        scan_kernel<<<1, 1024, 0, stream>>>(cnt_i, rowptr);
        scatter_kernel<<<(NEDGES + 255) / 256, 256, 0, stream>>>(
            src, dst, rowptr, fill, seid, ssrc16, sdst16);

        wprep_kernel<<<(NSTEPS * 16384 + 4096) / 256, 256, 0, stream>>>(
            eW3, pW1, pW2, pW3, eW2, wfrag);
        gfuse_kernel<<<NSTEPS, 128, 0, stream>>>(eb3, pW1, pb1, gb);

        if (mat) {
            h2prep_kernel<<<NEDGES / 128, 256, 0, stream>>>(
                edge_attr, eW1, eb1, eb2, ewf, seid, h2img);
            for (int l = 0; l < NSTEPS; ++l) {
                msg_mfma_m<<<NEDGES / 128, 256, 0, stream>>>(
                    node, h2img, wfrag + (size_t)l * 16384,
                    ssrc16, sdst16,
                    gb + l * HID, pb2 + l * HID, pb3 + l * HID, agg);
                update_kernel_csr<<<(NNODES * HID) / 256, 256, 0, stream>>>(node, agg, rowptr);
            }
        } else {
            for (int l = 0; l < NSTEPS; ++l) {
                msg_mfma_s<<<NEDGES / 128, 256, 0, stream>>>(
                    node, edge_attr, eW1, eb1, eb2,
                    ewf, wfrag + (size_t)l * 16384,
                    seid, ssrc16, sdst16,
                    gb + l * HID, pb2 + l * HID, pb3 + l * HID, agg);
                update_kernel_csr<<<(NNODES * HID) / 256, 256, 0, stream>>>(node, agg, rowptr);
            }
        }
    } else {
        hipMemsetAsync(ws + 10240000, 0, 10240000 + 80000, stream);
        degree_kernel<<<(NEDGES + 255) / 256, 256, 0, stream>>>(dst, cntf);
        fuse_kernel<<<NSTEPS * 8, 128, 0, stream>>>(eW3, eb3, pW1, pb1, Wc, gb2);
        for (int l = 0; l < NSTEPS; ++l) {
            msg_recomp<<<NEDGES / 32, 256, 0, stream>>>(
                node, edge_attr, eW1, eb1, eW2, eb2, src, dst,
                Wc + (size_t)l * 2 * HID * HID,  gb2 + l * HID,
                pW2 + (size_t)l * HID * HID,     pb2 + l * HID,
                pW3 + (size_t)l * HID * HID,     pb3 + l * HID,
                agg);
            update_kernel_cnt<<<(NNODES * HID) / 256, 256, 0, stream>>>(node, agg, cntf);
        }
    }

    decoder_kernel<<<NNODES / 16, 128, 0, stream>>>(
        node, dW1, db1, dW2, db2, dW3, db3, (float*)d_out);
}

// Round 11
// 2289.067 us; speedup vs baseline: 1.9663x; 1.2756x over previous
//
#include <hip/hip_runtime.h>

#define HID     128
#define NNODES  20000
#define NEDGES  640000
#define NSTEPS  10

typedef __attribute__((ext_vector_type(8)))  short short8;
typedef __attribute__((ext_vector_type(16))) float f32x16;

union Frag { short8 s; uint4 q; uint u[4]; };
union Acc  { f32x16 v; float f[16]; };

#define MFMA(a,b,c) __builtin_amdgcn_mfma_f32_32x32x16_bf16((a),(b),(c),0,0,0)

// split 4 fp32 into bf16 hi-plane pair-u32s and lo-plane pair-u32s (truncation)
static __device__ inline void pack4(const float v0, const float v1,
                                    const float v2, const float v3,
                                    uint2& hi, uint2& lo)
{
    const uint h0 = __float_as_uint(v0) & 0xFFFF0000u;
    const uint h1 = __float_as_uint(v1) & 0xFFFF0000u;
    const uint h2 = __float_as_uint(v2) & 0xFFFF0000u;
    const uint h3 = __float_as_uint(v3) & 0xFFFF0000u;
    hi.x = (h0 >> 16) | h1;
    hi.y = (h2 >> 16) | h3;
    lo.x = (__float_as_uint(v0 - __uint_as_float(h0)) >> 16)
         | (__float_as_uint(v1 - __uint_as_float(h1)) & 0xFFFF0000u);
    lo.y = (__float_as_uint(v2 - __uint_as_float(h2)) >> 16)
         | (__float_as_uint(v3 - __uint_as_float(h3)) & 0xFFFF0000u);
}

// RNE bf16 (unbiased)
static __device__ inline uint rne16(float x)
{
    const uint u = __float_as_uint(x);
    return (u + 0x7FFFu + ((u >> 16) & 1u)) >> 16;
}

// ---------------- node encoder (KIN=16, skip first 2 feats) ----------------
template<int KIN, int KSTART>
__global__ __launch_bounds__(128) void encoder_kernel(
    const float* __restrict__ in,
    const float* __restrict__ W1, const float* __restrict__ b1,
    const float* __restrict__ W2, const float* __restrict__ b2,
    const float* __restrict__ W3, const float* __restrict__ b3,
    float* __restrict__ out, int n)
{
    __shared__ float xs[16][(KIN < 4) ? 4 : KIN];
    __shared__ float h1[16][HID];
    __shared__ float h2[16][HID];
    const int t = threadIdx.x;
    const int base = blockIdx.x * 16;

    for (int i = t; i < 16 * KIN; i += 128) {
        int e = i / KIN, k = i % KIN;
        int g = base + e;
        xs[e][k] = (g < n) ? in[(size_t)g * KIN + k] : 0.f;
    }
    __syncthreads();
    {
        const float bb = b1[t];
        for (int e = 0; e < 16; ++e) {
            float acc = bb;
            #pragma unroll
            for (int k = KSTART; k < KIN; ++k) acc += xs[e][k] * W1[k * HID + t];
            h1[e][t] = fmaxf(acc, 0.f);
        }
    }
    __syncthreads();
    {
        const float bb = b2[t];
        for (int e = 0; e < 16; ++e) {
            float acc = bb;
            for (int k = 0; k < HID; ++k) acc += h1[e][k] * W2[k * HID + t];
            h2[e][t] = fmaxf(acc, 0.f);
        }
    }
    __syncthreads();
    {
        const float bb = b3[t];
        for (int e = 0; e < 16; ++e) {
            int g = base + e;
            if (g >= n) continue;
            float acc = bb;
            for (int k = 0; k < HID; ++k) acc += h2[e][k] * W3[k * HID + t];
            out[(size_t)g * HID + t] = acc;
        }
    }
}

// ---------------- weight repack to A-frag layout (hi/lo planes) ----------------
__global__ __launch_bounds__(256) void wprep_kernel(
    const float* __restrict__ eW3,
    const float* __restrict__ pW1, const float* __restrict__ pW2,
    const float* __restrict__ pW3, const float* __restrict__ eW2,
    uint4* __restrict__ out)
{
    const int gid = blockIdx.x * 256 + threadIdx.x;
    if (gid >= NSTEPS * 16384 + 4096) return;

    int layer, rr, sid = 0;
    if (gid >= NSTEPS * 16384) { layer = 3; rr = gid - NSTEPS * 16384; }
    else {
        sid = gid / 16384;
        const int r = gid % 16384;
        if (r < 8192)       { layer = 0; rr = r; }
        else if (r < 12288) { layer = 1; rr = r - 8192; }
        else                { layer = 2; rr = r - 12288; }
    }
    const int ks  = rr >> 9;
    const int rem = rr & 511;
    const int rb  = rem >> 7;
    const int pl  = (rem >> 6) & 1;
    const int l   = rem & 63;
    const int c   = rb * 32 + (l & 31);
    const int k0  = ks * 16 + 8 * (l >> 5);

    float vals[8];
    if (layer == 0 && ks >= 8) {
        const float* W1l = pW1 + (size_t)sid * 2 * HID * HID;
        #pragma unroll
        for (int j = 0; j < 8; ++j) vals[j] = 0.f;
        const int kp = k0 - HID;
        for (int k = 0; k < HID; ++k) {
            const float wv = W1l[(size_t)(HID + k) * HID + c];
            #pragma unroll
            for (int j = 0; j < 8; ++j)
                vals[j] += eW3[(size_t)(kp + j) * HID + k] * wv;
        }
    } else {
        const float* Wsrc =
            (layer == 0) ? pW1 + (size_t)sid * 2 * HID * HID :
            (layer == 1) ? pW2 + (size_t)sid * HID * HID :
            (layer == 2) ? pW3 + (size_t)sid * HID * HID : eW2;
        #pragma unroll
        for (int j = 0; j < 8; ++j)
            vals[j] = Wsrc[(size_t)(k0 + j) * HID + c];
    }

    uint b16[8];
    #pragma unroll
    for (int j = 0; j < 8; ++j) {
        const uint hx = __float_as_uint(vals[j]) & 0xFFFF0000u;
        b16[j] = (pl == 0) ? (hx >> 16)
                           : (__float_as_uint(vals[j] - __uint_as_float(hx)) >> 16);
    }
    uint4 o;
    o.x = b16[0] | (b16[1] << 16);
    o.y = b16[2] | (b16[3] << 16);
    o.z = b16[4] | (b16[5] << 16);
    o.w = b16[6] | (b16[7] << 16);
    out[gid] = o;
}

// ---------------- fused L1 bias: g = pb1 + eb3 @ W1_lower ----------------
__global__ __launch_bounds__(128) void gfuse_kernel(
    const float* __restrict__ eb3, const float* __restrict__ pW1,
    const float* __restrict__ pb1, float* __restrict__ g)
{
    const int l = blockIdx.x, c = threadIdx.x;
    const float* W1l = pW1 + (size_t)l * 2 * HID * HID;
    float a = pb1[l * HID + c];
    for (int k = 0; k < HID; ++k)
        a += eb3[k] * W1l[(size_t)(HID + k) * HID + c];
    g[l * HID + c] = a;
}

// ---------------- CSR sort: histogram -> scan -> scatter ----------------
__global__ void hist_kernel(const int* __restrict__ dst, int* __restrict__ cnt)
{
    int i = blockIdx.x * blockDim.x + threadIdx.x;
    if (i < NEDGES) {
        int d = min(max(dst[i], 0), NNODES - 1);
        atomicAdd(&cnt[d], 1);
    }
}

__global__ __launch_bounds__(1024) void scan_kernel(
    const int* __restrict__ cnt, int* __restrict__ rowptr)
{
    __shared__ int part[1024];
    const int t = threadIdx.x;
    int vals[20];
    int s = 0;
    const int base = t * 20;
    #pragma unroll
    for (int j = 0; j < 20; ++j) {
        int idx = base + j;
        int v = (idx < NNODES) ? cnt[idx] : 0;
        vals[j] = s;
        s += v;
    }
    part[t] = s;
    __syncthreads();
    for (int off = 1; off < 1024; off <<= 1) {
        int v = (t >= off) ? part[t - off] : 0;
        __syncthreads();
        part[t] += v;
        __syncthreads();
    }
    const int pre = (t == 0) ? 0 : part[t - 1];
    #pragma unroll
    for (int j = 0; j < 20; ++j) {
        int idx = base + j;
        if (idx < NNODES) rowptr[idx] = pre + vals[j];
    }
    if (t == 0) rowptr[NNODES] = NEDGES;
}

__global__ void scatter_kernel(
    const int* __restrict__ src, const int* __restrict__ dst,
    const int* __restrict__ rowptr, int* __restrict__ fill,
    int* __restrict__ seid, unsigned short* __restrict__ ssrc,
    unsigned short* __restrict__ sdst)
{
    int i = blockIdx.x * blockDim.x + threadIdx.x;
    if (i < NEDGES) {
        int d = min(max(dst[i], 0), NNODES - 1);
        int s = min(max(src[i], 0), NNODES - 1);
        int pos = rowptr[d] + atomicAdd(&fill[d], 1);
        seid[pos] = i;
        ssrc[pos] = (unsigned short)s;
        sdst[pos] = (unsigned short)d;
    }
}

// ---------------- MFMA phase, hi/lo-B version (used by h2prep + msg_mfma_s) ----------------
template<int NKS, bool HASLO>
static __device__ inline void run_phaseT(
    const uint4* __restrict__ wf, int rb, int l, int g, int l31,
    const uint* __restrict__ PH, const uint* __restrict__ PL,
    Acc& ac0, Acc& ac1, Acc& ac2, Acc& ac3)
{
    Frag wbuf[4][2];
    Frag bh[2][4], bl[2][4];
    auto loadW = [&](int ks, int slot) {
        const uint4* wbase = wf + (size_t)(ks * 4 + rb) * 2 * 64;
        wbuf[slot][0].q = wbase[l];
        wbuf[slot][1].q = wbase[64 + l];
    };
    auto loadB = [&](int ks, int slot) {
        const int sl = ((ks * 16 + 8 * g) >> 3);
        const int bo = l31 * 64 + ((sl ^ (l31 & 15)) << 2);
        #pragma unroll
        for (int gi = 0; gi < 4; ++gi) {
            bh[slot][gi].q = *(const uint4*)&PH[bo + gi * 2048];
            if (HASLO) bl[slot][gi].q = *(const uint4*)&PL[bo + gi * 2048];
        }
    };
    loadW(0, 0);
    loadB(0, 0);
    if (NKS > 1) loadW(1, 1);
    if (NKS > 2) loadW(2, 2);
    if (NKS > 3) loadW(3, 3);
    #pragma unroll
    for (int ks = 0; ks < NKS; ++ks) {
        if (ks + 1 < NKS) loadB(ks + 1, (ks + 1) & 1);
        Frag& ah = wbuf[ks & 3][0];
        Frag& al = wbuf[ks & 3][1];
        const int s = ks & 1;
        __builtin_amdgcn_s_setprio(1);
        ac0.v = MFMA(ah.s, bh[s][0].s, ac0.v);
        ac1.v = MFMA(ah.s, bh[s][1].s, ac1.v);
        ac2.v = MFMA(ah.s, bh[s][2].s, ac2.v);
        ac3.v = MFMA(ah.s, bh[s][3].s, ac3.v);
        ac0.v = MFMA(al.s, bh[s][0].s, ac0.v);
        ac1.v = MFMA(al.s, bh[s][1].s, ac1.v);
        ac2.v = MFMA(al.s, bh[s][2].s, ac2.v);
        ac3.v = MFMA(al.s, bh[s][3].s, ac3.v);
        if (HASLO) {
            ac0.v = MFMA(ah.s, bl[s][0].s, ac0.v);
            ac1.v = MFMA(ah.s, bl[s][1].s, ac1.v);
            ac2.v = MFMA(ah.s, bl[s][2].s, ac2.v);
            ac3.v = MFMA(ah.s, bl[s][3].s, ac3.v);
        }
        __builtin_amdgcn_s_setprio(0);
        if (ks + 4 < NKS) loadW(ks + 4, ks & 3);
    }
}

// ---------------- MFMA phase, hi-only-B (2 MFMA/product): the round-11 core ----------------
template<int NKS>
static __device__ inline void run_phase2(
    const uint4* __restrict__ wf, int rb, int l, int g, int l31,
    const uint4* __restrict__ P4,
    Acc& ac0, Acc& ac1, Acc& ac2, Acc& ac3)
{
    Frag wbuf[4][2];
    Frag bh[2][4];
    auto loadW = [&](int ks, int slot) {
        const uint4* wbase = wf + (size_t)(ks * 4 + rb) * 2 * 64;
        wbuf[slot][0].q = wbase[l];
        wbuf[slot][1].q = wbase[64 + l];
    };
    auto loadB = [&](int ks, int slot) {
        const int sl = ks * 2 + g;
        const int bo = l31 * 16 + (sl ^ (l31 & 15));
        #pragma unroll
        for (int gi = 0; gi < 4; ++gi)
            bh[slot][gi].q = P4[bo + gi * 512];
    };
    loadW(0, 0);
    loadB(0, 0);
    if (NKS > 1) loadW(1, 1);
    if (NKS > 2) loadW(2, 2);
    if (NKS > 3) loadW(3, 3);
    #pragma unroll
    for (int ks = 0; ks < NKS; ++ks) {
        if (ks + 1 < NKS) loadB(ks + 1, (ks + 1) & 1);
        Frag& ah = wbuf[ks & 3][0];
        Frag& al = wbuf[ks & 3][1];
        const int s = ks & 1;
        __builtin_amdgcn_s_setprio(1);
        ac0.v = MFMA(ah.s, bh[s][0].s, ac0.v);
        ac1.v = MFMA(ah.s, bh[s][1].s, ac1.v);
        ac2.v = MFMA(ah.s, bh[s][2].s, ac2.v);
        ac3.v = MFMA(ah.s, bh[s][3].s, ac3.v);
        ac0.v = MFMA(al.s, bh[s][0].s, ac0.v);
        ac1.v = MFMA(al.s, bh[s][1].s, ac1.v);
        ac2.v = MFMA(al.s, bh[s][2].s, ac2.v);
        ac3.v = MFMA(al.s, bh[s][3].s, ac3.v);
        __builtin_amdgcn_s_setprio(0);
        if (ks + 4 < NKS) loadW(ks + 4, ks & 3);
    }
}

// epilogue: bias (+relu), hi/lo store (fallback path)
static __device__ inline void epi_store(
    uint* __restrict__ PH, uint* __restrict__ PL, int rb, int e, int g,
    const Acc& a, const float* __restrict__ bias, bool relu)
{
    #pragma unroll
    for (int q = 0; q < 4; ++q) {
        const int c0 = rb * 32 + q * 8 + 4 * g;
        const float4 bv = *(const float4*)&bias[c0];
        float v0 = a.f[q*4+0] + bv.x;
        float v1 = a.f[q*4+1] + bv.y;
        float v2 = a.f[q*4+2] + bv.z;
        float v3 = a.f[q*4+3] + bv.w;
        if (relu) { v0 = fmaxf(v0, 0.f); v1 = fmaxf(v1, 0.f); v2 = fmaxf(v2, 0.f); v3 = fmaxf(v3, 0.f); }
        uint2 hi, lo;
        pack4(v0, v1, v2, v3, hi, lo);
        const int off = e * 64 + ((((c0 >> 3) ^ (e & 15))) << 2) + g * 2;
        *(uint2*)&PH[off] = hi;
        *(uint2*)&PL[off] = lo;
    }
}

// epilogue: bias + relu, RNE hi-only store into single plane
static __device__ inline void epi_storeh(
    uint* __restrict__ P, int rb, int e, int g,
    const Acc& a, const float* __restrict__ bias)
{
    #pragma unroll
    for (int q = 0; q < 4; ++q) {
        const int c0 = rb * 32 + q * 8 + 4 * g;
        const float4 bv = *(const float4*)&bias[c0];
        const float v0 = fmaxf(a.f[q*4+0] + bv.x, 0.f);
        const float v1 = fmaxf(a.f[q*4+1] + bv.y, 0.f);
        const float v2 = fmaxf(a.f[q*4+2] + bv.z, 0.f);
        const float v3 = fmaxf(a.f[q*4+3] + bv.w, 0.f);
        uint2 hi;
        hi.x = rne16(v0) | (rne16(v1) << 16);
        hi.y = rne16(v2) | (rne16(v3) << 16);
        const int off = (e * 16 + (((c0 >> 3)) ^ (e & 15))) * 4 + 2 * g;
        *(uint2*)&P[off] = hi;
    }
}

// ---------------- h2e prep: edge MLP once -> pre-swizzled hi-RNE image ----------------
__global__ __launch_bounds__(256, 2) void h2prep_kernel(
    const float* __restrict__ edge_attr,
    const float* __restrict__ eW1, const float* __restrict__ eb1,
    const float* __restrict__ eb2,
    const uint4* __restrict__ ewfrag,
    const int* __restrict__ seidg,
    uint4* __restrict__ h2img)
{
    __shared__ uint4 pool4[4096];
    __shared__ float eas[384];
    __shared__ int seid[128];
    uint* HH = (uint*)pool4;
    uint* HL = (uint*)(pool4 + 2048);

    const int t   = threadIdx.x;
    const int wv  = t >> 6;
    const int l   = t & 63;
    const int l31 = l & 31;
    const int g   = l >> 5;
    const int rb  = wv;
    const int eb0 = blockIdx.x * 128;

    if (t < 128) seid[t] = seidg[eb0 + t];
    __syncthreads();
    for (int i = t; i < 384; i += 256)
        eas[i] = edge_attr[(size_t)seid[i / 3] * 3 + (i % 3)];
    __syncthreads();

    // h1e = relu(ea @ eW1 + eb1) on VALU -> hi/lo planes
    {
        const int e = t & 127, sb = t >> 7;
        const float a0 = eas[e * 3 + 0], a1 = eas[e * 3 + 1], a2 = eas[e * 3 + 2];
        #pragma unroll
        for (int i = 0; i < 16; ++i) {
            const int s4 = sb * 16 + i;
            const int c0 = s4 * 4;
            const float4 w1 = *(const float4*)&eW1[0 * HID + c0];
            const float4 w2 = *(const float4*)&eW1[1 * HID + c0];
            const float4 w3 = *(const float4*)&eW1[2 * HID + c0];
            const float4 bb = *(const float4*)&eb1[c0];
            const float v0 = fmaxf(bb.x + a0 * w1.x + a1 * w2.x + a2 * w3.x, 0.f);
            const float v1 = fmaxf(bb.y + a0 * w1.y + a1 * w2.y + a2 * w3.y, 0.f);
            const float v2 = fmaxf(bb.z + a0 * w1.z + a1 * w2.z + a2 * w3.z, 0.f);
            const float v3 = fmaxf(bb.w + a0 * w1.w + a1 * w2.w + a2 * w3.w, 0.f);
            uint2 hi, lo;
            pack4(v0, v1, v2, v3, hi, lo);
            const int off = e * 64 + ((((s4 >> 1) ^ (e & 15))) << 2) + (s4 & 1) * 2;
            *(uint2*)&HH[off] = hi;
            *(uint2*)&HL[off] = lo;
        }
    }
    __syncthreads();

    Acc ac0, ac1, ac2, ac3;
    #pragma unroll
    for (int z = 0; z < 16; ++z) { ac0.f[z] = 0.f; ac1.f[z] = 0.f; ac2.f[z] = 0.f; ac3.f[z] = 0.f; }

    run_phaseT<8, true>(ewfrag, rb, l, g, l31, HH, HL, ac0, ac1, ac2, ac3);
    __syncthreads();

    epi_storeh(HH, rb,  0 + l31, g, ac0, eb2);
    epi_storeh(HH, rb, 32 + l31, g, ac1, eb2);
    epi_storeh(HH, rb, 64 + l31, g, ac2, eb2);
    epi_storeh(HH, rb, 96 + l31, g, ac3, eb2);
    __syncthreads();

    // linear coalesced copy of the 32 KB plane image to global
    uint4* dstp = h2img + (size_t)blockIdx.x * 2048;
    const uint4* srcp = (const uint4*)HH;
    #pragma unroll
    for (int i = 0; i < 8; ++i)
        dstp[i * 256 + t] = srcp[i * 256 + t];
}

// ---------------- MFMA message kernel, hi-RNE activations: 128 edges, 33 KB LDS ----------------
__global__ __launch_bounds__(256, 2) void msg_mfma_h(
    const float* __restrict__ node,
    const uint4* __restrict__ h2img,
    const uint4* __restrict__ wfrag,
    const unsigned short* __restrict__ ssrcg,
    const unsigned short* __restrict__ sdstg,
    const float* __restrict__ gb1, const float* __restrict__ b2,
    const float* __restrict__ b3,
    float* __restrict__ agg)
{
    __shared__ uint4 P4[2048];           // 32 KB: act plane / Mf bf16 overlay
    __shared__ int ssrc[128], sdst[128];
    uint* P = (uint*)P4;

    const int t   = threadIdx.x;
    const int wv  = t >> 6;
    const int l   = t & 63;
    const int l31 = l & 31;
    const int g   = l >> 5;
    const int rb  = wv;
    const int eb0 = blockIdx.x * 128;

    if (t < 128) ssrc[t] = ssrcg[eb0 + t];
    else         sdst[t - 128] = sdstg[eb0 + (t - 128)];
    __syncthreads();

    // stage x_j hi-RNE into plane
    #pragma unroll
    for (int i = 0; i < 16; ++i) {
        const int idx = i * 256 + t;         // 4096 float4 (e, q)
        const int ee = idx >> 5, q = idx & 31;
        const float4 v = *(const float4*)&node[(size_t)ssrc[ee] * HID + q * 4];
        uint2 hi;
        hi.x = rne16(v.x) | (rne16(v.y) << 16);
        hi.y = rne16(v.z) | (rne16(v.w) << 16);
        const int c0 = q * 4;
        const int off = (ee * 16 + ((c0 >> 3) ^ (ee & 15))) * 4 + ((c0 >> 1) & 3);
        *(uint2*)&P[off] = hi;
    }
    __syncthreads();

    Acc ac0, ac1, ac2, ac3;
#define ZACC() do { _Pragma("unroll") \
    for (int z = 0; z < 16; ++z) { ac0.f[z] = 0.f; ac1.f[z] = 0.f; ac2.f[z] = 0.f; ac3.f[z] = 0.f; } } while (0)
#define EPI4H(BIAS) do { \
    epi_storeh(P, rb,  0 + l31, g, ac0, (BIAS)); \
    epi_storeh(P, rb, 32 + l31, g, ac1, (BIAS)); \
    epi_storeh(P, rb, 64 + l31, g, ac2, (BIAS)); \
    epi_storeh(P, rb, 96 + l31, g, ac3, (BIAS)); } while (0)

    // ---- L1a: acc = x_j @ Wc_upper ----
    ZACC();
    run_phase2<8>(wfrag, rb, l, g, l31, P4, ac0, ac1, ac2, ac3);
    __syncthreads();

    // ---- load materialized h2e image (linear, coalesced) ----
    {
        const uint4* srcp = h2img + (size_t)blockIdx.x * 2048;
        #pragma unroll
        for (int i = 0; i < 8; ++i)
            P4[i * 256 + t] = srcp[i * 256 + t];
    }
    __syncthreads();

    // ---- L1b: acc += h2e @ Wc_lower ----
    run_phase2<8>(wfrag + 4096, rb, l, g, l31, P4, ac0, ac1, ac2, ac3);
    __syncthreads();
    EPI4H(gb1);
    __syncthreads();

    // ---- L2: h2 = relu(h1 @ W2 + b2) ----
    ZACC();
    run_phase2<8>(wfrag + 8192, rb, l, g, l31, P4, ac0, ac1, ac2, ac3);
    __syncthreads();
    EPI4H(b2);
    __syncthreads();

    // ---- L3: msg = h2 @ W3 + b3 -> Mf bf16-RNE overlay ----
    ZACC();
    run_phase2<8>(wfrag + 12288, rb, l, g, l31, P4, ac0, ac1, ac2, ac3);
    __syncthreads();     // all h2 reads done before overlay
    #pragma unroll
    for (int q = 0; q < 4; ++q) {
        const int c0 = rb * 32 + q * 8 + 4 * g;
        const float4 bva = *(const float4*)&b3[c0];
        const int p0 = c0 >> 1;
        Acc* accs[4] = { &ac0, &ac1, &ac2, &ac3 };
        #pragma unroll
        for (int gi = 0; gi < 4; ++gi) {
            const int e = gi * 32 + l31;
            const float v0 = accs[gi]->f[q*4+0] + bva.x;
            const float v1 = accs[gi]->f[q*4+1] + bva.y;
            const float v2 = accs[gi]->f[q*4+2] + bva.z;
            const float v3 = accs[gi]->f[q*4+3] + bva.w;
            uint2 m;
            m.x = rne16(v0) | (rne16(v1) << 16);
            m.y = rne16(v2) | (rne16(v3) << 16);
            const int off = e * 64 + (p0 ^ ((e & 31) << 1));
            *(uint2*)&P[off] = m;
        }
    }
#undef ZACC
#undef EPI4H
    __syncthreads();

    // ---- segmented sum over sorted dst (bf16 msgs -> fp32 runs -> atomics) ----
    {
        const int grp = t & 31;          // channel group: c0 = grp*4
        const int seg = t >> 5;          // 0..7
        const int c0  = grp << 2;
        const int p0  = c0 >> 1;
        const int es  = seg * 16;
        float4 run = make_float4(0.f, 0.f, 0.f, 0.f);
        int cur = sdst[es];
        for (int e2 = es; e2 < es + 16; ++e2) {
            const int d2 = sdst[e2];
            const uint2 m = *(const uint2*)&P[e2 * 64 + (p0 ^ ((e2 & 31) << 1))];
            if (d2 != cur) {
                float* ap = &agg[(size_t)cur * HID + c0];
                atomicAdd(ap + 0, run.x);
                atomicAdd(ap + 1, run.y);
                atomicAdd(ap + 2, run.z);
                atomicAdd(ap + 3, run.w);
                run = make_float4(0.f, 0.f, 0.f, 0.f);
                cur = d2;
            }
            run.x += __uint_as_float(m.x << 16);
            run.y += __uint_as_float(m.x & 0xFFFF0000u);
            run.z += __uint_as_float(m.y << 16);
            run.w += __uint_as_float(m.y & 0xFFFF0000u);
        }
        float* ap = &agg[(size_t)cur * HID + c0];
        atomicAdd(ap + 0, run.x);
        atomicAdd(ap + 1, run.y);
        atomicAdd(ap + 2, run.z);
        atomicAdd(ap + 3, run.w);
    }
}

// ---------------- mid-fallback: round-9 msg kernel (hi/lo acts, recompute h2e) ----------------
__global__ __launch_bounds__(256, 2) void msg_mfma_s(
    const float* __restrict__ node,
    const float* __restrict__ edge_attr,
    const float* __restrict__ eW1, const float* __restrict__ eb1,
    const float* __restrict__ eb2,
    const uint4* __restrict__ ewfrag,
    const uint4* __restrict__ wfrag,
    const int* __restrict__ seidg,
    const unsigned short* __restrict__ ssrcg,
    const unsigned short* __restrict__ sdstg,
    const float* __restrict__ gb1, const float* __restrict__ b2,
    const float* __restrict__ b3,
    float* __restrict__ agg)
{
    __shared__ uint4 pool4[4096];
    __shared__ float eas[384];
    __shared__ int ssrc[128], sdst[128], seid[128];
    uint* HH = (uint*)pool4;
    uint* HL = (uint*)(pool4 + 2048);
    float* Mf = (float*)pool4;

    const int t   = threadIdx.x;
    const int wv  = t >> 6;
    const int l   = t & 63;
    const int l31 = l & 31;
    const int g   = l >> 5;
    const int rb  = wv;
    const int eb0 = blockIdx.x * 128;

    if (t < 128) { ssrc[t] = ssrcg[eb0 + t]; seid[t] = seidg[eb0 + t]; }
    else         { sdst[t - 128] = sdstg[eb0 + (t - 128)]; }
    __syncthreads();

    for (int i = t; i < 384; i += 256)
        eas[i] = edge_attr[(size_t)seid[i / 3] * 3 + (i % 3)];
    __syncthreads();

    {
        const int e = t & 127, sb = t >> 7;
        const float a0 = eas[e * 3 + 0], a1 = eas[e * 3 + 1], a2 = eas[e * 3 + 2];
        #pragma unroll
        for (int i = 0; i < 16; ++i) {
            const int s4 = sb * 16 + i;
            const int c0 = s4 * 4;
            const float4 w1 = *(const float4*)&eW1[0 * HID + c0];
            const float4 w2 = *(const float4*)&eW1[1 * HID + c0];
            const float4 w3 = *(const float4*)&eW1[2 * HID + c0];
            const float4 bb = *(const float4*)&eb1[c0];
            const float v0 = fmaxf(bb.x + a0 * w1.x + a1 * w2.x + a2 * w3.x, 0.f);
            const float v1 = fmaxf(bb.y + a0 * w1.y + a1 * w2.y + a2 * w3.y, 0.f);
            const float v2 = fmaxf(bb.z + a0 * w1.z + a1 * w2.z + a2 * w3.z, 0.f);
            const float v3 = fmaxf(bb.w + a0 * w1.w + a1 * w2.w + a2 * w3.w, 0.f);
            uint2 hi, lo;
            pack4(v0, v1, v2, v3, hi, lo);
            const int off = e * 64 + ((((s4 >> 1) ^ (e & 15))) << 2) + (s4 & 1) * 2;
            *(uint2*)&HH[off] = hi;
            *(uint2*)&HL[off] = lo;
        }
    }
    __syncthreads();

    Acc ac0, ac1, ac2, ac3;
#define ZACC() do { _Pragma("unroll") \
    for (int z = 0; z < 16; ++z) { ac0.f[z] = 0.f; ac1.f[z] = 0.f; ac2.f[z] = 0.f; ac3.f[z] = 0.f; } } while (0)
#define EPI4(BIAS, RELU) do { \
    epi_store(HH, HL, rb,  0 + l31, g, ac0, (BIAS), (RELU)); \
    epi_store(HH, HL, rb, 32 + l31, g, ac1, (BIAS), (RELU)); \
    epi_store(HH, HL, rb, 64 + l31, g, ac2, (BIAS), (RELU)); \
    epi_store(HH, HL, rb, 96 + l31, g, ac3, (BIAS), (RELU)); } while (0)

    ZACC();
    run_phaseT<8, true>(ewfrag, rb, l, g, l31, HH, HL, ac0, ac1, ac2, ac3);
    __syncthreads();
    EPI4(eb2, true);
    __syncthreads();

    ZACC();
    run_phaseT<8, true>(wfrag + 4096, rb, l, g, l31, HH, HL, ac0, ac1, ac2, ac3);
    __syncthreads();
    #pragma unroll
    for (int i = 0; i < 16; ++i) {
        const int idx = i * 256 + t;
        const int ee = idx >> 5, q = idx & 31;
        const float4 v = *(const float4*)&node[(size_t)ssrc[ee] * HID + q * 4];
        uint2 hi, lo;
        pack4(v.x, v.y, v.z, v.w, hi, lo);
        const int off = ee * 64 + ((((q >> 1) ^ (ee & 15))) << 2) + (q & 1) * 2;
        *(uint2*)&HH[off] = hi;
        *(uint2*)&HL[off] = lo;
    }
    __syncthreads();

    run_phaseT<8, true>(wfrag, rb, l, g, l31, HH, HL, ac0, ac1, ac2, ac3);
    __syncthreads();
    EPI4(gb1, true);
    __syncthreads();

    ZACC();
    run_phaseT<8, true>(wfrag + 8192, rb, l, g, l31, HH, HL, ac0, ac1, ac2, ac3);
    __syncthreads();
    EPI4(b2, true);
    __syncthreads();

    ZACC();
    run_phaseT<8, true>(wfrag + 12288, rb, l, g, l31, HH, HL, ac0, ac1, ac2, ac3);
    __syncthreads();
    #pragma unroll
    for (int q = 0; q < 4; ++q) {
        const int c0 = rb * 32 + q * 8 + 4 * g;
        const float4 bva = *(const float4*)&b3[c0];
        const int sw = c0 ^ ((l31 & 7) << 2);
        float4 v0;
        v0.x = ac0.f[q*4+0] + bva.x; v0.y = ac0.f[q*4+1] + bva.y;
        v0.z = ac0.f[q*4+2] + bva.z; v0.w = ac0.f[q*4+3] + bva.w;
        *(float4*)&Mf[( 0 + l31) * 128 + sw] = v0;
        float4 v1;
        v1.x = ac1.f[q*4+0] + bva.x; v1.y = ac1.f[q*4+1] + bva.y;
        v1.z = ac1.f[q*4+2] + bva.z; v1.w = ac1.f[q*4+3] + bva.w;
        *(float4*)&Mf[(32 + l31) * 128 + sw] = v1;
        float4 v2;
        v2.x = ac2.f[q*4+0] + bva.x; v2.y = ac2.f[q*4+1] + bva.y;
        v2.z = ac2.f[q*4+2] + bva.z; v2.w = ac2.f[q*4+3] + bva.w;
        *(float4*)&Mf[(64 + l31) * 128 + sw] = v2;
        float4 v3;
        v3.x = ac3.f[q*4+0] + bva.x; v3.y = ac3.f[q*4+1] + bva.y;
        v3.z = ac3.f[q*4+2] + bva.z; v3.w = ac3.f[q*4+3] + bva.w;
        *(float4*)&Mf[(96 + l31) * 128 + sw] = v3;
    }
#undef ZACC
#undef EPI4
    __syncthreads();

    {
        const int grp = t & 31;
        const int seg = t >> 5;
        const int c0  = grp << 2;
        const int es  = seg * 16;
        float4 run = make_float4(0.f, 0.f, 0.f, 0.f);
        int cur = sdst[es];
        for (int e2 = es; e2 < es + 16; ++e2) {
            const int d2 = sdst[e2];
            const float4 v = *(const float4*)&Mf[e2 * 128 + (c0 ^ ((e2 & 7) << 2))];
            if (d2 != cur) {
                float* ap = &agg[(size_t)cur * HID + c0];
                atomicAdd(ap + 0, run.x);
                atomicAdd(ap + 1, run.y);
                atomicAdd(ap + 2, run.z);
                atomicAdd(ap + 3, run.w);
                run = make_float4(0.f, 0.f, 0.f, 0.f);
                cur = d2;
            }
            run.x += v.x; run.y += v.y; run.z += v.z; run.w += v.w;
        }
        float* ap = &agg[(size_t)cur * HID + c0];
        atomicAdd(ap + 0, run.x);
        atomicAdd(ap + 1, run.y);
        atomicAdd(ap + 2, run.z);
        atomicAdd(ap + 3, run.w);
    }
}

// ---------------- residual update; re-zero agg ----------------
__global__ void update_kernel_csr(float* __restrict__ node, float* __restrict__ agg,
                                  const int* __restrict__ rowptr)
{
    int i = blockIdx.x * blockDim.x + threadIdx.x;
    if (i < NNODES * HID) {
        int n = i >> 7;
        float cnt = (float)(rowptr[n + 1] - rowptr[n]);
        node[i] += agg[i] / fmaxf(cnt, 1.0f);
        agg[i] = 0.f;
    }
}

// ---------------- decoder: 128->128->128->2 ----------------
__global__ __launch_bounds__(128) void decoder_kernel(
    const float* __restrict__ node,
    const float* __restrict__ W1, const float* __restrict__ b1,
    const float* __restrict__ W2, const float* __restrict__ b2,
    const float* __restrict__ W3, const float* __restrict__ b3,
    float* __restrict__ out)
{
    __shared__ float xs[16][HID];
    __shared__ float h1[16][HID];
    __shared__ float h2[16][HID];
    const int t = threadIdx.x;
    const int base = blockIdx.x * 16;

    for (int i = t; i < 16 * 32; i += 128) {
        int e = i >> 5, c = (i & 31) << 2;
        *(float4*)&xs[e][c] = *(const float4*)&node[(size_t)(base + e) * HID + c];
    }
    __syncthreads();
    {
        const float bb = b1[t];
        for (int e = 0; e < 16; ++e) {
            float acc = bb;
            for (int k = 0; k < HID; ++k) acc += xs[e][k] * W1[k * HID + t];
            h1[e][t] = fmaxf(acc, 0.f);
        }
    }
    __syncthreads();
    {
        const float bb = b2[t];
        for (int e = 0; e < 16; ++e) {
            float acc = bb;
            for (int k = 0; k < HID; ++k) acc += h1[e][k] * W2[k * HID + t];
            h2[e][t] = fmaxf(acc, 0.f);
        }
    }
    __syncthreads();
    if (t < 32) {
        const int e = t >> 1, o = t & 1;
        float acc = b3[o];
        for (int k = 0; k < HID; ++k) acc += h2[e][k] * W3[k * 2 + o];
        out[(size_t)(base + e) * 2 + o] = acc;
    }
}

// ================= fp32 fallback (proven rounds 2-3) =================
__global__ void degree_kernel(const int* __restrict__ dst, float* __restrict__ cnt)
{
    int i = blockIdx.x * blockDim.x + threadIdx.x;
    if (i < NEDGES) {
        int d = min(max(dst[i], 0), NNODES - 1);
        atomicAdd(&cnt[d], 1.0f);
    }
}

__global__ void update_kernel_cnt(float* __restrict__ node, float* __restrict__ agg,
                                  const float* __restrict__ cnt)
{
    int i = blockIdx.x * blockDim.x + threadIdx.x;
    if (i < NNODES * HID) {
        int n = i >> 7;
        node[i] += agg[i] / fmaxf(cnt[n], 1.0f);
        agg[i] = 0.f;
    }
}

__global__ __launch_bounds__(128) void fuse_kernel(
    const float* __restrict__ eW3, const float* __restrict__ eb3,
    const float* __restrict__ pW1, const float* __restrict__ pb1,
    float* __restrict__ Wc, float* __restrict__ g)
{
    const int l = blockIdx.x >> 3;
    const int s = blockIdx.x & 7;
    const int c = threadIdx.x;
    const float* W1l = pW1 + (size_t)l * 2 * HID * HID;
    float* Wcl = Wc + (size_t)l * 2 * HID * HID;

    for (int r = s * 16; r < s * 16 + 16; ++r)
        Wcl[r * HID + c] = W1l[r * HID + c];

    for (int m = s * 16; m < s * 16 + 16; ++m) {
        float a0 = 0.f, a1 = 0.f, a2 = 0.f, a3 = 0.f;
        for (int k = 0; k < HID; k += 4) {
            a0 += eW3[m * HID + k + 0] * W1l[(HID + k + 0) * HID + c];
            a1 += eW3[m * HID + k + 1] * W1l[(HID + k + 1) * HID + c];
            a2 += eW3[m * HID + k + 2] * W1l[(HID + k + 2) * HID + c];
            a3 += eW3[m * HID + k + 3] * W1l[(HID + k + 3) * HID + c];
        }
        Wcl[(HID + m) * HID + c] = (a0 + a1) + (a2 + a3);
    }
    if (s == 0) {
        float a = pb1[l * HID + c];
        for (int k = 0; k < HID; ++k)
            a += eb3[k] * W1l[(HID + k) * HID + c];
        g[l * HID + c] = a;
    }
}

__global__ __launch_bounds__(256) void msg_recomp(
    const float* __restrict__ node,
    const float* __restrict__ edge_attr,
    const float* __restrict__ eW1, const float* __restrict__ eb1,
    const float* __restrict__ eW2, const float* __restrict__ eb2,
    const int* __restrict__ src_idx, const int* __restrict__ dst_idx,
    const float* __restrict__ W1, const float* __restrict__ b1,
    const float* __restrict__ W2, const float* __restrict__ b2,
    const float* __restrict__ W3, const float* __restrict__ b3,
    float* __restrict__ agg)
{
    __shared__ float X[32][256];
    __shared__ float H[32][HID];
    __shared__ int ssrc[32];
    __shared__ int sdst[32];
    __shared__ float ea_s[32][4];

    const int t = threadIdx.x;
    const int eb = blockIdx.x * 32;

    if (t < 32) { int s = src_idx[eb + t]; ssrc[t] = min(max(s, 0), NNODES - 1); }
    else if (t < 64) { int d = dst_idx[eb + (t - 32)]; sdst[t - 32] = min(max(d, 0), NNODES - 1); }
    __syncthreads();

    for (int i = t; i < 32 * 32; i += 256) {
        int e = i >> 5; int c = (i & 31) << 2;
        *(float4*)&X[e][c] = *(const float4*)&node[(size_t)ssrc[e] * HID + c];
    }
    for (int i = t; i < 32 * 3; i += 256)
        ea_s[i / 3][i % 3] = edge_attr[(size_t)(eb + i / 3) * 3 + (i % 3)];
    __syncthreads();

    const int ct = t & 31;
    const int et = (t >> 5) << 2;
    const int cb = ct << 2;
    float acc[4][4];

    {
        const float4 bv = *(const float4*)&eb1[cb];
        #pragma unroll
        for (int j = 0; j < 4; ++j) { acc[j][0] = bv.x; acc[j][1] = bv.y; acc[j][2] = bv.z; acc[j][3] = bv.w; }
        #pragma unroll
        for (int k = 0; k < 3; ++k) {
            const float4 wv = *(const float4*)&eW1[k * HID + cb];
            #pragma unroll
            for (int j = 0; j < 4; ++j) {
                const float xx = ea_s[et + j][k];
                acc[j][0] += xx * wv.x; acc[j][1] += xx * wv.y; acc[j][2] += xx * wv.z; acc[j][3] += xx * wv.w;
            }
        }
        #pragma unroll
        for (int j = 0; j < 4; ++j)
            *(float4*)&H[et + j][cb] = make_float4(fmaxf(acc[j][0],0.f), fmaxf(acc[j][1],0.f), fmaxf(acc[j][2],0.f), fmaxf(acc[j][3],0.f));
    }
    __syncthreads();
    {
        const float4 bv = *(const float4*)&eb2[cb];
        #pragma unroll
        for (int j = 0; j < 4; ++j) { acc[j][0] = bv.x; acc[j][1] = bv.y; acc[j][2] = bv.z; acc[j][3] = bv.w; }
        for (int k = 0; k < HID; ++k) {
            const float4 wv = *(const float4*)&eW2[k * HID + cb];
            const float x0 = H[et+0][k], x1 = H[et+1][k], x2 = H[et+2][k], x3 = H[et+3][k];
            acc[0][0]+=x0*wv.x; acc[0][1]+=x0*wv.y; acc[0][2]+=x0*wv.z; acc[0][3]+=x0*wv.w;
            acc[1][0]+=x1*wv.x; acc[1][1]+=x1*wv.y; acc[1][2]+=x1*wv.z; acc[1][3]+=x1*wv.w;
            acc[2][0]+=x2*wv.x; acc[2][1]+=x2*wv.y; acc[2][2]+=x2*wv.z; acc[2][3]+=x2*wv.w;
            acc[3][0]+=x3*wv.x; acc[3][1]+=x3*wv.y; acc[3][2]+=x3*wv.z; acc[3][3]+=x3*wv.w;
        }
        #pragma unroll
        for (int j = 0; j < 4; ++j)
            *(float4*)&X[et + j][HID + cb] = make_float4(fmaxf(acc[j][0],0.f), fmaxf(acc[j][1],0.f), fmaxf(acc[j][2],0.f), fmaxf(acc[j][3],0.f));
    }
    __syncthreads();
    {
        const float4 bv = *(const float4*)&b1[cb];
        #pragma unroll
        for (int j = 0; j < 4; ++j) { acc[j][0] = bv.x; acc[j][1] = bv.y; acc[j][2] = bv.z; acc[j][3] = bv.w; }
        for (int k = 0; k < 256; ++k) {
            const float4 wv = *(const float4*)&W1[k * HID + cb];
            const float x0 = X[et+0][k], x1 = X[et+1][k], x2 = X[et+2][k], x3 = X[et+3][k];
            acc[0][0]+=x0*wv.x; acc[0][1]+=x0*wv.y; acc[0][2]+=x0*wv.z; acc[0][3]+=x0*wv.w;
            acc[1][0]+=x1*wv.x; acc[1][1]+=x1*wv.y; acc[1][2]+=x1*wv.z; acc[1][3]+=x1*wv.w;
            acc[2][0]+=x2*wv.x; acc[2][1]+=x2*wv.y; acc[2][2]+=x2*wv.z; acc[2][3]+=x2*wv.w;
            acc[3][0]+=x3*wv.x; acc[3][1]+=x3*wv.y; acc[3][2]+=x3*wv.z; acc[3][3]+=x3*wv.w;
        }
        __syncthreads();
        #pragma unroll
        for (int j = 0; j < 4; ++j)
            *(float4*)&H[et + j][cb] = make_float4(fmaxf(acc[j][0],0.f), fmaxf(acc[j][1],0.f), fmaxf(acc[j][2],0.f), fmaxf(acc[j][3],0.f));
    }
    __syncthreads();
    float* Xf = &X[0][0];
    {
        const float4 bv = *(const float4*)&b2[cb];
        #pragma unroll
        for (int j = 0; j < 4; ++j) { acc[j][0] = bv.x; acc[j][1] = bv.y; acc[j][2] = bv.z; acc[j][3] = bv.w; }
        for (int k = 0; k < HID; ++k) {
            const float4 wv = *(const float4*)&W2[k * HID + cb];
            const float x0 = H[et+0][k], x1 = H[et+1][k], x2 = H[et+2][k], x3 = H[et+3][k];
            acc[0][0]+=x0*wv.x; acc[0][1]+=x0*wv.y; acc[0][2]+=x0*wv.z; acc[0][3]+=x0*wv.w;
            acc[1][0]+=x1*wv.x; acc[1][1]+=x1*wv.y; acc[1][2]+=x1*wv.z; acc[1][3]+=x1*wv.w;
            acc[2][0]+=x2*wv.x; acc[2][1]+=x2*wv.y; acc[2][2]+=x2*wv.z; acc[2][3]+=x2*wv.w;
            acc[3][0]+=x3*wv.x; acc[3][1]+=x3*wv.y; acc[3][2]+=x3*wv.z; acc[3][3]+=x3*wv.w;
        }
        #pragma unroll
        for (int j = 0; j < 4; ++j)
            *(float4*)&Xf[(et + j) * HID + cb] = make_float4(fmaxf(acc[j][0],0.f), fmaxf(acc[j][1],0.f), fmaxf(acc[j][2],0.f), fmaxf(acc[j][3],0.f));
    }
    __syncthreads();
    {
        const float4 bv = *(const float4*)&b3[cb];
        #pragma unroll
        for (int j = 0; j < 4; ++j) { acc[j][0] = bv.x; acc[j][1] = bv.y; acc[j][2] = bv.z; acc[j][3] = bv.w; }
        for (int k = 0; k < HID; ++k) {
            const float4 wv = *(const float4*)&W3[k * HID + cb];
            const float x0 = Xf[(et+0)*HID+k], x1 = Xf[(et+1)*HID+k];
            const float x2 = Xf[(et+2)*HID+k], x3 = Xf[(et+3)*HID+k];
            acc[0][0]+=x0*wv.x; acc[0][1]+=x0*wv.y; acc[0][2]+=x0*wv.z; acc[0][3]+=x0*wv.w;
            acc[1][0]+=x1*wv.x; acc[1][1]+=x1*wv.y; acc[1][2]+=x1*wv.z; acc[1][3]+=x1*wv.w;
            acc[2][0]+=x2*wv.x; acc[2][1]+=x2*wv.y; acc[2][2]+=x2*wv.z; acc[2][3]+=x2*wv.w;
            acc[3][0]+=x3*wv.x; acc[3][1]+=x3*wv.y; acc[3][2]+=x3*wv.z; acc[3][3]+=x3*wv.w;
        }
        #pragma unroll
        for (int j = 0; j < 4; ++j) {
            const int d = sdst[et + j];
            float* ap = &agg[(size_t)d * HID + cb];
            atomicAdd(ap + 0, acc[j][0]);
            atomicAdd(ap + 1, acc[j][1]);
            atomicAdd(ap + 2, acc[j][2]);
            atomicAdd(ap + 3, acc[j][3]);
        }
    }
}

extern "C" void kernel_launch(void* const* d_in, const int* in_sizes, int n_in,
                              void* d_out, int out_size, void* d_ws, size_t ws_size,
                              hipStream_t stream)
{
    const float* x         = (const float*)d_in[0];
    const float* edge_attr = (const float*)d_in[1];
    const float* nW1 = (const float*)d_in[2];  const float* nb1 = (const float*)d_in[3];
    const float* nW2 = (const float*)d_in[4];  const float* nb2 = (const float*)d_in[5];
    const float* nW3 = (const float*)d_in[6];  const float* nb3 = (const float*)d_in[7];
    const float* eW1 = (const float*)d_in[8];  const float* eb1 = (const float*)d_in[9];
    const float* eW2 = (const float*)d_in[10]; const float* eb2 = (const float*)d_in[11];
    const float* eW3 = (const float*)d_in[12]; const float* eb3 = (const float*)d_in[13];
    const float* pW1 = (const float*)d_in[14]; const float* pb1 = (const float*)d_in[15];
    const float* pW2 = (const float*)d_in[16]; const float* pb2 = (const float*)d_in[17];
    const float* pW3 = (const float*)d_in[18]; const float* pb3 = (const float*)d_in[19];
    const float* dW1 = (const float*)d_in[20]; const float* db1 = (const float*)d_in[21];
    const float* dW2 = (const float*)d_in[22]; const float* db2 = (const float*)d_in[23];
    const float* dW3 = (const float*)d_in[24]; const float* db3 = (const float*)d_in[25];
    const int* ei  = (const int*)d_in[26];
    const int* src = ei;
    const int* dst = ei + NEDGES;

    // fast-path workspace layout (bytes)
    char* ws = (char*)d_ws;
    float* node    = (float*)(ws);                     // 10,240,000
    float* agg     = (float*)(ws + 10240000);          // 10,240,000
    int*   cnt_i   = (int*)  (ws + 20480000);          //     80,000
    int*   fill    = (int*)  (ws + 20560000);          //     80,000
    int*   rowptr  = (int*)  (ws + 20640000);          //     80,064
    float* gb      = (float*)(ws + 20720064);          //      5,120
    uint4* wfrag   = (uint4*)(ws + 20725184);          //  2,621,440
    uint4* ewf     = (uint4*)(ws + 23346624);          //     65,536
    int*   seid    = (int*)  (ws + 23412160);          //  2,560,000
    unsigned short* ssrc16 = (unsigned short*)(ws + 25972160);  // 1,280,000
    unsigned short* sdst16 = (unsigned short*)(ws + 27252160);  // 1,280,000
    uint4* h2img   = (uint4*)(ws + 28532160);          // 163,840,000 (MAT only)
    const size_t NEED_FAST = 28532160ull;
    const size_t NEED_MAT  = 28532160ull + 163840000ull;   // 192,372,160 (proven fits)

    // fp32 fallback layout (proven fits)
    float* cntf = (float*)(ws + 20480000);
    float* Wc   = (float*)(ws + 20560000);
    float* gb2  = (float*)(ws + 21870720);

    const bool fast = (ws_size >= NEED_FAST);
    const bool mat  = (ws_size >= NEED_MAT);

    encoder_kernel<16, 2><<<NNODES / 16, 128, 0, stream>>>(
        x, nW1, nb1, nW2, nb2, nW3, nb3, node, NNODES);

    if (fast) {
        hipMemsetAsync(ws + 10240000, 0, 10240000 + 160000, stream);

        hist_kernel<<<(NEDGES + 255) / 256, 256, 0, stream>>>(dst, cnt_i);
        scan_kernel<<<1, 1024, 0, stream>>>(cnt_i, rowptr);
        scatter_kernel<<<(NEDGES + 255) / 256, 256, 0, stream>>>(
            src, dst, rowptr, fill, seid, ssrc16, sdst16);

        wprep_kernel<<<(NSTEPS * 16384 + 4096) / 256, 256, 0, stream>>>(
            eW3, pW1, pW2, pW3, eW2, wfrag);
        gfuse_kernel<<<NSTEPS, 128, 0, stream>>>(eb3, pW1, pb1, gb);

        if (mat) {
            h2prep_kernel<<<NEDGES / 128, 256, 0, stream>>>(
                edge_attr, eW1, eb1, eb2, ewf, seid, h2img);
            for (int l = 0; l < NSTEPS; ++l) {
                msg_mfma_h<<<NEDGES / 128, 256, 0, stream>>>(
                    node, h2img, wfrag + (size_t)l * 16384,
                    ssrc16, sdst16,
                    gb + l * HID, pb2 + l * HID, pb3 + l * HID, agg);
                update_kernel_csr<<<(NNODES * HID) / 256, 256, 0, stream>>>(node, agg, rowptr);
            }
        } else {
            for (int l = 0; l < NSTEPS; ++l) {
                msg_mfma_s<<<NEDGES / 128, 256, 0, stream>>>(
                    node, edge_attr, eW1, eb1, eb2,
                    ewf, wfrag + (size_t)l * 16384,
                    seid, ssrc16, sdst16,
                    gb + l * HID, pb2 + l * HID, pb3 + l * HID, agg);
                update_kernel_csr<<<(NNODES * HID) / 256, 256, 0, stream>>>(node, agg, rowptr);
            }
        }
    } else {
        hipMemsetAsync(ws + 10240000, 0, 10240000 + 80000, stream);
        degree_kernel<<<(NEDGES + 255) / 256, 256, 0, stream>>>(dst, cntf);
        fuse_kernel<<<NSTEPS * 8, 128, 0, stream>>>(eW3, eb3, pW1, pb1, Wc, gb2);
        for (int l = 0; l < NSTEPS; ++l) {
            msg_recomp<<<NEDGES / 32, 256, 0, stream>>>(
                node, edge_attr, eW1, eb1, eW2, eb2, src, dst,
                Wc + (size_t)l * 2 * HID * HID,  gb2 + l * HID,
                pW2 + (size_t)l * HID * HID,     pb2 + l * HID,
                pW3 + (size_t)l * HID * HID,     pb3 + l * HID,
                agg);
            update_kernel_cnt<<<(NNODES * HID) / 256, 256, 0, stream>>>(node, agg, cntf);
        }
    }

    decoder_kernel<<<NNODES / 16, 128, 0, stream>>>(
        node, dW1, db1, dW2, db2, dW3, db3, (float*)d_out);
}